// Round 8
// baseline (1161.738 us; speedup 1.0000x reference)
//
#include <hip/hip_runtime.h>

// GraphGRU on MI355X — round 14.
//   r13 proved chunk-phasing halves FETCH (153->83 MB) but 4x'd VMEM instructions
//   (VALUBusy 63%, dur regressed). v3 gathers keep the chunk locality and restore
//   per-instruction coverage: 4 lanes/row x dwordx4 -> one data VMEM covers 16 edges
//   (vs 4). Per 16-edge batch per chunk: 1 idx + 1 data VMEM. Reduce = 4 shfl stages.
//   Everything else identical to r13.

typedef __bf16 bf16;
typedef __bf16 bf16x8 __attribute__((ext_vector_type(8)));
typedef __bf16 bf16x4 __attribute__((ext_vector_type(4)));
typedef float  f32x4  __attribute__((ext_vector_type(4)));
typedef float  f32x2  __attribute__((ext_vector_type(2)));
typedef unsigned char u8;

#define DH 128

__device__ __forceinline__ float sigmoidf_(float x) { return 1.0f / (1.0f + expf(-x)); }

// ---------------- CSR build ----------------
__global__ __launch_bounds__(256) void hist_kernel(const int* __restrict__ ei, const int* __restrict__ role,
                                                   int* __restrict__ cnt3, int* __restrict__ rolecnt,
                                                   int E, int N)
{
  int i = blockIdx.x * 256 + threadIdx.x;
  int lane = threadIdx.x & 63;
  int r = (i < N) ? role[i] : -1;
  #pragma unroll
  for (int rr = 0; rr < 3; ++rr) {
    unsigned long long mask = __ballot(r == rr);
    if (lane == 0 && mask) atomicAdd(&rolecnt[rr], __popcll(mask));
  }
  if (i < E + N) {
    int src, dst;
    if (i < E) { src = ei[i]; dst = ei[E + i]; } else { src = i - E; dst = i - E; }
    int rs = (i < E) ? role[src] : r;
    if (i >= E) rs = role[i - E];
    atomicAdd(&cnt3[dst * 3 + rs], 1);
  }
}

__global__ __launch_bounds__(1024) void scan1_kernel(const int* __restrict__ cnt, int* __restrict__ off,
                                                     int* __restrict__ bsum, int n)
{
  __shared__ int wsum[16];
  int t = threadIdx.x, lane = t & 63, w = t >> 6;
  int idx = blockIdx.x * 1024 + t;
  int v = (idx < n) ? cnt[idx] : 0;
  int s = v;
  #pragma unroll
  for (int d = 1; d < 64; d <<= 1) { int u = __shfl_up(s, d); if (lane >= d) s += u; }
  if (lane == 63) wsum[w] = s;
  __syncthreads();
  if (w == 0 && lane < 16) {
    int ws = wsum[lane];
    #pragma unroll
    for (int d = 1; d < 16; d <<= 1) { int u = __shfl_up(ws, d); if (lane >= d) ws += u; }
    wsum[lane] = ws;
  }
  __syncthreads();
  int inc = ((w > 0) ? wsum[w - 1] : 0) + s;
  if (idx < n) off[idx + 1] = inc;
  if (t == 1023) bsum[blockIdx.x] = inc;
}

__global__ void scan2_kernel(int* __restrict__ bsum, int nb, const int* __restrict__ rolecnt,
                             int* __restrict__ rolefill, int* __restrict__ roleinfo)
{
  int lane = threadIdx.x;
  int carry = 0;
  for (int base = 0; base < nb; base += 64) {
    int v = (base + lane < nb) ? bsum[base + lane] : 0;
    int s = v;
    #pragma unroll
    for (int d = 1; d < 64; d <<= 1) { int u = __shfl_up(s, d); if (lane >= d) s += u; }
    if (base + lane < nb) bsum[base + lane] = carry + s - v;
    carry += __shfl(s, 63);
  }
  if (lane == 0) {
    int c0 = rolecnt[0], c1 = rolecnt[1], c2 = rolecnt[2];
    int s1 = (c0 + 255) & ~255;
    int s2 = s1 + ((c1 + 255) & ~255);
    int mp = s2 + ((c2 + 255) & ~255);
    rolefill[0] = 0; rolefill[1] = s1; rolefill[2] = s2;
    roleinfo[0] = s1; roleinfo[1] = s2;
    roleinfo[2] = c0;      roleinfo[3] = s1 - c0;
    roleinfo[4] = s1 + c1; roleinfo[5] = s2 - s1 - c1;
    roleinfo[6] = s2 + c2; roleinfo[7] = mp - s2 - c2;
  }
}

__global__ __launch_bounds__(1024) void scan3_kernel(int* __restrict__ off, int* __restrict__ fill,
                                                     const int* __restrict__ bsum, int n)
{
  int idx = blockIdx.x * 1024 + threadIdx.x;
  if (idx == 0) { off[0] = 0; fill[0] = 0; }
  if (idx < n) {
    int v = off[idx + 1] + bsum[blockIdx.x];
    off[idx + 1] = v;
    if (idx + 1 < n) fill[idx + 1] = v;
  }
}

// bucketfill[b] = off3[3 * min(b*W, N)]
__global__ void bucketinit_kernel(const int* __restrict__ off3, int* __restrict__ bucketfill,
                                  int NB, int W, int N)
{
  int b = blockIdx.x * 256 + threadIdx.x;
  if (b < NB) {
    int d = min(b * W, N);
    bucketfill[b] = off3[d * 3];
  }
}

// stage 1: partition edges into dst-range buckets; records = (bin, t)
__global__ __launch_bounds__(256) void partition_kernel(
    const int* __restrict__ ei, const int* __restrict__ spos,
    const int* __restrict__ roleinfo, int* __restrict__ bucketfill,
    int2* __restrict__ recs, int E, int N, int shiftB)
{
  __shared__ int lcnt[256], lbase[256];
  const int base = blockIdx.x * 4096;
  const int s1 = roleinfo[0], s2 = roleinfo[1];
  lcnt[threadIdx.x] = 0;
  __syncthreads();
  int myb[16], mybin[16], myt[16];
  #pragma unroll
  for (int k = 0; k < 16; ++k) {
    int i = base + k * 256 + threadIdx.x;
    myb[k] = -1;
    if (i < E + N) {
      int src, dst;
      if (i < E) { src = ei[i]; dst = ei[E + i]; } else { src = i - E; dst = i - E; }
      int t = spos[src];
      int r = (t >= s2) ? 2 : (t >= s1) ? 1 : 0;
      myb[k] = dst >> shiftB;
      mybin[k] = dst * 3 + r;
      myt[k] = t;
      atomicAdd(&lcnt[myb[k]], 1);
    }
  }
  __syncthreads();
  int c = lcnt[threadIdx.x];
  lbase[threadIdx.x] = (c > 0) ? atomicAdd(&bucketfill[threadIdx.x], c) : 0;
  __syncthreads();
  lcnt[threadIdx.x] = 0;          // reuse as per-bucket cursor
  __syncthreads();
  #pragma unroll
  for (int k = 0; k < 16; ++k) {
    if (myb[k] >= 0) {
      int slot = atomicAdd(&lcnt[myb[k]], 1);
      recs[lbase[myb[k]] + slot] = make_int2(mybin[k], myt[k]);
    }
  }
}

// stage 2: replay one bucket per WG; ssrc writes confined to the bucket's slice
__global__ __launch_bounds__(1024) void binscatter_kernel(
    const int2* __restrict__ recs, const int* __restrict__ off3,
    int* __restrict__ fill3, int* __restrict__ ssrc, int W, int N)
{
  int b = blockIdx.x;
  int d0 = min(b * W, N), d1 = min((b + 1) * W, N);
  int s = off3[d0 * 3], e = off3[d1 * 3];
  for (int i = s + threadIdx.x; i < e; i += 1024) {
    int2 rec = recs[i];
    int pz = atomicAdd(&fill3[rec.x], 1);
    ssrc[pz] = rec.y;
  }
}

__global__ __launch_bounds__(256) void permscatter_kernel(const int* __restrict__ role, int* __restrict__ rolefill,
                                                          int* __restrict__ spos, int* __restrict__ sposinv, int N)
{
  int i = blockIdx.x * 256 + threadIdx.x;
  int lane = threadIdx.x & 63;
  int r = (i < N) ? role[i] : -1;
  #pragma unroll
  for (int rr = 0; rr < 3; ++rr) {
    unsigned long long mask = __ballot(r == rr);
    if (!mask) continue;
    int base = 0;
    if (lane == 0) base = atomicAdd(&rolefill[rr], __popcll(mask));
    base = __shfl(base, 0);
    if (r == rr) {
      int rank = (int)__popcll(mask & ((1ull << lane) - 1ull));
      int pos = base + rank;
      spos[i] = pos;
      sposinv[pos] = i;
    }
  }
}

__global__ __launch_bounds__(256) void zeropad_kernel(const int* __restrict__ roleinfo,
                                                      bf16* __restrict__ Ax, bf16* __restrict__ Ah)
{
  int id = blockIdx.x * 256 + threadIdx.x;   // 98304
  int a = id / 49152, rem = id % 49152;
  int gp = rem / 16384, r2 = rem % 16384;
  int rr = r2 >> 6, c = r2 & 63;
  int gs = roleinfo[2 + gp * 2], gl = roleinfo[3 + gp * 2];
  if (rr < gl) {
    int row = gs + rr;
    size_t unit = (size_t)(row >> 4) * 1024 + c * 16 + (row & 15);
    bf16x8 z = {};
    ((bf16x8*)(a == 0 ? Ax : Ah))[unit] = z;
  }
}

// ---------------- prep ----------------
// xq8c: 4 planes of 64 B/row (planes 0-1 = x features, 2-3 = h features)
__global__ __launch_bounds__(256) void prep_xh_kernel(const float* __restrict__ x, const float* __restrict__ h,
                                                      const int* __restrict__ spos, u8* __restrict__ xq8c,
                                                      bf16* __restrict__ Ax, bf16* __restrict__ Ah,
                                                      int N, int rows_pad)
{
  int g = blockIdx.x * 256 + threadIdx.x;
  if (g >= N * 32) return;
  int n = g >> 5, j = g & 31;
  int t = spos[n];
  const float* src = (j < 16) ? (x + (size_t)n * 128 + (j << 3))
                              : (h + (size_t)n * 128 + ((j - 16) << 3));
  float4 v0 = ((const float4*)src)[0];
  float4 v1 = ((const float4*)src)[1];
  int lo = __builtin_amdgcn_cvt_pk_fp8_f32(v0.x, v0.y, 0, false);
  lo = __builtin_amdgcn_cvt_pk_fp8_f32(v0.z, v0.w, lo, true);
  int hi = __builtin_amdgcn_cvt_pk_fp8_f32(v1.x, v1.y, 0, false);
  hi = __builtin_amdgcn_cvt_pk_fp8_f32(v1.z, v1.w, hi, true);
  *(int2*)(xq8c + ((size_t)(j >> 3) * rows_pad + t) * 64 + (j & 7) * 8) = make_int2(lo, hi);
  bf16x8 o;
  o[0] = (bf16)v0.x; o[1] = (bf16)v0.y; o[2] = (bf16)v0.z; o[3] = (bf16)v0.w;
  o[4] = (bf16)v1.x; o[5] = (bf16)v1.y; o[6] = (bf16)v1.z; o[7] = (bf16)v1.w;
  size_t unit = (size_t)(t >> 4) * 1024 + (48 + (j & 15)) * 16 + (t & 15);
  ((bf16x8*)(j < 16 ? Ax : Ah))[unit] = o;
}

struct PrepW { const float* W[6]; const float* Wg[6]; const float* bg[6]; };
__global__ __launch_bounds__(256) void prep_wf_kernel(PrepW pw, bf16* __restrict__ Wf)
{
  int idx = blockIdx.x * 256 + threadIdx.x;
  if (idx >= 294912) return;
  int cv = idx / 49152, pos = idx % 49152;
  int ks4q = pos >> 10;
  int col = (pos >> 3) & 127, j = pos & 7;
  int k = (ks4q >> 2) * 32 + (ks4q & 3) * 8 + j;
  int r = k >> 7, kk = k & 127;
  float g = sigmoidf_(pw.Wg[cv][r * 128 + col] + pw.bg[cv][r * 128 + col]);
  Wf[idx] = (bf16)(pw.W[cv][kk * 128 + col] * g);
}

struct PrepP { const float* W[6]; const float* S[6]; };
__global__ __launch_bounds__(128) void prep_pf_kernel(PrepP pp, bf16* __restrict__ Pf)
{
  int b = blockIdx.x;                          // 6*3*128
  int cv = b / 384, rem = b % 384;
  int r = rem >> 7, kp = rem & 127;
  int col = threadIdx.x;
  const float* W = pp.W[cv] + (size_t)kp * 128;
  const float* S = pp.S[cv] + (size_t)r * 16384;
  float sum = 0.f;
  #pragma unroll 4
  for (int j2 = 0; j2 < 128; ++j2) sum += W[j2] * S[j2 * 128 + col];
  size_t o = (size_t)(cv * 3 + r) * 16384 + ((size_t)(kp >> 3) * 128 + col) * 8 + (kp & 7);
  Pf[o] = (bf16)sum;
}

// ---------------- chunked gathers v3: 4 lanes/row, dwordx4 -> 16 edges per data VMEM ----------
#define ACCUM16(U, d) do { f32x2 f_;                                                   \
  f_ = __builtin_amdgcn_cvt_pk_f32_fp8((d).x, false); U[0]  += f_[0]; U[1]  += f_[1];  \
  f_ = __builtin_amdgcn_cvt_pk_f32_fp8((d).x, true);  U[2]  += f_[0]; U[3]  += f_[1];  \
  f_ = __builtin_amdgcn_cvt_pk_f32_fp8((d).y, false); U[4]  += f_[0]; U[5]  += f_[1];  \
  f_ = __builtin_amdgcn_cvt_pk_f32_fp8((d).y, true);  U[6]  += f_[0]; U[7]  += f_[1];  \
  f_ = __builtin_amdgcn_cvt_pk_f32_fp8((d).z, false); U[8]  += f_[0]; U[9]  += f_[1];  \
  f_ = __builtin_amdgcn_cvt_pk_f32_fp8((d).z, true);  U[10] += f_[0]; U[11] += f_[1];  \
  f_ = __builtin_amdgcn_cvt_pk_f32_fp8((d).w, false); U[12] += f_[0]; U[13] += f_[1];  \
  f_ = __builtin_amdgcn_cvt_pk_f32_fp8((d).w, true);  U[14] += f_[0]; U[15] += f_[1];  \
} while (0)

#define ACCSEL16(d, p) do {                      \
  if ((p) < o1)      { ACCUM16(u0, d); }         \
  else if ((p) < o2) { ACCUM16(u1, d); }         \
  else               { ACCUM16(u2, d); }         \
} while (0)

#define RED4(U) do {                                         \
  U += __shfl_xor(U, 4);  U += __shfl_xor(U, 8);             \
  U += __shfl_xor(U, 16); U += __shfl_xor(U, 32);            \
} while (0)

__global__ __launch_bounds__(512) void gather_xh_kernel(
    const u8* __restrict__ xq8c, const int* __restrict__ off3, const int* __restrict__ ssrc,
    const int* __restrict__ sposinv, bf16* __restrict__ Ax, bf16* __restrict__ Ah,
    float4* __restrict__ cntf, int rows_pad)
{
  __shared__ alignas(16) bf16 lds[8][192];
  int w = threadIdx.x >> 6, lane = threadIdx.x & 63;
  int c = blockIdx.y;                    // chunk 0..3 (0-1 -> Ax, 2-3 -> Ah)
  int t0 = blockIdx.x * 8;
  int t = t0 + w;
  int node = sposinv[t];                 // -1 for pad rows
  int rg = lane >> 2, fo = lane & 3;     // row-group 0..15, 16B-segment 0..3

  if (node >= 0) {
    int o0 = __builtin_amdgcn_readfirstlane(off3[node * 3]);
    int o1 = __builtin_amdgcn_readfirstlane(off3[node * 3 + 1]);
    int o2 = __builtin_amdgcn_readfirstlane(off3[node * 3 + 2]);
    int o3 = __builtin_amdgcn_readfirstlane(off3[node * 3 + 3]);
    float inv = 1.0f / (float)(o3 - o0);
    const u8* base = xq8c + (size_t)c * rows_pad * 64 + fo * 16;

    float u0[16], u1[16], u2[16];
    #pragma unroll
    for (int k = 0; k < 16; ++k) { u0[k] = 0.f; u1[k] = 0.f; u2[k] = 0.f; }

    const int e = o3, emax = o3 - 1;
    for (int i = o0; i < e; i += 32) {
      int p0 = i + rg, p1 = i + 16 + rg;
      int t0i = ssrc[min(p0, emax)];
      int t1i = ssrc[min(p1, emax)];
      int4 d0 = make_int4(0, 0, 0, 0), d1 = d0;
      if (p0 < e) d0 = *(const int4*)(base + (size_t)t0i * 64);
      if (p1 < e) d1 = *(const int4*)(base + (size_t)t1i * 64);
      ACCSEL16(d0, p0);
      ACCSEL16(d1, p1);
    }

    #pragma unroll
    for (int k = 0; k < 16; ++k) { RED4(u0[k]); RED4(u1[k]); RED4(u2[k]); }

    if (rg == 0) {
      // lane fo holds features [fo*16, fo*16+16) of the 64-B chunk, per role
      bf16x8 pa, pb;
      #pragma unroll
      for (int k = 0; k < 8; ++k) { pa[k] = (bf16)(u0[k] * inv); pb[k] = (bf16)(u0[8 + k] * inv); }
      *(bf16x8*)&lds[w][fo * 16] = pa;
      *(bf16x8*)&lds[w][fo * 16 + 8] = pb;
      #pragma unroll
      for (int k = 0; k < 8; ++k) { pa[k] = (bf16)(u1[k] * inv); pb[k] = (bf16)(u1[8 + k] * inv); }
      *(bf16x8*)&lds[w][64 + fo * 16] = pa;
      *(bf16x8*)&lds[w][64 + fo * 16 + 8] = pb;
      #pragma unroll
      for (int k = 0; k < 8; ++k) { pa[k] = (bf16)(u2[k] * inv); pb[k] = (bf16)(u2[8 + k] * inv); }
      *(bf16x8*)&lds[w][128 + fo * 16] = pa;
      *(bf16x8*)&lds[w][128 + fo * 16 + 8] = pb;
    }
    if (lane == 0 && c == 0)
      cntf[t] = make_float4((o1 - o0) * inv, (o2 - o1) * inv, (o3 - o2) * inv, (float)(o3 - o0));
  } else {
    if (lane < 24) {
      bf16x8 z = {};
      *(bf16x8*)&lds[w][lane * 8] = z;
    }
    if (lane == 0 && c == 0) cntf[t] = make_float4(0.f, 0.f, 0.f, 0.f);
  }

  __syncthreads();

  // cooperative write: 8 consecutive rows x 24 chunk-units -> full 128-B lines
  int tid = threadIdx.x;
  if (tid < 192) {
    int lc2 = tid >> 3, row = tid & 7;       // lc2 0..23
    int rr = lc2 >> 3, j = lc2 & 7;
    int col = rr * 16 + (c & 1) * 8 + j;
    size_t unit = (size_t)(t0 >> 4) * 1024 + col * 16 + (t0 & 15) + row;
    bf16* dst = (c < 2) ? Ax : Ah;
    __builtin_nontemporal_store(*(const bf16x8*)&lds[row][lc2 * 8], (bf16x8*)dst + unit);
  }
}

__global__ __launch_bounds__(512) void gather_q_kernel(
    const u8* __restrict__ q8c, const int* __restrict__ off3, const int* __restrict__ ssrc,
    const int* __restrict__ sposinv, bf16* __restrict__ Aq, int rows_pad)
{
  __shared__ alignas(16) bf16 lds[8][192];
  int w = threadIdx.x >> 6, lane = threadIdx.x & 63;
  int c = blockIdx.y;                    // chunk 0..1
  int t0 = blockIdx.x * 8;
  int t = t0 + w;
  int node = sposinv[t];
  int rg = lane >> 2, fo = lane & 3;

  if (node >= 0) {
    int o0 = __builtin_amdgcn_readfirstlane(off3[node * 3]);
    int o1 = __builtin_amdgcn_readfirstlane(off3[node * 3 + 1]);
    int o2 = __builtin_amdgcn_readfirstlane(off3[node * 3 + 2]);
    int o3 = __builtin_amdgcn_readfirstlane(off3[node * 3 + 3]);
    float inv = 1.0f / (float)(o3 - o0);
    const u8* base = q8c + (size_t)c * rows_pad * 64 + fo * 16;

    float u0[16], u1[16], u2[16];
    #pragma unroll
    for (int k = 0; k < 16; ++k) { u0[k] = 0.f; u1[k] = 0.f; u2[k] = 0.f; }

    const int e = o3, emax = o3 - 1;
    for (int i = o0; i < e; i += 32) {
      int p0 = i + rg, p1 = i + 16 + rg;
      int t0i = ssrc[min(p0, emax)];
      int t1i = ssrc[min(p1, emax)];
      int4 d0 = make_int4(0, 0, 0, 0), d1 = d0;
      if (p0 < e) d0 = *(const int4*)(base + (size_t)t0i * 64);
      if (p1 < e) d1 = *(const int4*)(base + (size_t)t1i * 64);
      ACCSEL16(d0, p0);
      ACCSEL16(d1, p1);
    }

    #pragma unroll
    for (int k = 0; k < 16; ++k) { RED4(u0[k]); RED4(u1[k]); RED4(u2[k]); }

    if (rg == 0) {
      bf16x8 pa, pb;
      #pragma unroll
      for (int k = 0; k < 8; ++k) { pa[k] = (bf16)(u0[k] * inv); pb[k] = (bf16)(u0[8 + k] * inv); }
      *(bf16x8*)&lds[w][fo * 16] = pa;
      *(bf16x8*)&lds[w][fo * 16 + 8] = pb;
      #pragma unroll
      for (int k = 0; k < 8; ++k) { pa[k] = (bf16)(u1[k] * inv); pb[k] = (bf16)(u1[8 + k] * inv); }
      *(bf16x8*)&lds[w][64 + fo * 16] = pa;
      *(bf16x8*)&lds[w][64 + fo * 16 + 8] = pb;
      #pragma unroll
      for (int k = 0; k < 8; ++k) { pa[k] = (bf16)(u2[k] * inv); pb[k] = (bf16)(u2[8 + k] * inv); }
      *(bf16x8*)&lds[w][128 + fo * 16] = pa;
      *(bf16x8*)&lds[w][128 + fo * 16 + 8] = pb;
    }
  } else {
    if (lane < 24) {
      bf16x8 z = {};
      *(bf16x8*)&lds[w][lane * 8] = z;
    }
  }

  __syncthreads();

  int tid = threadIdx.x;
  if (tid < 192) {
    int lc2 = tid >> 3, row = tid & 7;
    int rr = lc2 >> 3, j = lc2 & 7;
    int col = rr * 16 + c * 8 + j;
    size_t unit = (size_t)(t0 >> 4) * 1024 + col * 16 + (t0 & 15) + row;
    __builtin_nontemporal_store(*(const bf16x8*)&lds[row][lc2 * 8], (bf16x8*)Aq + unit);
  }
}

// ---------------- streaming MFMA GEMM (no LDS/barriers; 2 row-blocks per wave, 3 waves/SIMD) ----------------
struct GArgs {
  const bf16* Ap[5];
  const bf16* wf[5];
  const bf16* pf[5];
  bf16* out[5];
  const float* bias[5];
};

__global__ __launch_bounds__(256, 3) void gemm_kernel(GArgs ga, const float4* __restrict__ cntf,
                                                      const int* __restrict__ roleinfo)
{
  const int cv = blockIdx.y;
  const bf16* __restrict__ Ap = ga.Ap[cv];
  const bf16* __restrict__ wf = ga.wf[cv];
  const bf16* __restrict__ pf = ga.pf[cv];
  bf16* __restrict__ out = ga.out[cv];
  const float* __restrict__ bias = ga.bias[cv];

  const int w = threadIdx.x >> 6, lane = threadIdx.x & 63;
  const int q = lane >> 4, l = lane & 15;
  const int rb0 = blockIdx.x * 8 + w * 2;
  const int row0 = blockIdx.x * 128;
  const int s1 = roleinfo[0], s2 = roleinfo[1];
  const int role = (row0 >= s2) ? 2 : (row0 >= s1) ? 1 : 0;
  const int laneoff = q * 128 + l;

  f32x4 acc[2][8];
  #pragma unroll
  for (int j = 0; j < 2; ++j)
    #pragma unroll
    for (int ct = 0; ct < 8; ++ct)
      #pragma unroll
      for (int k = 0; k < 4; ++k) acc[j][ct][k] = 0.f;

  const bf16x8* A0 = (const bf16x8*)Ap + (size_t)rb0 * 1024 + lane;
  const bf16x8* WF = (const bf16x8*)wf + laneoff;
  const bf16x8* PF = (const bf16x8*)pf + role * 2048 + laneoff;

  #pragma unroll 2
  for (int ks = 0; ks < 16; ++ks) {
    const bf16x8* bp = (ks < 12) ? (WF + ks * 512) : (PF + (ks - 12) * 512);
    bf16x8 a0 = A0[ks * 64];
    bf16x8 a1 = A0[1024 + ks * 64];
    #pragma unroll
    for (int ct = 0; ct < 8; ++ct) {
      bf16x8 b = bp[ct * 16];
      acc[0][ct] = __builtin_amdgcn_mfma_f32_16x16x32_bf16(a0, b, acc[0][ct], 0, 0, 0);
      acc[1][ct] = __builtin_amdgcn_mfma_f32_16x16x32_bf16(a1, b, acc[1][ct], 0, 0, 0);
    }
  }

  const bool hb = (bias != nullptr);
  #pragma unroll
  for (int j = 0; j < 2; ++j) {
    int rb = rb0 + j;
    float4 cfs[4];
    if (hb) {
      #pragma unroll
      for (int reg = 0; reg < 4; ++reg) cfs[reg] = cntf[rb * 16 + q * 4 + reg];
    }
    #pragma unroll
    for (int ct = 0; ct < 8; ++ct) {
      int col = ct * 16 + l;
      float b0 = 0, b1 = 0, b2 = 0;
      if (hb) { b0 = bias[col]; b1 = bias[128 + col]; b2 = bias[256 + col]; }
      #pragma unroll
      for (int reg = 0; reg < 4; ++reg) {
        int t = rb * 16 + q * 4 + reg;
        float v = acc[j][ct][reg];
        if (hb) v += cfs[reg].x * b0 + cfs[reg].y * b1 + cfs[reg].z * b2;
        out[(size_t)t * 128 + col] = (bf16)fmaxf(v, 0.f);
      }
    }
  }
}

// ---------------- combines ----------------
__global__ __launch_bounds__(256) void combine1_kernel(
    const bf16* __restrict__ o0, const bf16* __restrict__ o1,
    const bf16* __restrict__ o2, const bf16* __restrict__ o3,
    const float* __restrict__ h, const int* __restrict__ spos,
    float* __restrict__ zbuf, u8* __restrict__ q8c, bf16* __restrict__ Aq, int N, int rows_pad)
{
  int g = blockIdx.x * 256 + threadIdx.x;
  if (g >= N * 16) return;
  int n = g >> 4, o = g & 15;
  int t = spos[n];
  size_t tb = (size_t)t * 16 + o;
  bf16x8 a0 = ((const bf16x8*)o0)[tb];
  bf16x8 a1 = ((const bf16x8*)o1)[tb];
  bf16x8 a2 = ((const bf16x8*)o2)[tb];
  bf16x8 a3 = ((const bf16x8*)o3)[tb];
  size_t nb = (size_t)n * 16 + o;
  float4 h0 = ((const float4*)h)[nb * 2];
  float4 h1 = ((const float4*)h)[nb * 2 + 1];
  float hv[8] = {h0.x, h0.y, h0.z, h0.w, h1.x, h1.y, h1.z, h1.w};
  float zv[8], qv[8];
  bf16x8 qb;
  #pragma unroll
  for (int j = 0; j < 8; ++j) {
    zv[j] = sigmoidf_((float)a0[j] + (float)a1[j]);
    qv[j] = sigmoidf_((float)a2[j] + (float)a3[j]) * hv[j];
    qb[j] = (bf16)qv[j];
  }
  ((float4*)zbuf)[nb * 2]     = make_float4(zv[0], zv[1], zv[2], zv[3]);
  ((float4*)zbuf)[nb * 2 + 1] = make_float4(zv[4], zv[5], zv[6], zv[7]);
  int lo = __builtin_amdgcn_cvt_pk_fp8_f32(qv[0], qv[1], 0, false);
  lo = __builtin_amdgcn_cvt_pk_fp8_f32(qv[2], qv[3], lo, true);
  int hi = __builtin_amdgcn_cvt_pk_fp8_f32(qv[4], qv[5], 0, false);
  hi = __builtin_amdgcn_cvt_pk_fp8_f32(qv[6], qv[7], hi, true);
  *(int2*)(q8c + ((size_t)(o >> 3) * rows_pad + t) * 64 + (o & 7) * 8) = make_int2(lo, hi);
  size_t unit = (size_t)(t >> 4) * 1024 + (48 + o) * 16 + (t & 15);
  ((bf16x8*)Aq)[unit] = qb;
}

__global__ __launch_bounds__(256) void combine2_kernel(
    const float* __restrict__ zbuf, const bf16* __restrict__ o4, const bf16* __restrict__ o5,
    const float* __restrict__ h, const int* __restrict__ spos, float* __restrict__ out, int N)
{
  int g = blockIdx.x * 256 + threadIdx.x;
  if (g >= N * 16) return;
  int n = g >> 4, o = g & 15;
  int t = spos[n];
  size_t tb = (size_t)t * 16 + o;
  bf16x8 a = ((const bf16x8*)o4)[tb];
  bf16x8 b = ((const bf16x8*)o5)[tb];
  size_t nb = (size_t)n * 16 + o;
  float4 z0 = ((const float4*)zbuf)[nb * 2];
  float4 z1 = ((const float4*)zbuf)[nb * 2 + 1];
  float4 h0 = ((const float4*)h)[nb * 2];
  float4 h1 = ((const float4*)h)[nb * 2 + 1];
  float zv[8] = {z0.x, z0.y, z0.z, z0.w, z1.x, z1.y, z1.z, z1.w};
  float hv[8] = {h0.x, h0.y, h0.z, h0.w, h1.x, h1.y, h1.z, h1.w};
  float ov[8];
  #pragma unroll
  for (int j = 0; j < 8; ++j)
    ov[j] = zv[j] * hv[j] + (1.f - zv[j]) * tanhf((float)a[j] + (float)b[j]);
  ((float4*)out)[nb * 2]     = make_float4(ov[0], ov[1], ov[2], ov[3]);
  ((float4*)out)[nb * 2 + 1] = make_float4(ov[4], ov[5], ov[6], ov[7]);
}

// ---------------- host ----------------
extern "C" void kernel_launch(void* const* d_in, const int* in_sizes, int n_in,
                              void* d_out, int out_size, void* d_ws, size_t ws_size,
                              hipStream_t stream)
{
  (void)n_in; (void)out_size; (void)ws_size;
  const float* x    = (const float*)d_in[0];
  const float* h    = (const float*)d_in[1];
  const int*   ei   = (const int*)d_in[2];
  const int*   role = (const int*)d_in[3];
  const int N = in_sizes[0] / DH;
  const int E = in_sizes[2] / 2;
  const int Etot = E + N;
  const int rows_pad = ((N + 765) + 255) & ~255;
  const int gx = rows_pad / 128;
  const int n3 = N * 3;
  const int nb3 = (n3 + 1023) / 1024;

  // bucket geometry: <=256 buckets of W=2^shiftB dst rows
  int shiftB = 8;
  while (((N - 1) >> shiftB) >= 256) ++shiftB;
  const int W = 1 << shiftB;
  const int NB = (N + W - 1) >> shiftB;

  // conv order: 0 xz, 1 hz, 2 xr, 3 hr, 4 xh, 5 hh
  static const int Wi[6]  = {4, 9, 13, 18, 22, 27};
  static const int Wgi[6] = {5, 10, 14, 19, 23, 28};
  static const int bgi[6] = {6, 11, 15, 20, 24, 29};
  static const int Si[6]  = {7, 12, 16, 21, 25, 30};

  char* p = (char*)d_ws;
  auto alloc = [&](size_t bytes) -> char* {
    char* r = p;
    p += (bytes + 255) & ~(size_t)255;
    return r;
  };

  bf16* Ax = (bf16*)alloc((size_t)rows_pad * 512 * 2);   // Aq aliases Ax
  bf16* Ah = (bf16*)alloc((size_t)rows_pad * 512 * 2);
  bf16* Aq = Ax;
  u8* xq8  = (u8*)alloc((size_t)rows_pad * 256);         // 4 planes of 64 B/row
  u8* q8   = (u8*)alloc((size_t)rows_pad * 128);         // 2 planes of 64 B/row
  bf16* outs[6];
  for (int c = 0; c < 5; ++c) outs[c] = (bf16*)alloc((size_t)rows_pad * 128 * 2);
  outs[5] = outs[0];
  float* zbuf = (float*)alloc((size_t)N * 128 * 4);
  float4* cntf = (float4*)alloc((size_t)rows_pad * 16);
  bf16* Wf = (bf16*)alloc((size_t)6 * 49152 * 2);
  bf16* Pf = (bf16*)alloc((size_t)18 * 16384 * 2);
  int* cnt3  = (int*)alloc((size_t)n3 * 4);
  int* off3  = (int*)alloc((size_t)(n3 + 1) * 4);
  int* fill3 = (int*)alloc((size_t)n3 * 4);
  int* bsum  = (int*)alloc((size_t)(nb3 + 1) * 4);
  int* ssrc  = (int*)alloc((size_t)Etot * 4);
  int2* recs = (int2*)alloc((size_t)Etot * 8);
  int* spos  = (int*)alloc((size_t)N * 4);
  int* sposinv = (int*)alloc((size_t)rows_pad * 4);
  int* rolecnt  = (int*)alloc(64);
  int* rolefill = (int*)alloc(64);
  int* roleinfo = (int*)alloc(64);
  int* bucketfill = (int*)alloc((size_t)(NB + 1) * 4);

  hipMemsetAsync(cnt3, 0, (size_t)n3 * 4, stream);
  hipMemsetAsync(rolecnt, 0, 16, stream);
  hipMemsetAsync(sposinv, 0xFF, (size_t)rows_pad * 4, stream);   // -1 = pad row

  int egrid = (Etot + 255) / 256;
  int ngrid = (N + 255) / 256;
  hist_kernel<<<egrid, 256, 0, stream>>>(ei, role, cnt3, rolecnt, E, N);
  scan1_kernel<<<nb3, 1024, 0, stream>>>(cnt3, off3, bsum, n3);
  scan2_kernel<<<1, 64, 0, stream>>>(bsum, nb3, rolecnt, rolefill, roleinfo);
  scan3_kernel<<<nb3, 1024, 0, stream>>>(off3, fill3, bsum, n3);
  permscatter_kernel<<<ngrid, 256, 0, stream>>>(role, rolefill, spos, sposinv, N);
  bucketinit_kernel<<<1, 256, 0, stream>>>(off3, bucketfill, NB, W, N);
  partition_kernel<<<(Etot + 4095) / 4096, 256, 0, stream>>>(ei, spos, roleinfo, bucketfill,
                                                             recs, E, N, shiftB);
  binscatter_kernel<<<NB, 1024, 0, stream>>>(recs, off3, fill3, ssrc, W, N);
  zeropad_kernel<<<384, 256, 0, stream>>>(roleinfo, Ax, Ah);

  prep_xh_kernel<<<(N * 32 + 255) / 256, 256, 0, stream>>>(x, h, spos, xq8, Ax, Ah, N, rows_pad);

  PrepW pw;
  for (int c = 0; c < 6; ++c) {
    pw.W[c] = (const float*)d_in[Wi[c]];
    pw.Wg[c] = (const float*)d_in[Wgi[c]];
    pw.bg[c] = (const float*)d_in[bgi[c]];
  }
  prep_wf_kernel<<<1152, 256, 0, stream>>>(pw, Wf);
  PrepP pp;
  for (int c = 0; c < 6; ++c) { pp.W[c] = (const float*)d_in[Wi[c]]; pp.S[c] = (const float*)d_in[Si[c]]; }
  prep_pf_kernel<<<2304, 128, 0, stream>>>(pp, Pf);

  gather_xh_kernel<<<dim3(rows_pad / 8, 4), 512, 0, stream>>>(xq8, off3, ssrc, sposinv,
                                                              Ax, Ah, cntf, rows_pad);

  // pass 1: one dispatch, cv 0..4 = {xz,xr,xh on Ax (bias)} + {hz,hr on Ah}
  GArgs g0;
  { int cvs[5] = {0, 2, 4, 1, 3};
    static const int bi2[5] = {8, 17, 26, -1, -1};
    const bf16* Apts[5] = {Ax, Ax, Ax, Ah, Ah};
    for (int k = 0; k < 5; ++k) {
      int c = cvs[k];
      g0.Ap[k] = Apts[k];
      g0.wf[k] = Wf + (size_t)c * 49152;
      g0.pf[k] = Pf + (size_t)c * 3 * 16384;
      g0.out[k] = outs[c];
      g0.bias[k] = (bi2[k] >= 0) ? (const float*)d_in[bi2[k]] : nullptr;
    } }
  gemm_kernel<<<dim3(gx, 5), 256, 0, stream>>>(g0, cntf, roleinfo);

  combine1_kernel<<<(N * 16 + 255) / 256, 256, 0, stream>>>(outs[0], outs[1], outs[2], outs[3],
                                                            h, spos, zbuf, q8, Aq, N, rows_pad);

  gather_q_kernel<<<dim3(rows_pad / 8, 2), 512, 0, stream>>>(q8, off3, ssrc, sposinv, Aq, rows_pad);

  // pass 2: conv hh(5) on Aq
  GArgs g2 = {};
  g2.Ap[0] = Aq;
  g2.wf[0] = Wf + (size_t)5 * 49152;
  g2.pf[0] = Pf + (size_t)5 * 3 * 16384;
  g2.out[0] = outs[5];
  g2.bias[0] = nullptr;
  gemm_kernel<<<dim3(gx, 1), 256, 0, stream>>>(g2, cntf, roleinfo);

  combine2_kernel<<<(N * 16 + 255) / 256, 256, 0, stream>>>(zbuf, outs[4], outs[5], h, spos,
                                                            (float*)d_out, N);
}

// Round 9
// 682.345 us; speedup vs baseline: 1.7026x; 1.7026x over previous
//
#include <hip/hip_runtime.h>

// GraphGRU on MI355X — round 15: REVERT to round-11 best (682.26 µs).
//   r12 (t-sort) and r13/r14 (chunked gathers) both failed: chunking halves FETCH but
//   either 4x's VMEM instructions (r13, VALU-bound) or strips loop-level latency
//   amortization (r14, 442 µs). Banking the verified best state:
//   - gathers: t-ordered 8-node/512-thread blocks, 4 independent int4 chains,
//     cooperative full-128B-line NT writes (r9).
//   - gemm: 2 row-blocks/wave, __launch_bounds__(256,3) (r11).
//   - CSR: bucketed two-pass scatter, no sort (r10).

typedef __bf16 bf16;
typedef __bf16 bf16x8 __attribute__((ext_vector_type(8)));
typedef float  f32x4  __attribute__((ext_vector_type(4)));
typedef float  f32x2  __attribute__((ext_vector_type(2)));
typedef unsigned char u8;

#define DH 128

__device__ __forceinline__ float sigmoidf_(float x) { return 1.0f / (1.0f + expf(-x)); }

// ---------------- CSR build ----------------
__global__ __launch_bounds__(256) void hist_kernel(const int* __restrict__ ei, const int* __restrict__ role,
                                                   int* __restrict__ cnt3, int* __restrict__ rolecnt,
                                                   int E, int N)
{
  int i = blockIdx.x * 256 + threadIdx.x;
  int lane = threadIdx.x & 63;
  int r = (i < N) ? role[i] : -1;
  #pragma unroll
  for (int rr = 0; rr < 3; ++rr) {
    unsigned long long mask = __ballot(r == rr);
    if (lane == 0 && mask) atomicAdd(&rolecnt[rr], __popcll(mask));
  }
  if (i < E + N) {
    int src, dst;
    if (i < E) { src = ei[i]; dst = ei[E + i]; } else { src = i - E; dst = i - E; }
    int rs = (i < E) ? role[src] : r;
    if (i >= E) rs = role[i - E];
    atomicAdd(&cnt3[dst * 3 + rs], 1);
  }
}

__global__ __launch_bounds__(1024) void scan1_kernel(const int* __restrict__ cnt, int* __restrict__ off,
                                                     int* __restrict__ bsum, int n)
{
  __shared__ int wsum[16];
  int t = threadIdx.x, lane = t & 63, w = t >> 6;
  int idx = blockIdx.x * 1024 + t;
  int v = (idx < n) ? cnt[idx] : 0;
  int s = v;
  #pragma unroll
  for (int d = 1; d < 64; d <<= 1) { int u = __shfl_up(s, d); if (lane >= d) s += u; }
  if (lane == 63) wsum[w] = s;
  __syncthreads();
  if (w == 0 && lane < 16) {
    int ws = wsum[lane];
    #pragma unroll
    for (int d = 1; d < 16; d <<= 1) { int u = __shfl_up(ws, d); if (lane >= d) ws += u; }
    wsum[lane] = ws;
  }
  __syncthreads();
  int inc = ((w > 0) ? wsum[w - 1] : 0) + s;
  if (idx < n) off[idx + 1] = inc;
  if (t == 1023) bsum[blockIdx.x] = inc;
}

__global__ void scan2_kernel(int* __restrict__ bsum, int nb, const int* __restrict__ rolecnt,
                             int* __restrict__ rolefill, int* __restrict__ roleinfo)
{
  int lane = threadIdx.x;
  int carry = 0;
  for (int base = 0; base < nb; base += 64) {
    int v = (base + lane < nb) ? bsum[base + lane] : 0;
    int s = v;
    #pragma unroll
    for (int d = 1; d < 64; d <<= 1) { int u = __shfl_up(s, d); if (lane >= d) s += u; }
    if (base + lane < nb) bsum[base + lane] = carry + s - v;
    carry += __shfl(s, 63);
  }
  if (lane == 0) {
    int c0 = rolecnt[0], c1 = rolecnt[1], c2 = rolecnt[2];
    int s1 = (c0 + 255) & ~255;
    int s2 = s1 + ((c1 + 255) & ~255);
    int mp = s2 + ((c2 + 255) & ~255);
    rolefill[0] = 0; rolefill[1] = s1; rolefill[2] = s2;
    roleinfo[0] = s1; roleinfo[1] = s2;
    roleinfo[2] = c0;      roleinfo[3] = s1 - c0;
    roleinfo[4] = s1 + c1; roleinfo[5] = s2 - s1 - c1;
    roleinfo[6] = s2 + c2; roleinfo[7] = mp - s2 - c2;
  }
}

__global__ __launch_bounds__(1024) void scan3_kernel(int* __restrict__ off, int* __restrict__ fill,
                                                     const int* __restrict__ bsum, int n)
{
  int idx = blockIdx.x * 1024 + threadIdx.x;
  if (idx == 0) { off[0] = 0; fill[0] = 0; }
  if (idx < n) {
    int v = off[idx + 1] + bsum[blockIdx.x];
    off[idx + 1] = v;
    if (idx + 1 < n) fill[idx + 1] = v;
  }
}

// bucketfill[b] = off3[3 * min(b*W, N)]
__global__ void bucketinit_kernel(const int* __restrict__ off3, int* __restrict__ bucketfill,
                                  int NB, int W, int N)
{
  int b = blockIdx.x * 256 + threadIdx.x;
  if (b < NB) {
    int d = min(b * W, N);
    bucketfill[b] = off3[d * 3];
  }
}

// stage 1: partition edges into dst-range buckets; records = (bin, t)
__global__ __launch_bounds__(256) void partition_kernel(
    const int* __restrict__ ei, const int* __restrict__ spos,
    const int* __restrict__ roleinfo, int* __restrict__ bucketfill,
    int2* __restrict__ recs, int E, int N, int shiftB)
{
  __shared__ int lcnt[256], lbase[256];
  const int base = blockIdx.x * 4096;
  const int s1 = roleinfo[0], s2 = roleinfo[1];
  lcnt[threadIdx.x] = 0;
  __syncthreads();
  int myb[16], mybin[16], myt[16];
  #pragma unroll
  for (int k = 0; k < 16; ++k) {
    int i = base + k * 256 + threadIdx.x;
    myb[k] = -1;
    if (i < E + N) {
      int src, dst;
      if (i < E) { src = ei[i]; dst = ei[E + i]; } else { src = i - E; dst = i - E; }
      int t = spos[src];
      int r = (t >= s2) ? 2 : (t >= s1) ? 1 : 0;
      myb[k] = dst >> shiftB;
      mybin[k] = dst * 3 + r;
      myt[k] = t;
      atomicAdd(&lcnt[myb[k]], 1);
    }
  }
  __syncthreads();
  int c = lcnt[threadIdx.x];
  lbase[threadIdx.x] = (c > 0) ? atomicAdd(&bucketfill[threadIdx.x], c) : 0;
  __syncthreads();
  lcnt[threadIdx.x] = 0;          // reuse as per-bucket cursor
  __syncthreads();
  #pragma unroll
  for (int k = 0; k < 16; ++k) {
    if (myb[k] >= 0) {
      int slot = atomicAdd(&lcnt[myb[k]], 1);
      recs[lbase[myb[k]] + slot] = make_int2(mybin[k], myt[k]);
    }
  }
}

// stage 2: replay one bucket per WG; ssrc writes confined to the bucket's slice
__global__ __launch_bounds__(1024) void binscatter_kernel(
    const int2* __restrict__ recs, const int* __restrict__ off3,
    int* __restrict__ fill3, int* __restrict__ ssrc, int W, int N)
{
  int b = blockIdx.x;
  int d0 = min(b * W, N), d1 = min((b + 1) * W, N);
  int s = off3[d0 * 3], e = off3[d1 * 3];
  for (int i = s + threadIdx.x; i < e; i += 1024) {
    int2 rec = recs[i];
    int pz = atomicAdd(&fill3[rec.x], 1);
    ssrc[pz] = rec.y;
  }
}

__global__ __launch_bounds__(256) void permscatter_kernel(const int* __restrict__ role, int* __restrict__ rolefill,
                                                          int* __restrict__ spos, int* __restrict__ sposinv, int N)
{
  int i = blockIdx.x * 256 + threadIdx.x;
  int lane = threadIdx.x & 63;
  int r = (i < N) ? role[i] : -1;
  #pragma unroll
  for (int rr = 0; rr < 3; ++rr) {
    unsigned long long mask = __ballot(r == rr);
    if (!mask) continue;
    int base = 0;
    if (lane == 0) base = atomicAdd(&rolefill[rr], __popcll(mask));
    base = __shfl(base, 0);
    if (r == rr) {
      int rank = (int)__popcll(mask & ((1ull << lane) - 1ull));
      int pos = base + rank;
      spos[i] = pos;
      sposinv[pos] = i;
    }
  }
}

__global__ __launch_bounds__(256) void zeropad_kernel(const int* __restrict__ roleinfo,
                                                      bf16* __restrict__ Ax, bf16* __restrict__ Ah)
{
  int id = blockIdx.x * 256 + threadIdx.x;   // 98304
  int a = id / 49152, rem = id % 49152;
  int gp = rem / 16384, r2 = rem % 16384;
  int rr = r2 >> 6, c = r2 & 63;
  int gs = roleinfo[2 + gp * 2], gl = roleinfo[3 + gp * 2];
  if (rr < gl) {
    int row = gs + rr;
    size_t unit = (size_t)(row >> 4) * 1024 + c * 16 + (row & 15);
    bf16x8 z = {};
    ((bf16x8*)(a == 0 ? Ax : Ah))[unit] = z;
  }
}

// ---------------- prep ----------------
__global__ __launch_bounds__(256) void prep_xh_kernel(const float* __restrict__ x, const float* __restrict__ h,
                                                      const int* __restrict__ spos, u8* __restrict__ xq8,
                                                      bf16* __restrict__ Ax, bf16* __restrict__ Ah, int N)
{
  int g = blockIdx.x * 256 + threadIdx.x;
  if (g >= N * 32) return;
  int n = g >> 5, j = g & 31;
  int t = spos[n];
  const float* src = (j < 16) ? (x + (size_t)n * 128 + (j << 3))
                              : (h + (size_t)n * 128 + ((j - 16) << 3));
  float4 v0 = ((const float4*)src)[0];
  float4 v1 = ((const float4*)src)[1];
  int lo = __builtin_amdgcn_cvt_pk_fp8_f32(v0.x, v0.y, 0, false);
  lo = __builtin_amdgcn_cvt_pk_fp8_f32(v0.z, v0.w, lo, true);
  int hi = __builtin_amdgcn_cvt_pk_fp8_f32(v1.x, v1.y, 0, false);
  hi = __builtin_amdgcn_cvt_pk_fp8_f32(v1.z, v1.w, hi, true);
  *(int2*)(xq8 + (size_t)t * 256 + j * 8) = make_int2(lo, hi);
  bf16x8 o;
  o[0] = (bf16)v0.x; o[1] = (bf16)v0.y; o[2] = (bf16)v0.z; o[3] = (bf16)v0.w;
  o[4] = (bf16)v1.x; o[5] = (bf16)v1.y; o[6] = (bf16)v1.z; o[7] = (bf16)v1.w;
  size_t unit = (size_t)(t >> 4) * 1024 + (48 + (j & 15)) * 16 + (t & 15);
  ((bf16x8*)(j < 16 ? Ax : Ah))[unit] = o;
}

struct PrepW { const float* W[6]; const float* Wg[6]; const float* bg[6]; };
__global__ __launch_bounds__(256) void prep_wf_kernel(PrepW pw, bf16* __restrict__ Wf)
{
  int idx = blockIdx.x * 256 + threadIdx.x;
  if (idx >= 294912) return;
  int cv = idx / 49152, pos = idx % 49152;
  int ks4q = pos >> 10;
  int col = (pos >> 3) & 127, j = pos & 7;
  int k = (ks4q >> 2) * 32 + (ks4q & 3) * 8 + j;
  int r = k >> 7, kk = k & 127;
  float g = sigmoidf_(pw.Wg[cv][r * 128 + col] + pw.bg[cv][r * 128 + col]);
  Wf[idx] = (bf16)(pw.W[cv][kk * 128 + col] * g);
}

struct PrepP { const float* W[6]; const float* S[6]; };
__global__ __launch_bounds__(128) void prep_pf_kernel(PrepP pp, bf16* __restrict__ Pf)
{
  int b = blockIdx.x;                          // 6*3*128
  int cv = b / 384, rem = b % 384;
  int r = rem >> 7, kp = rem & 127;
  int col = threadIdx.x;
  const float* W = pp.W[cv] + (size_t)kp * 128;
  const float* S = pp.S[cv] + (size_t)r * 16384;
  float sum = 0.f;
  #pragma unroll 4
  for (int j2 = 0; j2 < 128; ++j2) sum += W[j2] * S[j2 * 128 + col];
  size_t o = (size_t)(cv * 3 + r) * 16384 + ((size_t)(kp >> 3) * 128 + col) * 8 + (kp & 7);
  Pf[o] = (bf16)sum;
}

// ---------------- gathers (t-ordered 8-node blocks, cooperative full-line NT writes) ----------------
#define ACCUM16(U, d) do { f32x2 f_;                                                   \
  f_ = __builtin_amdgcn_cvt_pk_f32_fp8((d).x, false); U[0]  += f_[0]; U[1]  += f_[1];  \
  f_ = __builtin_amdgcn_cvt_pk_f32_fp8((d).x, true);  U[2]  += f_[0]; U[3]  += f_[1];  \
  f_ = __builtin_amdgcn_cvt_pk_f32_fp8((d).y, false); U[4]  += f_[0]; U[5]  += f_[1];  \
  f_ = __builtin_amdgcn_cvt_pk_f32_fp8((d).y, true);  U[6]  += f_[0]; U[7]  += f_[1];  \
  f_ = __builtin_amdgcn_cvt_pk_f32_fp8((d).z, false); U[8]  += f_[0]; U[9]  += f_[1];  \
  f_ = __builtin_amdgcn_cvt_pk_f32_fp8((d).z, true);  U[10] += f_[0]; U[11] += f_[1];  \
  f_ = __builtin_amdgcn_cvt_pk_f32_fp8((d).w, false); U[12] += f_[0]; U[13] += f_[1];  \
  f_ = __builtin_amdgcn_cvt_pk_f32_fp8((d).w, true);  U[14] += f_[0]; U[15] += f_[1];  \
} while (0)

#define ACCSEL16(d, p) do {                      \
  if ((p) < o1)      { ACCUM16(u0, d); }         \
  else if ((p) < o2) { ACCUM16(u1, d); }         \
  else               { ACCUM16(u2, d); }         \
} while (0)

__global__ __launch_bounds__(512) void gather_xh_kernel(
    const u8* __restrict__ xq8, const int* __restrict__ off3, const int* __restrict__ ssrc,
    const int* __restrict__ sposinv, bf16* __restrict__ Ax, bf16* __restrict__ Ah,
    float4* __restrict__ cntf)
{
  __shared__ alignas(16) bf16 lds[8][768];
  int w = threadIdx.x >> 6, lane = threadIdx.x & 63;
  int t0 = blockIdx.x * 8;
  int t = t0 + w;
  int node = sposinv[t];                 // -1 for pad rows
  int qt = lane >> 4, ql = lane & 15;

  if (node >= 0) {
    int o0 = __builtin_amdgcn_readfirstlane(off3[node * 3]);
    int o1 = __builtin_amdgcn_readfirstlane(off3[node * 3 + 1]);
    int o2 = __builtin_amdgcn_readfirstlane(off3[node * 3 + 2]);
    int o3 = __builtin_amdgcn_readfirstlane(off3[node * 3 + 3]);
    float inv = 1.0f / (float)(o3 - o0);
    const u8* base = xq8 + ql * 16;

    float u0[16], u1[16], u2[16];
    #pragma unroll
    for (int k = 0; k < 16; ++k) { u0[k] = 0.f; u1[k] = 0.f; u2[k] = 0.f; }

    const int e = o3, emax = o3 - 1;
    for (int i = o0; i < e; i += 16) {
      int p0 = i + qt, p1 = p0 + 4, p2 = p0 + 8, p3 = p0 + 12;
      int t0i = ssrc[min(p0, emax)];
      int t1i = ssrc[min(p1, emax)];
      int t2i = ssrc[min(p2, emax)];
      int t3i = ssrc[min(p3, emax)];
      int4 d0 = make_int4(0, 0, 0, 0), d1 = d0, d2 = d0, d3 = d0;
      if (p0 < e) d0 = *(const int4*)(base + (size_t)t0i * 256);
      if (p1 < e) d1 = *(const int4*)(base + (size_t)t1i * 256);
      if (p2 < e) d2 = *(const int4*)(base + (size_t)t2i * 256);
      if (p3 < e) d3 = *(const int4*)(base + (size_t)t3i * 256);
      ACCSEL16(d0, p0);
      ACCSEL16(d1, p1);
      ACCSEL16(d2, p2);
      ACCSEL16(d3, p3);
    }

    #pragma unroll
    for (int k = 0; k < 16; ++k) {
      u0[k] += __shfl_xor(u0[k], 16); u0[k] += __shfl_xor(u0[k], 32);
      u1[k] += __shfl_xor(u1[k], 16); u1[k] += __shfl_xor(u1[k], 32);
      u2[k] += __shfl_xor(u2[k], 16); u2[k] += __shfl_xor(u2[k], 32);
    }
    if (qt == 0) {
      bf16x8 p0v, p1v;
      int sb0 = (ql < 8) ? (ql * 16) : (384 + (ql - 8) * 16);
      #pragma unroll
      for (int k = 0; k < 8; ++k) { p0v[k] = (bf16)(u0[k] * inv); p1v[k] = (bf16)(u0[8 + k] * inv); }
      *(bf16x8*)&lds[w][sb0] = p0v;
      *(bf16x8*)&lds[w][sb0 + 8] = p1v;
      #pragma unroll
      for (int k = 0; k < 8; ++k) { p0v[k] = (bf16)(u1[k] * inv); p1v[k] = (bf16)(u1[8 + k] * inv); }
      *(bf16x8*)&lds[w][sb0 + 128] = p0v;
      *(bf16x8*)&lds[w][sb0 + 136] = p1v;
      #pragma unroll
      for (int k = 0; k < 8; ++k) { p0v[k] = (bf16)(u2[k] * inv); p1v[k] = (bf16)(u2[8 + k] * inv); }
      *(bf16x8*)&lds[w][sb0 + 256] = p0v;
      *(bf16x8*)&lds[w][sb0 + 264] = p1v;
    }
    if (lane == 0)
      cntf[t] = make_float4((o1 - o0) * inv, (o2 - o1) * inv, (o3 - o2) * inv, (float)(o3 - o0));
  } else {
    // pad row: zero-fill this wave's LDS section so the cooperative write stores zeros
    if (lane < 48) {
      bf16x8 z = {};
      *(bf16x8*)&lds[w][lane * 16] = z;
      *(bf16x8*)&lds[w][lane * 16 + 8] = z;
    }
    if (lane == 0) cntf[t] = make_float4(0.f, 0.f, 0.f, 0.f);
  }

  __syncthreads();

  // cooperative write: 8 consecutive rows (t0..t0+7, same 16-group) -> full 128-B lines
  int tid = threadIdx.x;
  if (tid < 384) {
    int lc = tid >> 3, row = tid & 7;
    size_t unit = (size_t)(t0 >> 4) * 1024 + lc * 16 + (t0 & 15) + row;
    __builtin_nontemporal_store(*(const bf16x8*)&lds[row][lc * 8], (bf16x8*)Ax + unit);
    __builtin_nontemporal_store(*(const bf16x8*)&lds[row][384 + lc * 8], (bf16x8*)Ah + unit);
  }
}

#define ACCUM8(U, d) do { f32x2 f_;                                                  \
  f_ = __builtin_amdgcn_cvt_pk_f32_fp8((d).x, false); U[0] += f_[0]; U[1] += f_[1];  \
  f_ = __builtin_amdgcn_cvt_pk_f32_fp8((d).x, true);  U[2] += f_[0]; U[3] += f_[1];  \
  f_ = __builtin_amdgcn_cvt_pk_f32_fp8((d).y, false); U[4] += f_[0]; U[5] += f_[1];  \
  f_ = __builtin_amdgcn_cvt_pk_f32_fp8((d).y, true);  U[6] += f_[0]; U[7] += f_[1];  \
} while (0)

#define ACCSEL8(d, p) do {                      \
  if ((p) < o1)      { ACCUM8(v0, d); }         \
  else if ((p) < o2) { ACCUM8(v1, d); }         \
  else               { ACCUM8(v2, d); }         \
} while (0)

__global__ __launch_bounds__(512) void gather_q_kernel(
    const u8* __restrict__ q8, const int* __restrict__ off3, const int* __restrict__ ssrc,
    const int* __restrict__ sposinv, bf16* __restrict__ Aq)
{
  __shared__ alignas(16) bf16 lds[8][384];
  int w = threadIdx.x >> 6, lane = threadIdx.x & 63;
  int t0 = blockIdx.x * 8;
  int t = t0 + w;
  int node = sposinv[t];
  int qt = lane >> 4, ql = lane & 15;

  if (node >= 0) {
    int o0 = __builtin_amdgcn_readfirstlane(off3[node * 3]);
    int o1 = __builtin_amdgcn_readfirstlane(off3[node * 3 + 1]);
    int o2 = __builtin_amdgcn_readfirstlane(off3[node * 3 + 2]);
    int o3 = __builtin_amdgcn_readfirstlane(off3[node * 3 + 3]);
    float inv = 1.0f / (float)(o3 - o0);
    const u8* base = q8 + ql * 8;

    float v0[8], v1[8], v2[8];
    #pragma unroll
    for (int k = 0; k < 8; ++k) { v0[k] = 0.f; v1[k] = 0.f; v2[k] = 0.f; }

    const int e = o3, emax = o3 - 1;
    for (int i = o0; i < e; i += 16) {
      int p0 = i + qt, p1 = p0 + 4, p2 = p0 + 8, p3 = p0 + 12;
      int t0i = ssrc[min(p0, emax)];
      int t1i = ssrc[min(p1, emax)];
      int t2i = ssrc[min(p2, emax)];
      int t3i = ssrc[min(p3, emax)];
      int2 d0 = make_int2(0, 0), d1 = d0, d2 = d0, d3 = d0;
      if (p0 < e) d0 = *(const int2*)(base + (size_t)t0i * 128);
      if (p1 < e) d1 = *(const int2*)(base + (size_t)t1i * 128);
      if (p2 < e) d2 = *(const int2*)(base + (size_t)t2i * 128);
      if (p3 < e) d3 = *(const int2*)(base + (size_t)t3i * 128);
      ACCSEL8(d0, p0);
      ACCSEL8(d1, p1);
      ACCSEL8(d2, p2);
      ACCSEL8(d3, p3);
    }

    #pragma unroll
    for (int k = 0; k < 8; ++k) {
      v0[k] += __shfl_xor(v0[k], 16); v0[k] += __shfl_xor(v0[k], 32);
      v1[k] += __shfl_xor(v1[k], 16); v1[k] += __shfl_xor(v1[k], 32);
      v2[k] += __shfl_xor(v2[k], 16); v2[k] += __shfl_xor(v2[k], 32);
    }
    if (qt == 0) {
      bf16x8 pk;
      #pragma unroll
      for (int k = 0; k < 8; ++k) pk[k] = (bf16)(v0[k] * inv);
      *(bf16x8*)&lds[w][ql * 8] = pk;
      #pragma unroll
      for (int k = 0; k < 8; ++k) pk[k] = (bf16)(v1[k] * inv);
      *(bf16x8*)&lds[w][128 + ql * 8] = pk;
      #pragma unroll
      for (int k = 0; k < 8; ++k) pk[k] = (bf16)(v2[k] * inv);
      *(bf16x8*)&lds[w][256 + ql * 8] = pk;
    }
  } else {
    if (lane < 48) {
      bf16x8 z = {};
      *(bf16x8*)&lds[w][lane * 8] = z;
    }
  }

  __syncthreads();

  int tid = threadIdx.x;
  if (tid < 384) {
    int lc = tid >> 3, row = tid & 7;
    size_t unit = (size_t)(t0 >> 4) * 1024 + lc * 16 + (t0 & 15) + row;
    __builtin_nontemporal_store(*(const bf16x8*)&lds[row][lc * 8], (bf16x8*)Aq + unit);
  }
}

// ---------------- streaming MFMA GEMM (no LDS/barriers; 2 row-blocks per wave, 3 waves/SIMD) ----------------
struct GArgs {
  const bf16* Ap[5];
  const bf16* wf[5];
  const bf16* pf[5];
  bf16* out[5];
  const float* bias[5];
};

__global__ __launch_bounds__(256, 3) void gemm_kernel(GArgs ga, const float4* __restrict__ cntf,
                                                      const int* __restrict__ roleinfo)
{
  const int cv = blockIdx.y;
  const bf16* __restrict__ Ap = ga.Ap[cv];
  const bf16* __restrict__ wf = ga.wf[cv];
  const bf16* __restrict__ pf = ga.pf[cv];
  bf16* __restrict__ out = ga.out[cv];
  const float* __restrict__ bias = ga.bias[cv];

  const int w = threadIdx.x >> 6, lane = threadIdx.x & 63;
  const int q = lane >> 4, l = lane & 15;
  const int rb0 = blockIdx.x * 8 + w * 2;
  const int row0 = blockIdx.x * 128;
  const int s1 = roleinfo[0], s2 = roleinfo[1];
  const int role = (row0 >= s2) ? 2 : (row0 >= s1) ? 1 : 0;
  const int laneoff = q * 128 + l;

  f32x4 acc[2][8];
  #pragma unroll
  for (int j = 0; j < 2; ++j)
    #pragma unroll
    for (int ct = 0; ct < 8; ++ct)
      #pragma unroll
      for (int k = 0; k < 4; ++k) acc[j][ct][k] = 0.f;

  const bf16x8* A0 = (const bf16x8*)Ap + (size_t)rb0 * 1024 + lane;
  const bf16x8* WF = (const bf16x8*)wf + laneoff;
  const bf16x8* PF = (const bf16x8*)pf + role * 2048 + laneoff;

  #pragma unroll 2
  for (int ks = 0; ks < 16; ++ks) {
    const bf16x8* bp = (ks < 12) ? (WF + ks * 512) : (PF + (ks - 12) * 512);
    bf16x8 a0 = A0[ks * 64];
    bf16x8 a1 = A0[1024 + ks * 64];
    #pragma unroll
    for (int ct = 0; ct < 8; ++ct) {
      bf16x8 b = bp[ct * 16];
      acc[0][ct] = __builtin_amdgcn_mfma_f32_16x16x32_bf16(a0, b, acc[0][ct], 0, 0, 0);
      acc[1][ct] = __builtin_amdgcn_mfma_f32_16x16x32_bf16(a1, b, acc[1][ct], 0, 0, 0);
    }
  }

  const bool hb = (bias != nullptr);
  #pragma unroll
  for (int j = 0; j < 2; ++j) {
    int rb = rb0 + j;
    float4 cfs[4];
    if (hb) {
      #pragma unroll
      for (int reg = 0; reg < 4; ++reg) cfs[reg] = cntf[rb * 16 + q * 4 + reg];
    }
    #pragma unroll
    for (int ct = 0; ct < 8; ++ct) {
      int col = ct * 16 + l;
      float b0 = 0, b1 = 0, b2 = 0;
      if (hb) { b0 = bias[col]; b1 = bias[128 + col]; b2 = bias[256 + col]; }
      #pragma unroll
      for (int reg = 0; reg < 4; ++reg) {
        int t = rb * 16 + q * 4 + reg;
        float v = acc[j][ct][reg];
        if (hb) v += cfs[reg].x * b0 + cfs[reg].y * b1 + cfs[reg].z * b2;
        out[(size_t)t * 128 + col] = (bf16)fmaxf(v, 0.f);
      }
    }
  }
}

// ---------------- combines ----------------
__global__ __launch_bounds__(256) void combine1_kernel(
    const bf16* __restrict__ o0, const bf16* __restrict__ o1,
    const bf16* __restrict__ o2, const bf16* __restrict__ o3,
    const float* __restrict__ h, const int* __restrict__ spos,
    float* __restrict__ zbuf, u8* __restrict__ q8, bf16* __restrict__ Aq, int N)
{
  int g = blockIdx.x * 256 + threadIdx.x;
  if (g >= N * 16) return;
  int n = g >> 4, o = g & 15;
  int t = spos[n];
  size_t tb = (size_t)t * 16 + o;
  bf16x8 a0 = ((const bf16x8*)o0)[tb];
  bf16x8 a1 = ((const bf16x8*)o1)[tb];
  bf16x8 a2 = ((const bf16x8*)o2)[tb];
  bf16x8 a3 = ((const bf16x8*)o3)[tb];
  size_t nb = (size_t)n * 16 + o;
  float4 h0 = ((const float4*)h)[nb * 2];
  float4 h1 = ((const float4*)h)[nb * 2 + 1];
  float hv[8] = {h0.x, h0.y, h0.z, h0.w, h1.x, h1.y, h1.z, h1.w};
  float zv[8], qv[8];
  bf16x8 qb;
  #pragma unroll
  for (int j = 0; j < 8; ++j) {
    zv[j] = sigmoidf_((float)a0[j] + (float)a1[j]);
    qv[j] = sigmoidf_((float)a2[j] + (float)a3[j]) * hv[j];
    qb[j] = (bf16)qv[j];
  }
  ((float4*)zbuf)[nb * 2]     = make_float4(zv[0], zv[1], zv[2], zv[3]);
  ((float4*)zbuf)[nb * 2 + 1] = make_float4(zv[4], zv[5], zv[6], zv[7]);
  int lo = __builtin_amdgcn_cvt_pk_fp8_f32(qv[0], qv[1], 0, false);
  lo = __builtin_amdgcn_cvt_pk_fp8_f32(qv[2], qv[3], lo, true);
  int hi = __builtin_amdgcn_cvt_pk_fp8_f32(qv[4], qv[5], 0, false);
  hi = __builtin_amdgcn_cvt_pk_fp8_f32(qv[6], qv[7], hi, true);
  *(int2*)(q8 + (size_t)t * 128 + o * 8) = make_int2(lo, hi);
  size_t unit = (size_t)(t >> 4) * 1024 + (48 + o) * 16 + (t & 15);
  ((bf16x8*)Aq)[unit] = qb;
}

__global__ __launch_bounds__(256) void combine2_kernel(
    const float* __restrict__ zbuf, const bf16* __restrict__ o4, const bf16* __restrict__ o5,
    const float* __restrict__ h, const int* __restrict__ spos, float* __restrict__ out, int N)
{
  int g = blockIdx.x * 256 + threadIdx.x;
  if (g >= N * 16) return;
  int n = g >> 4, o = g & 15;
  int t = spos[n];
  size_t tb = (size_t)t * 16 + o;
  bf16x8 a = ((const bf16x8*)o4)[tb];
  bf16x8 b = ((const bf16x8*)o5)[tb];
  size_t nb = (size_t)n * 16 + o;
  float4 z0 = ((const float4*)zbuf)[nb * 2];
  float4 z1 = ((const float4*)zbuf)[nb * 2 + 1];
  float4 h0 = ((const float4*)h)[nb * 2];
  float4 h1 = ((const float4*)h)[nb * 2 + 1];
  float zv[8] = {z0.x, z0.y, z0.z, z0.w, z1.x, z1.y, z1.z, z1.w};
  float hv[8] = {h0.x, h0.y, h0.z, h0.w, h1.x, h1.y, h1.z, h1.w};
  float ov[8];
  #pragma unroll
  for (int j = 0; j < 8; ++j)
    ov[j] = zv[j] * hv[j] + (1.f - zv[j]) * tanhf((float)a[j] + (float)b[j]);
  ((float4*)out)[nb * 2]     = make_float4(ov[0], ov[1], ov[2], ov[3]);
  ((float4*)out)[nb * 2 + 1] = make_float4(ov[4], ov[5], ov[6], ov[7]);
}

// ---------------- host ----------------
extern "C" void kernel_launch(void* const* d_in, const int* in_sizes, int n_in,
                              void* d_out, int out_size, void* d_ws, size_t ws_size,
                              hipStream_t stream)
{
  (void)n_in; (void)out_size; (void)ws_size;
  const float* x    = (const float*)d_in[0];
  const float* h    = (const float*)d_in[1];
  const int*   ei   = (const int*)d_in[2];
  const int*   role = (const int*)d_in[3];
  const int N = in_sizes[0] / DH;
  const int E = in_sizes[2] / 2;
  const int Etot = E + N;
  const int rows_pad = ((N + 765) + 255) & ~255;
  const int gx = rows_pad / 128;
  const int n3 = N * 3;
  const int nb3 = (n3 + 1023) / 1024;

  // bucket geometry: <=256 buckets of W=2^shiftB dst rows
  int shiftB = 8;
  while (((N - 1) >> shiftB) >= 256) ++shiftB;
  const int W = 1 << shiftB;
  const int NB = (N + W - 1) >> shiftB;

  // conv order: 0 xz, 1 hz, 2 xr, 3 hr, 4 xh, 5 hh
  static const int Wi[6]  = {4, 9, 13, 18, 22, 27};
  static const int Wgi[6] = {5, 10, 14, 19, 23, 28};
  static const int bgi[6] = {6, 11, 15, 20, 24, 29};
  static const int Si[6]  = {7, 12, 16, 21, 25, 30};

  char* p = (char*)d_ws;
  auto alloc = [&](size_t bytes) -> char* {
    char* r = p;
    p += (bytes + 255) & ~(size_t)255;
    return r;
  };

  bf16* Ax = (bf16*)alloc((size_t)rows_pad * 512 * 2);   // Aq aliases Ax
  bf16* Ah = (bf16*)alloc((size_t)rows_pad * 512 * 2);
  bf16* Aq = Ax;
  u8* xq8  = (u8*)alloc((size_t)rows_pad * 256);
  u8* q8   = (u8*)alloc((size_t)rows_pad * 128);
  bf16* outs[6];
  for (int c = 0; c < 5; ++c) outs[c] = (bf16*)alloc((size_t)rows_pad * 128 * 2);
  outs[5] = outs[0];
  float* zbuf = (float*)alloc((size_t)N * 128 * 4);
  float4* cntf = (float4*)alloc((size_t)rows_pad * 16);
  bf16* Wf = (bf16*)alloc((size_t)6 * 49152 * 2);
  bf16* Pf = (bf16*)alloc((size_t)18 * 16384 * 2);
  int* cnt3  = (int*)alloc((size_t)n3 * 4);
  int* off3  = (int*)alloc((size_t)(n3 + 1) * 4);
  int* fill3 = (int*)alloc((size_t)n3 * 4);
  int* bsum  = (int*)alloc((size_t)(nb3 + 1) * 4);
  int* ssrc  = (int*)alloc((size_t)Etot * 4);
  int2* recs = (int2*)alloc((size_t)Etot * 8);
  int* spos  = (int*)alloc((size_t)N * 4);
  int* sposinv = (int*)alloc((size_t)rows_pad * 4);
  int* rolecnt  = (int*)alloc(64);
  int* rolefill = (int*)alloc(64);
  int* roleinfo = (int*)alloc(64);
  int* bucketfill = (int*)alloc((size_t)(NB + 1) * 4);

  hipMemsetAsync(cnt3, 0, (size_t)n3 * 4, stream);
  hipMemsetAsync(rolecnt, 0, 16, stream);
  hipMemsetAsync(sposinv, 0xFF, (size_t)rows_pad * 4, stream);   // -1 = pad row

  int egrid = (Etot + 255) / 256;
  int ngrid = (N + 255) / 256;
  hist_kernel<<<egrid, 256, 0, stream>>>(ei, role, cnt3, rolecnt, E, N);
  scan1_kernel<<<nb3, 1024, 0, stream>>>(cnt3, off3, bsum, n3);
  scan2_kernel<<<1, 64, 0, stream>>>(bsum, nb3, rolecnt, rolefill, roleinfo);
  scan3_kernel<<<nb3, 1024, 0, stream>>>(off3, fill3, bsum, n3);
  permscatter_kernel<<<ngrid, 256, 0, stream>>>(role, rolefill, spos, sposinv, N);
  bucketinit_kernel<<<1, 256, 0, stream>>>(off3, bucketfill, NB, W, N);
  partition_kernel<<<(Etot + 4095) / 4096, 256, 0, stream>>>(ei, spos, roleinfo, bucketfill,
                                                             recs, E, N, shiftB);
  binscatter_kernel<<<NB, 1024, 0, stream>>>(recs, off3, fill3, ssrc, W, N);
  zeropad_kernel<<<384, 256, 0, stream>>>(roleinfo, Ax, Ah);

  prep_xh_kernel<<<(N * 32 + 255) / 256, 256, 0, stream>>>(x, h, spos, xq8, Ax, Ah, N);

  PrepW pw;
  for (int c = 0; c < 6; ++c) {
    pw.W[c] = (const float*)d_in[Wi[c]];
    pw.Wg[c] = (const float*)d_in[Wgi[c]];
    pw.bg[c] = (const float*)d_in[bgi[c]];
  }
  prep_wf_kernel<<<1152, 256, 0, stream>>>(pw, Wf);
  PrepP pp;
  for (int c = 0; c < 6; ++c) { pp.W[c] = (const float*)d_in[Wi[c]]; pp.S[c] = (const float*)d_in[Si[c]]; }
  prep_pf_kernel<<<2304, 128, 0, stream>>>(pp, Pf);

  gather_xh_kernel<<<rows_pad / 8, 512, 0, stream>>>(xq8, off3, ssrc, sposinv, Ax, Ah, cntf);

  // pass 1: one dispatch, cv 0..4 = {xz,xr,xh on Ax (bias)} + {hz,hr on Ah}
  GArgs g0;
  { int cvs[5] = {0, 2, 4, 1, 3};
    static const int bi2[5] = {8, 17, 26, -1, -1};
    const bf16* Apts[5] = {Ax, Ax, Ax, Ah, Ah};
    for (int k = 0; k < 5; ++k) {
      int c = cvs[k];
      g0.Ap[k] = Apts[k];
      g0.wf[k] = Wf + (size_t)c * 49152;
      g0.pf[k] = Pf + (size_t)c * 3 * 16384;
      g0.out[k] = outs[c];
      g0.bias[k] = (bi2[k] >= 0) ? (const float*)d_in[bi2[k]] : nullptr;
    } }
  gemm_kernel<<<dim3(gx, 5), 256, 0, stream>>>(g0, cntf, roleinfo);

  combine1_kernel<<<(N * 16 + 255) / 256, 256, 0, stream>>>(outs[0], outs[1], outs[2], outs[3],
                                                            h, spos, zbuf, q8, Aq, N);

  gather_q_kernel<<<rows_pad / 8, 512, 0, stream>>>(q8, off3, ssrc, sposinv, Aq);

  // pass 2: conv hh(5) on Aq
  GArgs g2 = {};
  g2.Ap[0] = Aq;
  g2.wf[0] = Wf + (size_t)5 * 49152;
  g2.pf[0] = Pf + (size_t)5 * 3 * 16384;
  g2.out[0] = outs[5];
  g2.bias[0] = nullptr;
  gemm_kernel<<<dim3(gx, 1), 256, 0, stream>>>(g2, cntf, roleinfo);

  combine2_kernel<<<(N * 16 + 255) / 256, 256, 0, stream>>>(zbuf, outs[4], outs[5], h, spos,
                                                            (float*)d_out, N);
}

// Round 10
// 611.252 us; speedup vs baseline: 1.9006x; 1.1163x over previous
//
#include <hip/hip_runtime.h>

// GraphGRU on MI355X — round 16.
//   CSR build restructured bucket-locally (gather-side levers exhausted at ~108 µs):
//   - hist_kernel's 1.7M device-scope random atomics on cnt3 ELIMINATED, along with
//     scan1/scan3 (150K-bin passes), bucketinit, cnt3/fill3.
//   - new: rolecnt (N-scale ballot) + roleinfo (1-thread), coarsehist (256-bin LDS bucket
//     counts), bucketscan (1-block scan -> bucketbase/bucketfill), binscatter v2 (per-bucket
//     LDS 768-bin histogram + scan; writes its off3 slice = bucketbase[b]+excl; scatters ssrc
//     via LDS cursors). off3 semantics identical; within-bin ssrc order changes (sums are
//     order-independent).
//   Gathers/GEMM/combines byte-identical to round-15 (682.3 µs verified).

typedef __bf16 bf16;
typedef __bf16 bf16x8 __attribute__((ext_vector_type(8)));
typedef float  f32x4  __attribute__((ext_vector_type(4)));
typedef float  f32x2  __attribute__((ext_vector_type(2)));
typedef unsigned char u8;

#define DH 128

__device__ __forceinline__ float sigmoidf_(float x) { return 1.0f / (1.0f + expf(-x)); }

// ---------------- CSR build (bucket-local) ----------------
__global__ __launch_bounds__(256) void rolecnt_kernel(const int* __restrict__ role,
                                                      int* __restrict__ rolecnt, int N)
{
  int i = blockIdx.x * 256 + threadIdx.x;
  int lane = threadIdx.x & 63;
  int r = (i < N) ? role[i] : -1;
  #pragma unroll
  for (int rr = 0; rr < 3; ++rr) {
    unsigned long long mask = __ballot(r == rr);
    if (lane == 0 && mask) atomicAdd(&rolecnt[rr], __popcll(mask));
  }
}

__global__ void roleinfo_kernel(const int* __restrict__ rolecnt,
                                int* __restrict__ rolefill, int* __restrict__ roleinfo)
{
  if (threadIdx.x == 0) {
    int c0 = rolecnt[0], c1 = rolecnt[1], c2 = rolecnt[2];
    int s1 = (c0 + 255) & ~255;
    int s2 = s1 + ((c1 + 255) & ~255);
    int mp = s2 + ((c2 + 255) & ~255);
    rolefill[0] = 0; rolefill[1] = s1; rolefill[2] = s2;
    roleinfo[0] = s1; roleinfo[1] = s2;
    roleinfo[2] = c0;      roleinfo[3] = s1 - c0;
    roleinfo[4] = s1 + c1; roleinfo[5] = s2 - s1 - c1;
    roleinfo[6] = s2 + c2; roleinfo[7] = mp - s2 - c2;
  }
}

__global__ __launch_bounds__(256) void permscatter_kernel(const int* __restrict__ role, int* __restrict__ rolefill,
                                                          int* __restrict__ spos, int* __restrict__ sposinv, int N)
{
  int i = blockIdx.x * 256 + threadIdx.x;
  int lane = threadIdx.x & 63;
  int r = (i < N) ? role[i] : -1;
  #pragma unroll
  for (int rr = 0; rr < 3; ++rr) {
    unsigned long long mask = __ballot(r == rr);
    if (!mask) continue;
    int base = 0;
    if (lane == 0) base = atomicAdd(&rolefill[rr], __popcll(mask));
    base = __shfl(base, 0);
    if (r == rr) {
      int rank = (int)__popcll(mask & ((1ull << lane) - 1ull));
      int pos = base + rank;
      spos[i] = pos;
      sposinv[pos] = i;
    }
  }
}

// coarse per-bucket edge counts (bucket = dst >> shiftB, <=256 buckets)
__global__ __launch_bounds__(256) void coarsehist_kernel(const int* __restrict__ ei,
                                                         int* __restrict__ bucketcnt,
                                                         int E, int N, int shiftB)
{
  __shared__ int lc[256];
  lc[threadIdx.x] = 0;
  __syncthreads();
  const int base = blockIdx.x * 4096;
  #pragma unroll
  for (int k = 0; k < 16; ++k) {
    int i = base + k * 256 + threadIdx.x;
    if (i < E + N) {
      int dst = (i < E) ? ei[E + i] : i - E;
      atomicAdd(&lc[dst >> shiftB], 1);
    }
  }
  __syncthreads();
  int c = lc[threadIdx.x];
  if (c > 0) atomicAdd(&bucketcnt[threadIdx.x], c);
}

// single-block scan of bucket counts -> bucketbase (excl, +total at [NB]) and bucketfill
__global__ __launch_bounds__(256) void bucketscan_kernel(const int* __restrict__ bucketcnt,
                                                         int* __restrict__ bucketbase,
                                                         int* __restrict__ bucketfill, int NB)
{
  __shared__ int lh[256];
  int tid = threadIdx.x;
  lh[tid] = (tid < NB) ? bucketcnt[tid] : 0;
  __syncthreads();
  for (int d = 1; d < 256; d <<= 1) {
    int v = (tid >= d) ? lh[tid - d] : 0;
    __syncthreads();
    lh[tid] += v;
    __syncthreads();
  }
  int excl = (tid > 0) ? lh[tid - 1] : 0;
  if (tid < NB) { bucketbase[tid] = excl; bucketfill[tid] = excl; }
  if (tid == 0) bucketbase[NB] = lh[255];
}

// stage 1: partition edges into dst-range buckets; records = (bin, t)
__global__ __launch_bounds__(256) void partition_kernel(
    const int* __restrict__ ei, const int* __restrict__ spos,
    const int* __restrict__ roleinfo, int* __restrict__ bucketfill,
    int2* __restrict__ recs, int E, int N, int shiftB)
{
  __shared__ int lcnt[256], lbase[256];
  const int base = blockIdx.x * 4096;
  const int s1 = roleinfo[0], s2 = roleinfo[1];
  lcnt[threadIdx.x] = 0;
  __syncthreads();
  int myb[16], mybin[16], myt[16];
  #pragma unroll
  for (int k = 0; k < 16; ++k) {
    int i = base + k * 256 + threadIdx.x;
    myb[k] = -1;
    if (i < E + N) {
      int src, dst;
      if (i < E) { src = ei[i]; dst = ei[E + i]; } else { src = i - E; dst = i - E; }
      int t = spos[src];
      int r = (t >= s2) ? 2 : (t >= s1) ? 1 : 0;
      myb[k] = dst >> shiftB;
      mybin[k] = dst * 3 + r;
      myt[k] = t;
      atomicAdd(&lcnt[myb[k]], 1);
    }
  }
  __syncthreads();
  int c = lcnt[threadIdx.x];
  lbase[threadIdx.x] = (c > 0) ? atomicAdd(&bucketfill[threadIdx.x], c) : 0;
  __syncthreads();
  lcnt[threadIdx.x] = 0;          // reuse as per-bucket cursor
  __syncthreads();
  #pragma unroll
  for (int k = 0; k < 16; ++k) {
    if (myb[k] >= 0) {
      int slot = atomicAdd(&lcnt[myb[k]], 1);
      recs[lbase[myb[k]] + slot] = make_int2(mybin[k], myt[k]);
    }
  }
}

// stage 2 (v2): per bucket, LDS histogram over local bins (<=768), LDS scan,
// write the bucket's off3 slice, then scatter ssrc via LDS cursors.
__global__ __launch_bounds__(1024) void binscatter_kernel(
    const int2* __restrict__ recs, const int* __restrict__ bucketbase,
    int* __restrict__ off3, int* __restrict__ ssrc, int W, int N, int NB)
{
  __shared__ int lh[1024];
  int b = blockIdx.x;
  int tid = threadIdx.x;
  int d0 = min(b * W, N), d1 = min((b + 1) * W, N);
  int nloc = (d1 - d0) * 3;                 // <= 768
  int s = bucketbase[b], e = bucketbase[b + 1];
  int lb0 = d0 * 3;

  lh[tid] = 0;
  __syncthreads();
  for (int i = s + tid; i < e; i += 1024)
    atomicAdd(&lh[recs[i].x - lb0], 1);
  __syncthreads();
  // inclusive scan over 1024 (bins >= nloc are zero)
  for (int d = 1; d < 1024; d <<= 1) {
    int v = (tid >= d) ? lh[tid - d] : 0;
    __syncthreads();
    lh[tid] += v;
    __syncthreads();
  }
  // write off3 slice: off3[lb0 + j] = s + excl(j)
  if (tid < nloc) off3[lb0 + tid] = s + ((tid > 0) ? lh[tid - 1] : 0);
  if (b == NB - 1 && tid == 0) off3[N * 3] = e;
  // convert to exclusive cursors
  int excl = (tid > 0) ? lh[tid - 1] : 0;
  __syncthreads();
  lh[tid] = excl;
  __syncthreads();
  for (int i = s + tid; i < e; i += 1024) {
    int2 rec = recs[i];
    int slot = atomicAdd(&lh[rec.x - lb0], 1);
    ssrc[s + slot] = rec.y;
  }
}

__global__ __launch_bounds__(256) void zeropad_kernel(const int* __restrict__ roleinfo,
                                                      bf16* __restrict__ Ax, bf16* __restrict__ Ah)
{
  int id = blockIdx.x * 256 + threadIdx.x;   // 98304
  int a = id / 49152, rem = id % 49152;
  int gp = rem / 16384, r2 = rem % 16384;
  int rr = r2 >> 6, c = r2 & 63;
  int gs = roleinfo[2 + gp * 2], gl = roleinfo[3 + gp * 2];
  if (rr < gl) {
    int row = gs + rr;
    size_t unit = (size_t)(row >> 4) * 1024 + c * 16 + (row & 15);
    bf16x8 z = {};
    ((bf16x8*)(a == 0 ? Ax : Ah))[unit] = z;
  }
}

// ---------------- prep ----------------
__global__ __launch_bounds__(256) void prep_xh_kernel(const float* __restrict__ x, const float* __restrict__ h,
                                                      const int* __restrict__ spos, u8* __restrict__ xq8,
                                                      bf16* __restrict__ Ax, bf16* __restrict__ Ah, int N)
{
  int g = blockIdx.x * 256 + threadIdx.x;
  if (g >= N * 32) return;
  int n = g >> 5, j = g & 31;
  int t = spos[n];
  const float* src = (j < 16) ? (x + (size_t)n * 128 + (j << 3))
                              : (h + (size_t)n * 128 + ((j - 16) << 3));
  float4 v0 = ((const float4*)src)[0];
  float4 v1 = ((const float4*)src)[1];
  int lo = __builtin_amdgcn_cvt_pk_fp8_f32(v0.x, v0.y, 0, false);
  lo = __builtin_amdgcn_cvt_pk_fp8_f32(v0.z, v0.w, lo, true);
  int hi = __builtin_amdgcn_cvt_pk_fp8_f32(v1.x, v1.y, 0, false);
  hi = __builtin_amdgcn_cvt_pk_fp8_f32(v1.z, v1.w, hi, true);
  *(int2*)(xq8 + (size_t)t * 256 + j * 8) = make_int2(lo, hi);
  bf16x8 o;
  o[0] = (bf16)v0.x; o[1] = (bf16)v0.y; o[2] = (bf16)v0.z; o[3] = (bf16)v0.w;
  o[4] = (bf16)v1.x; o[5] = (bf16)v1.y; o[6] = (bf16)v1.z; o[7] = (bf16)v1.w;
  size_t unit = (size_t)(t >> 4) * 1024 + (48 + (j & 15)) * 16 + (t & 15);
  ((bf16x8*)(j < 16 ? Ax : Ah))[unit] = o;
}

struct PrepW { const float* W[6]; const float* Wg[6]; const float* bg[6]; };
__global__ __launch_bounds__(256) void prep_wf_kernel(PrepW pw, bf16* __restrict__ Wf)
{
  int idx = blockIdx.x * 256 + threadIdx.x;
  if (idx >= 294912) return;
  int cv = idx / 49152, pos = idx % 49152;
  int ks4q = pos >> 10;
  int col = (pos >> 3) & 127, j = pos & 7;
  int k = (ks4q >> 2) * 32 + (ks4q & 3) * 8 + j;
  int r = k >> 7, kk = k & 127;
  float g = sigmoidf_(pw.Wg[cv][r * 128 + col] + pw.bg[cv][r * 128 + col]);
  Wf[idx] = (bf16)(pw.W[cv][kk * 128 + col] * g);
}

struct PrepP { const float* W[6]; const float* S[6]; };
__global__ __launch_bounds__(128) void prep_pf_kernel(PrepP pp, bf16* __restrict__ Pf)
{
  int b = blockIdx.x;                          // 6*3*128
  int cv = b / 384, rem = b % 384;
  int r = rem >> 7, kp = rem & 127;
  int col = threadIdx.x;
  const float* W = pp.W[cv] + (size_t)kp * 128;
  const float* S = pp.S[cv] + (size_t)r * 16384;
  float sum = 0.f;
  #pragma unroll 4
  for (int j2 = 0; j2 < 128; ++j2) sum += W[j2] * S[j2 * 128 + col];
  size_t o = (size_t)(cv * 3 + r) * 16384 + ((size_t)(kp >> 3) * 128 + col) * 8 + (kp & 7);
  Pf[o] = (bf16)sum;
}

// ---------------- gathers (t-ordered 8-node blocks, cooperative full-line NT writes) ----------------
#define ACCUM16(U, d) do { f32x2 f_;                                                   \
  f_ = __builtin_amdgcn_cvt_pk_f32_fp8((d).x, false); U[0]  += f_[0]; U[1]  += f_[1];  \
  f_ = __builtin_amdgcn_cvt_pk_f32_fp8((d).x, true);  U[2]  += f_[0]; U[3]  += f_[1];  \
  f_ = __builtin_amdgcn_cvt_pk_f32_fp8((d).y, false); U[4]  += f_[0]; U[5]  += f_[1];  \
  f_ = __builtin_amdgcn_cvt_pk_f32_fp8((d).y, true);  U[6]  += f_[0]; U[7]  += f_[1];  \
  f_ = __builtin_amdgcn_cvt_pk_f32_fp8((d).z, false); U[8]  += f_[0]; U[9]  += f_[1];  \
  f_ = __builtin_amdgcn_cvt_pk_f32_fp8((d).z, true);  U[10] += f_[0]; U[11] += f_[1];  \
  f_ = __builtin_amdgcn_cvt_pk_f32_fp8((d).w, false); U[12] += f_[0]; U[13] += f_[1];  \
  f_ = __builtin_amdgcn_cvt_pk_f32_fp8((d).w, true);  U[14] += f_[0]; U[15] += f_[1];  \
} while (0)

#define ACCSEL16(d, p) do {                      \
  if ((p) < o1)      { ACCUM16(u0, d); }         \
  else if ((p) < o2) { ACCUM16(u1, d); }         \
  else               { ACCUM16(u2, d); }         \
} while (0)

__global__ __launch_bounds__(512) void gather_xh_kernel(
    const u8* __restrict__ xq8, const int* __restrict__ off3, const int* __restrict__ ssrc,
    const int* __restrict__ sposinv, bf16* __restrict__ Ax, bf16* __restrict__ Ah,
    float4* __restrict__ cntf)
{
  __shared__ alignas(16) bf16 lds[8][768];
  int w = threadIdx.x >> 6, lane = threadIdx.x & 63;
  int t0 = blockIdx.x * 8;
  int t = t0 + w;
  int node = sposinv[t];                 // -1 for pad rows
  int qt = lane >> 4, ql = lane & 15;

  if (node >= 0) {
    int o0 = __builtin_amdgcn_readfirstlane(off3[node * 3]);
    int o1 = __builtin_amdgcn_readfirstlane(off3[node * 3 + 1]);
    int o2 = __builtin_amdgcn_readfirstlane(off3[node * 3 + 2]);
    int o3 = __builtin_amdgcn_readfirstlane(off3[node * 3 + 3]);
    float inv = 1.0f / (float)(o3 - o0);
    const u8* base = xq8 + ql * 16;

    float u0[16], u1[16], u2[16];
    #pragma unroll
    for (int k = 0; k < 16; ++k) { u0[k] = 0.f; u1[k] = 0.f; u2[k] = 0.f; }

    const int e = o3, emax = o3 - 1;
    for (int i = o0; i < e; i += 16) {
      int p0 = i + qt, p1 = p0 + 4, p2 = p0 + 8, p3 = p0 + 12;
      int t0i = ssrc[min(p0, emax)];
      int t1i = ssrc[min(p1, emax)];
      int t2i = ssrc[min(p2, emax)];
      int t3i = ssrc[min(p3, emax)];
      int4 d0 = make_int4(0, 0, 0, 0), d1 = d0, d2 = d0, d3 = d0;
      if (p0 < e) d0 = *(const int4*)(base + (size_t)t0i * 256);
      if (p1 < e) d1 = *(const int4*)(base + (size_t)t1i * 256);
      if (p2 < e) d2 = *(const int4*)(base + (size_t)t2i * 256);
      if (p3 < e) d3 = *(const int4*)(base + (size_t)t3i * 256);
      ACCSEL16(d0, p0);
      ACCSEL16(d1, p1);
      ACCSEL16(d2, p2);
      ACCSEL16(d3, p3);
    }

    #pragma unroll
    for (int k = 0; k < 16; ++k) {
      u0[k] += __shfl_xor(u0[k], 16); u0[k] += __shfl_xor(u0[k], 32);
      u1[k] += __shfl_xor(u1[k], 16); u1[k] += __shfl_xor(u1[k], 32);
      u2[k] += __shfl_xor(u2[k], 16); u2[k] += __shfl_xor(u2[k], 32);
    }
    if (qt == 0) {
      bf16x8 p0v, p1v;
      int sb0 = (ql < 8) ? (ql * 16) : (384 + (ql - 8) * 16);
      #pragma unroll
      for (int k = 0; k < 8; ++k) { p0v[k] = (bf16)(u0[k] * inv); p1v[k] = (bf16)(u0[8 + k] * inv); }
      *(bf16x8*)&lds[w][sb0] = p0v;
      *(bf16x8*)&lds[w][sb0 + 8] = p1v;
      #pragma unroll
      for (int k = 0; k < 8; ++k) { p0v[k] = (bf16)(u1[k] * inv); p1v[k] = (bf16)(u1[8 + k] * inv); }
      *(bf16x8*)&lds[w][sb0 + 128] = p0v;
      *(bf16x8*)&lds[w][sb0 + 136] = p1v;
      #pragma unroll
      for (int k = 0; k < 8; ++k) { p0v[k] = (bf16)(u2[k] * inv); p1v[k] = (bf16)(u2[8 + k] * inv); }
      *(bf16x8*)&lds[w][sb0 + 256] = p0v;
      *(bf16x8*)&lds[w][sb0 + 264] = p1v;
    }
    if (lane == 0)
      cntf[t] = make_float4((o1 - o0) * inv, (o2 - o1) * inv, (o3 - o2) * inv, (float)(o3 - o0));
  } else {
    // pad row: zero-fill this wave's LDS section so the cooperative write stores zeros
    if (lane < 48) {
      bf16x8 z = {};
      *(bf16x8*)&lds[w][lane * 16] = z;
      *(bf16x8*)&lds[w][lane * 16 + 8] = z;
    }
    if (lane == 0) cntf[t] = make_float4(0.f, 0.f, 0.f, 0.f);
  }

  __syncthreads();

  // cooperative write: 8 consecutive rows (t0..t0+7, same 16-group) -> full 128-B lines
  int tid = threadIdx.x;
  if (tid < 384) {
    int lc = tid >> 3, row = tid & 7;
    size_t unit = (size_t)(t0 >> 4) * 1024 + lc * 16 + (t0 & 15) + row;
    __builtin_nontemporal_store(*(const bf16x8*)&lds[row][lc * 8], (bf16x8*)Ax + unit);
    __builtin_nontemporal_store(*(const bf16x8*)&lds[row][384 + lc * 8], (bf16x8*)Ah + unit);
  }
}

#define ACCUM8(U, d) do { f32x2 f_;                                                  \
  f_ = __builtin_amdgcn_cvt_pk_f32_fp8((d).x, false); U[0] += f_[0]; U[1] += f_[1];  \
  f_ = __builtin_amdgcn_cvt_pk_f32_fp8((d).x, true);  U[2] += f_[0]; U[3] += f_[1];  \
  f_ = __builtin_amdgcn_cvt_pk_f32_fp8((d).y, false); U[4] += f_[0]; U[5] += f_[1];  \
  f_ = __builtin_amdgcn_cvt_pk_f32_fp8((d).y, true);  U[6] += f_[0]; U[7] += f_[1];  \
} while (0)

#define ACCSEL8(d, p) do {                      \
  if ((p) < o1)      { ACCUM8(v0, d); }         \
  else if ((p) < o2) { ACCUM8(v1, d); }         \
  else               { ACCUM8(v2, d); }         \
} while (0)

__global__ __launch_bounds__(512) void gather_q_kernel(
    const u8* __restrict__ q8, const int* __restrict__ off3, const int* __restrict__ ssrc,
    const int* __restrict__ sposinv, bf16* __restrict__ Aq)
{
  __shared__ alignas(16) bf16 lds[8][384];
  int w = threadIdx.x >> 6, lane = threadIdx.x & 63;
  int t0 = blockIdx.x * 8;
  int t = t0 + w;
  int node = sposinv[t];
  int qt = lane >> 4, ql = lane & 15;

  if (node >= 0) {
    int o0 = __builtin_amdgcn_readfirstlane(off3[node * 3]);
    int o1 = __builtin_amdgcn_readfirstlane(off3[node * 3 + 1]);
    int o2 = __builtin_amdgcn_readfirstlane(off3[node * 3 + 2]);
    int o3 = __builtin_amdgcn_readfirstlane(off3[node * 3 + 3]);
    float inv = 1.0f / (float)(o3 - o0);
    const u8* base = q8 + ql * 8;

    float v0[8], v1[8], v2[8];
    #pragma unroll
    for (int k = 0; k < 8; ++k) { v0[k] = 0.f; v1[k] = 0.f; v2[k] = 0.f; }

    const int e = o3, emax = o3 - 1;
    for (int i = o0; i < e; i += 16) {
      int p0 = i + qt, p1 = p0 + 4, p2 = p0 + 8, p3 = p0 + 12;
      int t0i = ssrc[min(p0, emax)];
      int t1i = ssrc[min(p1, emax)];
      int t2i = ssrc[min(p2, emax)];
      int t3i = ssrc[min(p3, emax)];
      int2 d0 = make_int2(0, 0), d1 = d0, d2 = d0, d3 = d0;
      if (p0 < e) d0 = *(const int2*)(base + (size_t)t0i * 128);
      if (p1 < e) d1 = *(const int2*)(base + (size_t)t1i * 128);
      if (p2 < e) d2 = *(const int2*)(base + (size_t)t2i * 128);
      if (p3 < e) d3 = *(const int2*)(base + (size_t)t3i * 128);
      ACCSEL8(d0, p0);
      ACCSEL8(d1, p1);
      ACCSEL8(d2, p2);
      ACCSEL8(d3, p3);
    }

    #pragma unroll
    for (int k = 0; k < 8; ++k) {
      v0[k] += __shfl_xor(v0[k], 16); v0[k] += __shfl_xor(v0[k], 32);
      v1[k] += __shfl_xor(v1[k], 16); v1[k] += __shfl_xor(v1[k], 32);
      v2[k] += __shfl_xor(v2[k], 16); v2[k] += __shfl_xor(v2[k], 32);
    }
    if (qt == 0) {
      bf16x8 pk;
      #pragma unroll
      for (int k = 0; k < 8; ++k) pk[k] = (bf16)(v0[k] * inv);
      *(bf16x8*)&lds[w][ql * 8] = pk;
      #pragma unroll
      for (int k = 0; k < 8; ++k) pk[k] = (bf16)(v1[k] * inv);
      *(bf16x8*)&lds[w][128 + ql * 8] = pk;
      #pragma unroll
      for (int k = 0; k < 8; ++k) pk[k] = (bf16)(v2[k] * inv);
      *(bf16x8*)&lds[w][256 + ql * 8] = pk;
    }
  } else {
    if (lane < 48) {
      bf16x8 z = {};
      *(bf16x8*)&lds[w][lane * 8] = z;
    }
  }

  __syncthreads();

  int tid = threadIdx.x;
  if (tid < 384) {
    int lc = tid >> 3, row = tid & 7;
    size_t unit = (size_t)(t0 >> 4) * 1024 + lc * 16 + (t0 & 15) + row;
    __builtin_nontemporal_store(*(const bf16x8*)&lds[row][lc * 8], (bf16x8*)Aq + unit);
  }
}

// ---------------- streaming MFMA GEMM (no LDS/barriers; 2 row-blocks per wave, 3 waves/SIMD) ----------------
struct GArgs {
  const bf16* Ap[5];
  const bf16* wf[5];
  const bf16* pf[5];
  bf16* out[5];
  const float* bias[5];
};

__global__ __launch_bounds__(256, 3) void gemm_kernel(GArgs ga, const float4* __restrict__ cntf,
                                                      const int* __restrict__ roleinfo)
{
  const int cv = blockIdx.y;
  const bf16* __restrict__ Ap = ga.Ap[cv];
  const bf16* __restrict__ wf = ga.wf[cv];
  const bf16* __restrict__ pf = ga.pf[cv];
  bf16* __restrict__ out = ga.out[cv];
  const float* __restrict__ bias = ga.bias[cv];

  const int w = threadIdx.x >> 6, lane = threadIdx.x & 63;
  const int q = lane >> 4, l = lane & 15;
  const int rb0 = blockIdx.x * 8 + w * 2;
  const int row0 = blockIdx.x * 128;
  const int s1 = roleinfo[0], s2 = roleinfo[1];
  const int role = (row0 >= s2) ? 2 : (row0 >= s1) ? 1 : 0;
  const int laneoff = q * 128 + l;

  f32x4 acc[2][8];
  #pragma unroll
  for (int j = 0; j < 2; ++j)
    #pragma unroll
    for (int ct = 0; ct < 8; ++ct)
      #pragma unroll
      for (int k = 0; k < 4; ++k) acc[j][ct][k] = 0.f;

  const bf16x8* A0 = (const bf16x8*)Ap + (size_t)rb0 * 1024 + lane;
  const bf16x8* WF = (const bf16x8*)wf + laneoff;
  const bf16x8* PF = (const bf16x8*)pf + role * 2048 + laneoff;

  #pragma unroll 2
  for (int ks = 0; ks < 16; ++ks) {
    const bf16x8* bp = (ks < 12) ? (WF + ks * 512) : (PF + (ks - 12) * 512);
    bf16x8 a0 = A0[ks * 64];
    bf16x8 a1 = A0[1024 + ks * 64];
    #pragma unroll
    for (int ct = 0; ct < 8; ++ct) {
      bf16x8 b = bp[ct * 16];
      acc[0][ct] = __builtin_amdgcn_mfma_f32_16x16x32_bf16(a0, b, acc[0][ct], 0, 0, 0);
      acc[1][ct] = __builtin_amdgcn_mfma_f32_16x16x32_bf16(a1, b, acc[1][ct], 0, 0, 0);
    }
  }

  const bool hb = (bias != nullptr);
  #pragma unroll
  for (int j = 0; j < 2; ++j) {
    int rb = rb0 + j;
    float4 cfs[4];
    if (hb) {
      #pragma unroll
      for (int reg = 0; reg < 4; ++reg) cfs[reg] = cntf[rb * 16 + q * 4 + reg];
    }
    #pragma unroll
    for (int ct = 0; ct < 8; ++ct) {
      int col = ct * 16 + l;
      float b0 = 0, b1 = 0, b2 = 0;
      if (hb) { b0 = bias[col]; b1 = bias[128 + col]; b2 = bias[256 + col]; }
      #pragma unroll
      for (int reg = 0; reg < 4; ++reg) {
        int t = rb * 16 + q * 4 + reg;
        float v = acc[j][ct][reg];
        if (hb) v += cfs[reg].x * b0 + cfs[reg].y * b1 + cfs[reg].z * b2;
        out[(size_t)t * 128 + col] = (bf16)fmaxf(v, 0.f);
      }
    }
  }
}

// ---------------- combines ----------------
__global__ __launch_bounds__(256) void combine1_kernel(
    const bf16* __restrict__ o0, const bf16* __restrict__ o1,
    const bf16* __restrict__ o2, const bf16* __restrict__ o3,
    const float* __restrict__ h, const int* __restrict__ spos,
    float* __restrict__ zbuf, u8* __restrict__ q8, bf16* __restrict__ Aq, int N)
{
  int g = blockIdx.x * 256 + threadIdx.x;
  if (g >= N * 16) return;
  int n = g >> 4, o = g & 15;
  int t = spos[n];
  size_t tb = (size_t)t * 16 + o;
  bf16x8 a0 = ((const bf16x8*)o0)[tb];
  bf16x8 a1 = ((const bf16x8*)o1)[tb];
  bf16x8 a2 = ((const bf16x8*)o2)[tb];
  bf16x8 a3 = ((const bf16x8*)o3)[tb];
  size_t nb = (size_t)n * 16 + o;
  float4 h0 = ((const float4*)h)[nb * 2];
  float4 h1 = ((const float4*)h)[nb * 2 + 1];
  float hv[8] = {h0.x, h0.y, h0.z, h0.w, h1.x, h1.y, h1.z, h1.w};
  float zv[8], qv[8];
  bf16x8 qb;
  #pragma unroll
  for (int j = 0; j < 8; ++j) {
    zv[j] = sigmoidf_((float)a0[j] + (float)a1[j]);
    qv[j] = sigmoidf_((float)a2[j] + (float)a3[j]) * hv[j];
    qb[j] = (bf16)qv[j];
  }
  ((float4*)zbuf)[nb * 2]     = make_float4(zv[0], zv[1], zv[2], zv[3]);
  ((float4*)zbuf)[nb * 2 + 1] = make_float4(zv[4], zv[5], zv[6], zv[7]);
  int lo = __builtin_amdgcn_cvt_pk_fp8_f32(qv[0], qv[1], 0, false);
  lo = __builtin_amdgcn_cvt_pk_fp8_f32(qv[2], qv[3], lo, true);
  int hi = __builtin_amdgcn_cvt_pk_fp8_f32(qv[4], qv[5], 0, false);
  hi = __builtin_amdgcn_cvt_pk_fp8_f32(qv[6], qv[7], hi, true);
  *(int2*)(q8 + (size_t)t * 128 + o * 8) = make_int2(lo, hi);
  size_t unit = (size_t)(t >> 4) * 1024 + (48 + o) * 16 + (t & 15);
  ((bf16x8*)Aq)[unit] = qb;
}

__global__ __launch_bounds__(256) void combine2_kernel(
    const float* __restrict__ zbuf, const bf16* __restrict__ o4, const bf16* __restrict__ o5,
    const float* __restrict__ h, const int* __restrict__ spos, float* __restrict__ out, int N)
{
  int g = blockIdx.x * 256 + threadIdx.x;
  if (g >= N * 16) return;
  int n = g >> 4, o = g & 15;
  int t = spos[n];
  size_t tb = (size_t)t * 16 + o;
  bf16x8 a = ((const bf16x8*)o4)[tb];
  bf16x8 b = ((const bf16x8*)o5)[tb];
  size_t nb = (size_t)n * 16 + o;
  float4 z0 = ((const float4*)zbuf)[nb * 2];
  float4 z1 = ((const float4*)zbuf)[nb * 2 + 1];
  float4 h0 = ((const float4*)h)[nb * 2];
  float4 h1 = ((const float4*)h)[nb * 2 + 1];
  float zv[8] = {z0.x, z0.y, z0.z, z0.w, z1.x, z1.y, z1.z, z1.w};
  float hv[8] = {h0.x, h0.y, h0.z, h0.w, h1.x, h1.y, h1.z, h1.w};
  float ov[8];
  #pragma unroll
  for (int j = 0; j < 8; ++j)
    ov[j] = zv[j] * hv[j] + (1.f - zv[j]) * tanhf((float)a[j] + (float)b[j]);
  ((float4*)out)[nb * 2]     = make_float4(ov[0], ov[1], ov[2], ov[3]);
  ((float4*)out)[nb * 2 + 1] = make_float4(ov[4], ov[5], ov[6], ov[7]);
}

// ---------------- host ----------------
extern "C" void kernel_launch(void* const* d_in, const int* in_sizes, int n_in,
                              void* d_out, int out_size, void* d_ws, size_t ws_size,
                              hipStream_t stream)
{
  (void)n_in; (void)out_size; (void)ws_size;
  const float* x    = (const float*)d_in[0];
  const float* h    = (const float*)d_in[1];
  const int*   ei   = (const int*)d_in[2];
  const int*   role = (const int*)d_in[3];
  const int N = in_sizes[0] / DH;
  const int E = in_sizes[2] / 2;
  const int Etot = E + N;
  const int rows_pad = ((N + 765) + 255) & ~255;
  const int gx = rows_pad / 128;
  const int n3 = N * 3;

  // bucket geometry: <=256 buckets of W=2^shiftB dst rows (N=50000 -> shiftB=8, W=256, NB=196)
  int shiftB = 8;
  while (((N - 1) >> shiftB) >= 256) ++shiftB;
  const int W = 1 << shiftB;
  const int NB = (N + W - 1) >> shiftB;

  // conv order: 0 xz, 1 hz, 2 xr, 3 hr, 4 xh, 5 hh
  static const int Wi[6]  = {4, 9, 13, 18, 22, 27};
  static const int Wgi[6] = {5, 10, 14, 19, 23, 28};
  static const int bgi[6] = {6, 11, 15, 20, 24, 29};
  static const int Si[6]  = {7, 12, 16, 21, 25, 30};

  char* p = (char*)d_ws;
  auto alloc = [&](size_t bytes) -> char* {
    char* r = p;
    p += (bytes + 255) & ~(size_t)255;
    return r;
  };

  bf16* Ax = (bf16*)alloc((size_t)rows_pad * 512 * 2);   // Aq aliases Ax
  bf16* Ah = (bf16*)alloc((size_t)rows_pad * 512 * 2);
  bf16* Aq = Ax;
  u8* xq8  = (u8*)alloc((size_t)rows_pad * 256);
  u8* q8   = (u8*)alloc((size_t)rows_pad * 128);
  bf16* outs[6];
  for (int c = 0; c < 5; ++c) outs[c] = (bf16*)alloc((size_t)rows_pad * 128 * 2);
  outs[5] = outs[0];
  float* zbuf = (float*)alloc((size_t)N * 128 * 4);
  float4* cntf = (float4*)alloc((size_t)rows_pad * 16);
  bf16* Wf = (bf16*)alloc((size_t)6 * 49152 * 2);
  bf16* Pf = (bf16*)alloc((size_t)18 * 16384 * 2);
  int* off3  = (int*)alloc((size_t)(n3 + 1) * 4);
  int* ssrc  = (int*)alloc((size_t)Etot * 4);
  int2* recs = (int2*)alloc((size_t)Etot * 8);
  int* spos  = (int*)alloc((size_t)N * 4);
  int* sposinv = (int*)alloc((size_t)rows_pad * 4);
  int* rolecnt  = (int*)alloc(64);
  int* rolefill = (int*)alloc(64);
  int* roleinfo = (int*)alloc(64);
  int* bucketcnt  = (int*)alloc(257 * 4);
  int* bucketbase = (int*)alloc(258 * 4);
  int* bucketfill = (int*)alloc(257 * 4);

  hipMemsetAsync(rolecnt, 0, 16, stream);
  hipMemsetAsync(bucketcnt, 0, 257 * 4, stream);
  hipMemsetAsync(sposinv, 0xFF, (size_t)rows_pad * 4, stream);   // -1 = pad row

  int egrid4k = (Etot + 4095) / 4096;
  int ngrid = (N + 255) / 256;
  rolecnt_kernel<<<ngrid, 256, 0, stream>>>(role, rolecnt, N);
  roleinfo_kernel<<<1, 64, 0, stream>>>(rolecnt, rolefill, roleinfo);
  permscatter_kernel<<<ngrid, 256, 0, stream>>>(role, rolefill, spos, sposinv, N);
  coarsehist_kernel<<<egrid4k, 256, 0, stream>>>(ei, bucketcnt, E, N, shiftB);
  bucketscan_kernel<<<1, 256, 0, stream>>>(bucketcnt, bucketbase, bucketfill, NB);
  partition_kernel<<<egrid4k, 256, 0, stream>>>(ei, spos, roleinfo, bucketfill,
                                                recs, E, N, shiftB);
  binscatter_kernel<<<NB, 1024, 0, stream>>>(recs, bucketbase, off3, ssrc, W, N, NB);
  zeropad_kernel<<<384, 256, 0, stream>>>(roleinfo, Ax, Ah);

  prep_xh_kernel<<<(N * 32 + 255) / 256, 256, 0, stream>>>(x, h, spos, xq8, Ax, Ah, N);

  PrepW pw;
  for (int c = 0; c < 6; ++c) {
    pw.W[c] = (const float*)d_in[Wi[c]];
    pw.Wg[c] = (const float*)d_in[Wgi[c]];
    pw.bg[c] = (const float*)d_in[bgi[c]];
  }
  prep_wf_kernel<<<1152, 256, 0, stream>>>(pw, Wf);
  PrepP pp;
  for (int c = 0; c < 6; ++c) { pp.W[c] = (const float*)d_in[Wi[c]]; pp.S[c] = (const float*)d_in[Si[c]]; }
  prep_pf_kernel<<<2304, 128, 0, stream>>>(pp, Pf);

  gather_xh_kernel<<<rows_pad / 8, 512, 0, stream>>>(xq8, off3, ssrc, sposinv, Ax, Ah, cntf);

  // pass 1: one dispatch, cv 0..4 = {xz,xr,xh on Ax (bias)} + {hz,hr on Ah}
  GArgs g0;
  { int cvs[5] = {0, 2, 4, 1, 3};
    static const int bi2[5] = {8, 17, 26, -1, -1};
    const bf16* Apts[5] = {Ax, Ax, Ax, Ah, Ah};
    for (int k = 0; k < 5; ++k) {
      int c = cvs[k];
      g0.Ap[k] = Apts[k];
      g0.wf[k] = Wf + (size_t)c * 49152;
      g0.pf[k] = Pf + (size_t)c * 3 * 16384;
      g0.out[k] = outs[c];
      g0.bias[k] = (bi2[k] >= 0) ? (const float*)d_in[bi2[k]] : nullptr;
    } }
  gemm_kernel<<<dim3(gx, 5), 256, 0, stream>>>(g0, cntf, roleinfo);

  combine1_kernel<<<(N * 16 + 255) / 256, 256, 0, stream>>>(outs[0], outs[1], outs[2], outs[3],
                                                            h, spos, zbuf, q8, Aq, N);

  gather_q_kernel<<<rows_pad / 8, 512, 0, stream>>>(q8, off3, ssrc, sposinv, Aq);

  // pass 2: conv hh(5) on Aq
  GArgs g2 = {};
  g2.Ap[0] = Aq;
  g2.wf[0] = Wf + (size_t)5 * 49152;
  g2.pf[0] = Pf + (size_t)5 * 3 * 16384;
  g2.out[0] = outs[5];
  g2.bias[0] = nullptr;
  gemm_kernel<<<dim3(gx, 1), 256, 0, stream>>>(g2, cntf, roleinfo);

  combine2_kernel<<<(N * 16 + 255) / 256, 256, 0, stream>>>(zbuf, outs[4], outs[5], h, spos,
                                                            (float*)d_out, N);
}

// Round 11
// 610.641 us; speedup vs baseline: 1.9025x; 1.0010x over previous
//
#include <hip/hip_runtime.h>

// GraphGRU on MI355X — round 17.
//   Two low-risk fixes below the top-5 (base r16 = 611.3 µs verified):
//   1. gemm grid axes swapped to (conv, tile): the 5 convs sharing one A-tile now dispatch
//      adjacently -> A stays L2-hot across convs (was ~398 blocks apart; r7 FETCH showed
//      A re-fetched ~2x). Pure index rename.
//   2. prep_xh flipped to t-major (n = sposinv[t]): reads become random full-line (no amp),
//      writes become t-contiguous full 128-B lines (was 16-B random-t scatter = partial-line
//      write amplification, same pathology r9 fixed in the gathers).
//   Gathers/CSR/combines byte-identical to r16.

typedef __bf16 bf16;
typedef __bf16 bf16x8 __attribute__((ext_vector_type(8)));
typedef float  f32x4  __attribute__((ext_vector_type(4)));
typedef float  f32x2  __attribute__((ext_vector_type(2)));
typedef unsigned char u8;

#define DH 128

__device__ __forceinline__ float sigmoidf_(float x) { return 1.0f / (1.0f + expf(-x)); }

// ---------------- CSR build (bucket-local) ----------------
__global__ __launch_bounds__(256) void rolecnt_kernel(const int* __restrict__ role,
                                                      int* __restrict__ rolecnt, int N)
{
  int i = blockIdx.x * 256 + threadIdx.x;
  int lane = threadIdx.x & 63;
  int r = (i < N) ? role[i] : -1;
  #pragma unroll
  for (int rr = 0; rr < 3; ++rr) {
    unsigned long long mask = __ballot(r == rr);
    if (lane == 0 && mask) atomicAdd(&rolecnt[rr], __popcll(mask));
  }
}

__global__ void roleinfo_kernel(const int* __restrict__ rolecnt,
                                int* __restrict__ rolefill, int* __restrict__ roleinfo)
{
  if (threadIdx.x == 0) {
    int c0 = rolecnt[0], c1 = rolecnt[1], c2 = rolecnt[2];
    int s1 = (c0 + 255) & ~255;
    int s2 = s1 + ((c1 + 255) & ~255);
    int mp = s2 + ((c2 + 255) & ~255);
    rolefill[0] = 0; rolefill[1] = s1; rolefill[2] = s2;
    roleinfo[0] = s1; roleinfo[1] = s2;
    roleinfo[2] = c0;      roleinfo[3] = s1 - c0;
    roleinfo[4] = s1 + c1; roleinfo[5] = s2 - s1 - c1;
    roleinfo[6] = s2 + c2; roleinfo[7] = mp - s2 - c2;
  }
}

__global__ __launch_bounds__(256) void permscatter_kernel(const int* __restrict__ role, int* __restrict__ rolefill,
                                                          int* __restrict__ spos, int* __restrict__ sposinv, int N)
{
  int i = blockIdx.x * 256 + threadIdx.x;
  int lane = threadIdx.x & 63;
  int r = (i < N) ? role[i] : -1;
  #pragma unroll
  for (int rr = 0; rr < 3; ++rr) {
    unsigned long long mask = __ballot(r == rr);
    if (!mask) continue;
    int base = 0;
    if (lane == 0) base = atomicAdd(&rolefill[rr], __popcll(mask));
    base = __shfl(base, 0);
    if (r == rr) {
      int rank = (int)__popcll(mask & ((1ull << lane) - 1ull));
      int pos = base + rank;
      spos[i] = pos;
      sposinv[pos] = i;
    }
  }
}

// coarse per-bucket edge counts (bucket = dst >> shiftB, <=256 buckets)
__global__ __launch_bounds__(256) void coarsehist_kernel(const int* __restrict__ ei,
                                                         int* __restrict__ bucketcnt,
                                                         int E, int N, int shiftB)
{
  __shared__ int lc[256];
  lc[threadIdx.x] = 0;
  __syncthreads();
  const int base = blockIdx.x * 4096;
  #pragma unroll
  for (int k = 0; k < 16; ++k) {
    int i = base + k * 256 + threadIdx.x;
    if (i < E + N) {
      int dst = (i < E) ? ei[E + i] : i - E;
      atomicAdd(&lc[dst >> shiftB], 1);
    }
  }
  __syncthreads();
  int c = lc[threadIdx.x];
  if (c > 0) atomicAdd(&bucketcnt[threadIdx.x], c);
}

// single-block scan of bucket counts -> bucketbase (excl, +total at [NB]) and bucketfill
__global__ __launch_bounds__(256) void bucketscan_kernel(const int* __restrict__ bucketcnt,
                                                         int* __restrict__ bucketbase,
                                                         int* __restrict__ bucketfill, int NB)
{
  __shared__ int lh[256];
  int tid = threadIdx.x;
  lh[tid] = (tid < NB) ? bucketcnt[tid] : 0;
  __syncthreads();
  for (int d = 1; d < 256; d <<= 1) {
    int v = (tid >= d) ? lh[tid - d] : 0;
    __syncthreads();
    lh[tid] += v;
    __syncthreads();
  }
  int excl = (tid > 0) ? lh[tid - 1] : 0;
  if (tid < NB) { bucketbase[tid] = excl; bucketfill[tid] = excl; }
  if (tid == 0) bucketbase[NB] = lh[255];
}

// stage 1: partition edges into dst-range buckets; records = (bin, t)
__global__ __launch_bounds__(256) void partition_kernel(
    const int* __restrict__ ei, const int* __restrict__ spos,
    const int* __restrict__ roleinfo, int* __restrict__ bucketfill,
    int2* __restrict__ recs, int E, int N, int shiftB)
{
  __shared__ int lcnt[256], lbase[256];
  const int base = blockIdx.x * 4096;
  const int s1 = roleinfo[0], s2 = roleinfo[1];
  lcnt[threadIdx.x] = 0;
  __syncthreads();
  int myb[16], mybin[16], myt[16];
  #pragma unroll
  for (int k = 0; k < 16; ++k) {
    int i = base + k * 256 + threadIdx.x;
    myb[k] = -1;
    if (i < E + N) {
      int src, dst;
      if (i < E) { src = ei[i]; dst = ei[E + i]; } else { src = i - E; dst = i - E; }
      int t = spos[src];
      int r = (t >= s2) ? 2 : (t >= s1) ? 1 : 0;
      myb[k] = dst >> shiftB;
      mybin[k] = dst * 3 + r;
      myt[k] = t;
      atomicAdd(&lcnt[myb[k]], 1);
    }
  }
  __syncthreads();
  int c = lcnt[threadIdx.x];
  lbase[threadIdx.x] = (c > 0) ? atomicAdd(&bucketfill[threadIdx.x], c) : 0;
  __syncthreads();
  lcnt[threadIdx.x] = 0;          // reuse as per-bucket cursor
  __syncthreads();
  #pragma unroll
  for (int k = 0; k < 16; ++k) {
    if (myb[k] >= 0) {
      int slot = atomicAdd(&lcnt[myb[k]], 1);
      recs[lbase[myb[k]] + slot] = make_int2(mybin[k], myt[k]);
    }
  }
}

// stage 2 (v2): per bucket, LDS histogram over local bins (<=768), LDS scan,
// write the bucket's off3 slice, then scatter ssrc via LDS cursors.
__global__ __launch_bounds__(1024) void binscatter_kernel(
    const int2* __restrict__ recs, const int* __restrict__ bucketbase,
    int* __restrict__ off3, int* __restrict__ ssrc, int W, int N, int NB)
{
  __shared__ int lh[1024];
  int b = blockIdx.x;
  int tid = threadIdx.x;
  int d0 = min(b * W, N), d1 = min((b + 1) * W, N);
  int nloc = (d1 - d0) * 3;                 // <= 768
  int s = bucketbase[b], e = bucketbase[b + 1];
  int lb0 = d0 * 3;

  lh[tid] = 0;
  __syncthreads();
  for (int i = s + tid; i < e; i += 1024)
    atomicAdd(&lh[recs[i].x - lb0], 1);
  __syncthreads();
  // inclusive scan over 1024 (bins >= nloc are zero)
  for (int d = 1; d < 1024; d <<= 1) {
    int v = (tid >= d) ? lh[tid - d] : 0;
    __syncthreads();
    lh[tid] += v;
    __syncthreads();
  }
  // write off3 slice: off3[lb0 + j] = s + excl(j)
  if (tid < nloc) off3[lb0 + tid] = s + ((tid > 0) ? lh[tid - 1] : 0);
  if (b == NB - 1 && tid == 0) off3[N * 3] = e;
  // convert to exclusive cursors
  int excl = (tid > 0) ? lh[tid - 1] : 0;
  __syncthreads();
  lh[tid] = excl;
  __syncthreads();
  for (int i = s + tid; i < e; i += 1024) {
    int2 rec = recs[i];
    int slot = atomicAdd(&lh[rec.x - lb0], 1);
    ssrc[s + slot] = rec.y;
  }
}

__global__ __launch_bounds__(256) void zeropad_kernel(const int* __restrict__ roleinfo,
                                                      bf16* __restrict__ Ax, bf16* __restrict__ Ah)
{
  int id = blockIdx.x * 256 + threadIdx.x;   // 98304
  int a = id / 49152, rem = id % 49152;
  int gp = rem / 16384, r2 = rem % 16384;
  int rr = r2 >> 6, c = r2 & 63;
  int gs = roleinfo[2 + gp * 2], gl = roleinfo[3 + gp * 2];
  if (rr < gl) {
    int row = gs + rr;
    size_t unit = (size_t)(row >> 4) * 1024 + c * 16 + (row & 15);
    bf16x8 z = {};
    ((bf16x8*)(a == 0 ? Ax : Ah))[unit] = z;
  }
}

// ---------------- prep (t-major: contiguous writes, full-line random reads) ----------------
__global__ __launch_bounds__(256) void prep_xh_kernel(const float* __restrict__ x, const float* __restrict__ h,
                                                      const int* __restrict__ sposinv, u8* __restrict__ xq8,
                                                      bf16* __restrict__ Ax, bf16* __restrict__ Ah, int rows_pad)
{
  int g = blockIdx.x * 256 + threadIdx.x;
  if (g >= rows_pad * 32) return;
  int t = g >> 5, j = g & 31;
  int n = sposinv[t];
  if (n < 0) return;                       // pad rows: A filled by zeropad; xq8 never read
  const float* src = (j < 16) ? (x + (size_t)n * 128 + (j << 3))
                              : (h + (size_t)n * 128 + ((j - 16) << 3));
  float4 v0 = ((const float4*)src)[0];
  float4 v1 = ((const float4*)src)[1];
  int lo = __builtin_amdgcn_cvt_pk_fp8_f32(v0.x, v0.y, 0, false);
  lo = __builtin_amdgcn_cvt_pk_fp8_f32(v0.z, v0.w, lo, true);
  int hi = __builtin_amdgcn_cvt_pk_fp8_f32(v1.x, v1.y, 0, false);
  hi = __builtin_amdgcn_cvt_pk_fp8_f32(v1.z, v1.w, hi, true);
  *(int2*)(xq8 + (size_t)t * 256 + j * 8) = make_int2(lo, hi);
  bf16x8 o;
  o[0] = (bf16)v0.x; o[1] = (bf16)v0.y; o[2] = (bf16)v0.z; o[3] = (bf16)v0.w;
  o[4] = (bf16)v1.x; o[5] = (bf16)v1.y; o[6] = (bf16)v1.z; o[7] = (bf16)v1.w;
  size_t unit = (size_t)(t >> 4) * 1024 + (48 + (j & 15)) * 16 + (t & 15);
  ((bf16x8*)(j < 16 ? Ax : Ah))[unit] = o;
}

struct PrepW { const float* W[6]; const float* Wg[6]; const float* bg[6]; };
__global__ __launch_bounds__(256) void prep_wf_kernel(PrepW pw, bf16* __restrict__ Wf)
{
  int idx = blockIdx.x * 256 + threadIdx.x;
  if (idx >= 294912) return;
  int cv = idx / 49152, pos = idx % 49152;
  int ks4q = pos >> 10;
  int col = (pos >> 3) & 127, j = pos & 7;
  int k = (ks4q >> 2) * 32 + (ks4q & 3) * 8 + j;
  int r = k >> 7, kk = k & 127;
  float g = sigmoidf_(pw.Wg[cv][r * 128 + col] + pw.bg[cv][r * 128 + col]);
  Wf[idx] = (bf16)(pw.W[cv][kk * 128 + col] * g);
}

struct PrepP { const float* W[6]; const float* S[6]; };
__global__ __launch_bounds__(128) void prep_pf_kernel(PrepP pp, bf16* __restrict__ Pf)
{
  int b = blockIdx.x;                          // 6*3*128
  int cv = b / 384, rem = b % 384;
  int r = rem >> 7, kp = rem & 127;
  int col = threadIdx.x;
  const float* W = pp.W[cv] + (size_t)kp * 128;
  const float* S = pp.S[cv] + (size_t)r * 16384;
  float sum = 0.f;
  #pragma unroll 4
  for (int j2 = 0; j2 < 128; ++j2) sum += W[j2] * S[j2 * 128 + col];
  size_t o = (size_t)(cv * 3 + r) * 16384 + ((size_t)(kp >> 3) * 128 + col) * 8 + (kp & 7);
  Pf[o] = (bf16)sum;
}

// ---------------- gathers (t-ordered 8-node blocks, cooperative full-line NT writes) ----------------
#define ACCUM16(U, d) do { f32x2 f_;                                                   \
  f_ = __builtin_amdgcn_cvt_pk_f32_fp8((d).x, false); U[0]  += f_[0]; U[1]  += f_[1];  \
  f_ = __builtin_amdgcn_cvt_pk_f32_fp8((d).x, true);  U[2]  += f_[0]; U[3]  += f_[1];  \
  f_ = __builtin_amdgcn_cvt_pk_f32_fp8((d).y, false); U[4]  += f_[0]; U[5]  += f_[1];  \
  f_ = __builtin_amdgcn_cvt_pk_f32_fp8((d).y, true);  U[6]  += f_[0]; U[7]  += f_[1];  \
  f_ = __builtin_amdgcn_cvt_pk_f32_fp8((d).z, false); U[8]  += f_[0]; U[9]  += f_[1];  \
  f_ = __builtin_amdgcn_cvt_pk_f32_fp8((d).z, true);  U[10] += f_[0]; U[11] += f_[1];  \
  f_ = __builtin_amdgcn_cvt_pk_f32_fp8((d).w, false); U[12] += f_[0]; U[13] += f_[1];  \
  f_ = __builtin_amdgcn_cvt_pk_f32_fp8((d).w, true);  U[14] += f_[0]; U[15] += f_[1];  \
} while (0)

#define ACCSEL16(d, p) do {                      \
  if ((p) < o1)      { ACCUM16(u0, d); }         \
  else if ((p) < o2) { ACCUM16(u1, d); }         \
  else               { ACCUM16(u2, d); }         \
} while (0)

__global__ __launch_bounds__(512) void gather_xh_kernel(
    const u8* __restrict__ xq8, const int* __restrict__ off3, const int* __restrict__ ssrc,
    const int* __restrict__ sposinv, bf16* __restrict__ Ax, bf16* __restrict__ Ah,
    float4* __restrict__ cntf)
{
  __shared__ alignas(16) bf16 lds[8][768];
  int w = threadIdx.x >> 6, lane = threadIdx.x & 63;
  int t0 = blockIdx.x * 8;
  int t = t0 + w;
  int node = sposinv[t];                 // -1 for pad rows
  int qt = lane >> 4, ql = lane & 15;

  if (node >= 0) {
    int o0 = __builtin_amdgcn_readfirstlane(off3[node * 3]);
    int o1 = __builtin_amdgcn_readfirstlane(off3[node * 3 + 1]);
    int o2 = __builtin_amdgcn_readfirstlane(off3[node * 3 + 2]);
    int o3 = __builtin_amdgcn_readfirstlane(off3[node * 3 + 3]);
    float inv = 1.0f / (float)(o3 - o0);
    const u8* base = xq8 + ql * 16;

    float u0[16], u1[16], u2[16];
    #pragma unroll
    for (int k = 0; k < 16; ++k) { u0[k] = 0.f; u1[k] = 0.f; u2[k] = 0.f; }

    const int e = o3, emax = o3 - 1;
    for (int i = o0; i < e; i += 16) {
      int p0 = i + qt, p1 = p0 + 4, p2 = p0 + 8, p3 = p0 + 12;
      int t0i = ssrc[min(p0, emax)];
      int t1i = ssrc[min(p1, emax)];
      int t2i = ssrc[min(p2, emax)];
      int t3i = ssrc[min(p3, emax)];
      int4 d0 = make_int4(0, 0, 0, 0), d1 = d0, d2 = d0, d3 = d0;
      if (p0 < e) d0 = *(const int4*)(base + (size_t)t0i * 256);
      if (p1 < e) d1 = *(const int4*)(base + (size_t)t1i * 256);
      if (p2 < e) d2 = *(const int4*)(base + (size_t)t2i * 256);
      if (p3 < e) d3 = *(const int4*)(base + (size_t)t3i * 256);
      ACCSEL16(d0, p0);
      ACCSEL16(d1, p1);
      ACCSEL16(d2, p2);
      ACCSEL16(d3, p3);
    }

    #pragma unroll
    for (int k = 0; k < 16; ++k) {
      u0[k] += __shfl_xor(u0[k], 16); u0[k] += __shfl_xor(u0[k], 32);
      u1[k] += __shfl_xor(u1[k], 16); u1[k] += __shfl_xor(u1[k], 32);
      u2[k] += __shfl_xor(u2[k], 16); u2[k] += __shfl_xor(u2[k], 32);
    }
    if (qt == 0) {
      bf16x8 p0v, p1v;
      int sb0 = (ql < 8) ? (ql * 16) : (384 + (ql - 8) * 16);
      #pragma unroll
      for (int k = 0; k < 8; ++k) { p0v[k] = (bf16)(u0[k] * inv); p1v[k] = (bf16)(u0[8 + k] * inv); }
      *(bf16x8*)&lds[w][sb0] = p0v;
      *(bf16x8*)&lds[w][sb0 + 8] = p1v;
      #pragma unroll
      for (int k = 0; k < 8; ++k) { p0v[k] = (bf16)(u1[k] * inv); p1v[k] = (bf16)(u1[8 + k] * inv); }
      *(bf16x8*)&lds[w][sb0 + 128] = p0v;
      *(bf16x8*)&lds[w][sb0 + 136] = p1v;
      #pragma unroll
      for (int k = 0; k < 8; ++k) { p0v[k] = (bf16)(u2[k] * inv); p1v[k] = (bf16)(u2[8 + k] * inv); }
      *(bf16x8*)&lds[w][sb0 + 256] = p0v;
      *(bf16x8*)&lds[w][sb0 + 264] = p1v;
    }
    if (lane == 0)
      cntf[t] = make_float4((o1 - o0) * inv, (o2 - o1) * inv, (o3 - o2) * inv, (float)(o3 - o0));
  } else {
    // pad row: zero-fill this wave's LDS section so the cooperative write stores zeros
    if (lane < 48) {
      bf16x8 z = {};
      *(bf16x8*)&lds[w][lane * 16] = z;
      *(bf16x8*)&lds[w][lane * 16 + 8] = z;
    }
    if (lane == 0) cntf[t] = make_float4(0.f, 0.f, 0.f, 0.f);
  }

  __syncthreads();

  // cooperative write: 8 consecutive rows (t0..t0+7, same 16-group) -> full 128-B lines
  int tid = threadIdx.x;
  if (tid < 384) {
    int lc = tid >> 3, row = tid & 7;
    size_t unit = (size_t)(t0 >> 4) * 1024 + lc * 16 + (t0 & 15) + row;
    __builtin_nontemporal_store(*(const bf16x8*)&lds[row][lc * 8], (bf16x8*)Ax + unit);
    __builtin_nontemporal_store(*(const bf16x8*)&lds[row][384 + lc * 8], (bf16x8*)Ah + unit);
  }
}

#define ACCUM8(U, d) do { f32x2 f_;                                                  \
  f_ = __builtin_amdgcn_cvt_pk_f32_fp8((d).x, false); U[0] += f_[0]; U[1] += f_[1];  \
  f_ = __builtin_amdgcn_cvt_pk_f32_fp8((d).x, true);  U[2] += f_[0]; U[3] += f_[1];  \
  f_ = __builtin_amdgcn_cvt_pk_f32_fp8((d).y, false); U[4] += f_[0]; U[5] += f_[1];  \
  f_ = __builtin_amdgcn_cvt_pk_f32_fp8((d).y, true);  U[6] += f_[0]; U[7] += f_[1];  \
} while (0)

#define ACCSEL8(d, p) do {                      \
  if ((p) < o1)      { ACCUM8(v0, d); }         \
  else if ((p) < o2) { ACCUM8(v1, d); }         \
  else               { ACCUM8(v2, d); }         \
} while (0)

__global__ __launch_bounds__(512) void gather_q_kernel(
    const u8* __restrict__ q8, const int* __restrict__ off3, const int* __restrict__ ssrc,
    const int* __restrict__ sposinv, bf16* __restrict__ Aq)
{
  __shared__ alignas(16) bf16 lds[8][384];
  int w = threadIdx.x >> 6, lane = threadIdx.x & 63;
  int t0 = blockIdx.x * 8;
  int t = t0 + w;
  int node = sposinv[t];
  int qt = lane >> 4, ql = lane & 15;

  if (node >= 0) {
    int o0 = __builtin_amdgcn_readfirstlane(off3[node * 3]);
    int o1 = __builtin_amdgcn_readfirstlane(off3[node * 3 + 1]);
    int o2 = __builtin_amdgcn_readfirstlane(off3[node * 3 + 2]);
    int o3 = __builtin_amdgcn_readfirstlane(off3[node * 3 + 3]);
    float inv = 1.0f / (float)(o3 - o0);
    const u8* base = q8 + ql * 8;

    float v0[8], v1[8], v2[8];
    #pragma unroll
    for (int k = 0; k < 8; ++k) { v0[k] = 0.f; v1[k] = 0.f; v2[k] = 0.f; }

    const int e = o3, emax = o3 - 1;
    for (int i = o0; i < e; i += 16) {
      int p0 = i + qt, p1 = p0 + 4, p2 = p0 + 8, p3 = p0 + 12;
      int t0i = ssrc[min(p0, emax)];
      int t1i = ssrc[min(p1, emax)];
      int t2i = ssrc[min(p2, emax)];
      int t3i = ssrc[min(p3, emax)];
      int2 d0 = make_int2(0, 0), d1 = d0, d2 = d0, d3 = d0;
      if (p0 < e) d0 = *(const int2*)(base + (size_t)t0i * 128);
      if (p1 < e) d1 = *(const int2*)(base + (size_t)t1i * 128);
      if (p2 < e) d2 = *(const int2*)(base + (size_t)t2i * 128);
      if (p3 < e) d3 = *(const int2*)(base + (size_t)t3i * 128);
      ACCSEL8(d0, p0);
      ACCSEL8(d1, p1);
      ACCSEL8(d2, p2);
      ACCSEL8(d3, p3);
    }

    #pragma unroll
    for (int k = 0; k < 8; ++k) {
      v0[k] += __shfl_xor(v0[k], 16); v0[k] += __shfl_xor(v0[k], 32);
      v1[k] += __shfl_xor(v1[k], 16); v1[k] += __shfl_xor(v1[k], 32);
      v2[k] += __shfl_xor(v2[k], 16); v2[k] += __shfl_xor(v2[k], 32);
    }
    if (qt == 0) {
      bf16x8 pk;
      #pragma unroll
      for (int k = 0; k < 8; ++k) pk[k] = (bf16)(v0[k] * inv);
      *(bf16x8*)&lds[w][ql * 8] = pk;
      #pragma unroll
      for (int k = 0; k < 8; ++k) pk[k] = (bf16)(v1[k] * inv);
      *(bf16x8*)&lds[w][128 + ql * 8] = pk;
      #pragma unroll
      for (int k = 0; k < 8; ++k) pk[k] = (bf16)(v2[k] * inv);
      *(bf16x8*)&lds[w][256 + ql * 8] = pk;
    }
  } else {
    if (lane < 48) {
      bf16x8 z = {};
      *(bf16x8*)&lds[w][lane * 8] = z;
    }
  }

  __syncthreads();

  int tid = threadIdx.x;
  if (tid < 384) {
    int lc = tid >> 3, row = tid & 7;
    size_t unit = (size_t)(t0 >> 4) * 1024 + lc * 16 + (t0 & 15) + row;
    __builtin_nontemporal_store(*(const bf16x8*)&lds[row][lc * 8], (bf16x8*)Aq + unit);
  }
}

// ---------------- streaming MFMA GEMM (grid = (conv, tile); 2 row-blocks/wave, 3 waves/SIMD) --
struct GArgs {
  const bf16* Ap[5];
  const bf16* wf[5];
  const bf16* pf[5];
  bf16* out[5];
  const float* bias[5];
};

__global__ __launch_bounds__(256, 3) void gemm_kernel(GArgs ga, const float4* __restrict__ cntf,
                                                      const int* __restrict__ roleinfo)
{
  const int cv = blockIdx.x;           // conv varies fastest -> same A-tile L2-hot across convs
  const int tile = blockIdx.y;
  const bf16* __restrict__ Ap = ga.Ap[cv];
  const bf16* __restrict__ wf = ga.wf[cv];
  const bf16* __restrict__ pf = ga.pf[cv];
  bf16* __restrict__ out = ga.out[cv];
  const float* __restrict__ bias = ga.bias[cv];

  const int w = threadIdx.x >> 6, lane = threadIdx.x & 63;
  const int q = lane >> 4, l = lane & 15;
  const int rb0 = tile * 8 + w * 2;
  const int row0 = tile * 128;
  const int s1 = roleinfo[0], s2 = roleinfo[1];
  const int role = (row0 >= s2) ? 2 : (row0 >= s1) ? 1 : 0;
  const int laneoff = q * 128 + l;

  f32x4 acc[2][8];
  #pragma unroll
  for (int j = 0; j < 2; ++j)
    #pragma unroll
    for (int ct = 0; ct < 8; ++ct)
      #pragma unroll
      for (int k = 0; k < 4; ++k) acc[j][ct][k] = 0.f;

  const bf16x8* A0 = (const bf16x8*)Ap + (size_t)rb0 * 1024 + lane;
  const bf16x8* WF = (const bf16x8*)wf + laneoff;
  const bf16x8* PF = (const bf16x8*)pf + role * 2048 + laneoff;

  #pragma unroll 2
  for (int ks = 0; ks < 16; ++ks) {
    const bf16x8* bp = (ks < 12) ? (WF + ks * 512) : (PF + (ks - 12) * 512);
    bf16x8 a0 = A0[ks * 64];
    bf16x8 a1 = A0[1024 + ks * 64];
    #pragma unroll
    for (int ct = 0; ct < 8; ++ct) {
      bf16x8 b = bp[ct * 16];
      acc[0][ct] = __builtin_amdgcn_mfma_f32_16x16x32_bf16(a0, b, acc[0][ct], 0, 0, 0);
      acc[1][ct] = __builtin_amdgcn_mfma_f32_16x16x32_bf16(a1, b, acc[1][ct], 0, 0, 0);
    }
  }

  const bool hb = (bias != nullptr);
  #pragma unroll
  for (int j = 0; j < 2; ++j) {
    int rb = rb0 + j;
    float4 cfs[4];
    if (hb) {
      #pragma unroll
      for (int reg = 0; reg < 4; ++reg) cfs[reg] = cntf[rb * 16 + q * 4 + reg];
    }
    #pragma unroll
    for (int ct = 0; ct < 8; ++ct) {
      int col = ct * 16 + l;
      float b0 = 0, b1 = 0, b2 = 0;
      if (hb) { b0 = bias[col]; b1 = bias[128 + col]; b2 = bias[256 + col]; }
      #pragma unroll
      for (int reg = 0; reg < 4; ++reg) {
        int t = rb * 16 + q * 4 + reg;
        float v = acc[j][ct][reg];
        if (hb) v += cfs[reg].x * b0 + cfs[reg].y * b1 + cfs[reg].z * b2;
        out[(size_t)t * 128 + col] = (bf16)fmaxf(v, 0.f);
      }
    }
  }
}

// ---------------- combines ----------------
__global__ __launch_bounds__(256) void combine1_kernel(
    const bf16* __restrict__ o0, const bf16* __restrict__ o1,
    const bf16* __restrict__ o2, const bf16* __restrict__ o3,
    const float* __restrict__ h, const int* __restrict__ spos,
    float* __restrict__ zbuf, u8* __restrict__ q8, bf16* __restrict__ Aq, int N)
{
  int g = blockIdx.x * 256 + threadIdx.x;
  if (g >= N * 16) return;
  int n = g >> 4, o = g & 15;
  int t = spos[n];
  size_t tb = (size_t)t * 16 + o;
  bf16x8 a0 = ((const bf16x8*)o0)[tb];
  bf16x8 a1 = ((const bf16x8*)o1)[tb];
  bf16x8 a2 = ((const bf16x8*)o2)[tb];
  bf16x8 a3 = ((const bf16x8*)o3)[tb];
  size_t nb = (size_t)n * 16 + o;
  float4 h0 = ((const float4*)h)[nb * 2];
  float4 h1 = ((const float4*)h)[nb * 2 + 1];
  float hv[8] = {h0.x, h0.y, h0.z, h0.w, h1.x, h1.y, h1.z, h1.w};
  float zv[8], qv[8];
  bf16x8 qb;
  #pragma unroll
  for (int j = 0; j < 8; ++j) {
    zv[j] = sigmoidf_((float)a0[j] + (float)a1[j]);
    qv[j] = sigmoidf_((float)a2[j] + (float)a3[j]) * hv[j];
    qb[j] = (bf16)qv[j];
  }
  ((float4*)zbuf)[nb * 2]     = make_float4(zv[0], zv[1], zv[2], zv[3]);
  ((float4*)zbuf)[nb * 2 + 1] = make_float4(zv[4], zv[5], zv[6], zv[7]);
  int lo = __builtin_amdgcn_cvt_pk_fp8_f32(qv[0], qv[1], 0, false);
  lo = __builtin_amdgcn_cvt_pk_fp8_f32(qv[2], qv[3], lo, true);
  int hi = __builtin_amdgcn_cvt_pk_fp8_f32(qv[4], qv[5], 0, false);
  hi = __builtin_amdgcn_cvt_pk_fp8_f32(qv[6], qv[7], hi, true);
  *(int2*)(q8 + (size_t)t * 128 + o * 8) = make_int2(lo, hi);
  size_t unit = (size_t)(t >> 4) * 1024 + (48 + o) * 16 + (t & 15);
  ((bf16x8*)Aq)[unit] = qb;
}

__global__ __launch_bounds__(256) void combine2_kernel(
    const float* __restrict__ zbuf, const bf16* __restrict__ o4, const bf16* __restrict__ o5,
    const float* __restrict__ h, const int* __restrict__ spos, float* __restrict__ out, int N)
{
  int g = blockIdx.x * 256 + threadIdx.x;
  if (g >= N * 16) return;
  int n = g >> 4, o = g & 15;
  int t = spos[n];
  size_t tb = (size_t)t * 16 + o;
  bf16x8 a = ((const bf16x8*)o4)[tb];
  bf16x8 b = ((const bf16x8*)o5)[tb];
  size_t nb = (size_t)n * 16 + o;
  float4 z0 = ((const float4*)zbuf)[nb * 2];
  float4 z1 = ((const float4*)zbuf)[nb * 2 + 1];
  float4 h0 = ((const float4*)h)[nb * 2];
  float4 h1 = ((const float4*)h)[nb * 2 + 1];
  float zv[8] = {z0.x, z0.y, z0.z, z0.w, z1.x, z1.y, z1.z, z1.w};
  float hv[8] = {h0.x, h0.y, h0.z, h0.w, h1.x, h1.y, h1.z, h1.w};
  float ov[8];
  #pragma unroll
  for (int j = 0; j < 8; ++j)
    ov[j] = zv[j] * hv[j] + (1.f - zv[j]) * tanhf((float)a[j] + (float)b[j]);
  ((float4*)out)[nb * 2]     = make_float4(ov[0], ov[1], ov[2], ov[3]);
  ((float4*)out)[nb * 2 + 1] = make_float4(ov[4], ov[5], ov[6], ov[7]);
}

// ---------------- host ----------------
extern "C" void kernel_launch(void* const* d_in, const int* in_sizes, int n_in,
                              void* d_out, int out_size, void* d_ws, size_t ws_size,
                              hipStream_t stream)
{
  (void)n_in; (void)out_size; (void)ws_size;
  const float* x    = (const float*)d_in[0];
  const float* h    = (const float*)d_in[1];
  const int*   ei   = (const int*)d_in[2];
  const int*   role = (const int*)d_in[3];
  const int N = in_sizes[0] / DH;
  const int E = in_sizes[2] / 2;
  const int Etot = E + N;
  const int rows_pad = ((N + 765) + 255) & ~255;
  const int gx = rows_pad / 128;
  const int n3 = N * 3;

  // bucket geometry: <=256 buckets of W=2^shiftB dst rows (N=50000 -> shiftB=8, W=256, NB=196)
  int shiftB = 8;
  while (((N - 1) >> shiftB) >= 256) ++shiftB;
  const int W = 1 << shiftB;
  const int NB = (N + W - 1) >> shiftB;

  // conv order: 0 xz, 1 hz, 2 xr, 3 hr, 4 xh, 5 hh
  static const int Wi[6]  = {4, 9, 13, 18, 22, 27};
  static const int Wgi[6] = {5, 10, 14, 19, 23, 28};
  static const int bgi[6] = {6, 11, 15, 20, 24, 29};
  static const int Si[6]  = {7, 12, 16, 21, 25, 30};

  char* p = (char*)d_ws;
  auto alloc = [&](size_t bytes) -> char* {
    char* r = p;
    p += (bytes + 255) & ~(size_t)255;
    return r;
  };

  bf16* Ax = (bf16*)alloc((size_t)rows_pad * 512 * 2);   // Aq aliases Ax
  bf16* Ah = (bf16*)alloc((size_t)rows_pad * 512 * 2);
  bf16* Aq = Ax;
  u8* xq8  = (u8*)alloc((size_t)rows_pad * 256);
  u8* q8   = (u8*)alloc((size_t)rows_pad * 128);
  bf16* outs[6];
  for (int c = 0; c < 5; ++c) outs[c] = (bf16*)alloc((size_t)rows_pad * 128 * 2);
  outs[5] = outs[0];
  float* zbuf = (float*)alloc((size_t)N * 128 * 4);
  float4* cntf = (float4*)alloc((size_t)rows_pad * 16);
  bf16* Wf = (bf16*)alloc((size_t)6 * 49152 * 2);
  bf16* Pf = (bf16*)alloc((size_t)18 * 16384 * 2);
  int* off3  = (int*)alloc((size_t)(n3 + 1) * 4);
  int* ssrc  = (int*)alloc((size_t)Etot * 4);
  int2* recs = (int2*)alloc((size_t)Etot * 8);
  int* spos  = (int*)alloc((size_t)N * 4);
  int* sposinv = (int*)alloc((size_t)rows_pad * 4);
  int* rolecnt  = (int*)alloc(64);
  int* rolefill = (int*)alloc(64);
  int* roleinfo = (int*)alloc(64);
  int* bucketcnt  = (int*)alloc(257 * 4);
  int* bucketbase = (int*)alloc(258 * 4);
  int* bucketfill = (int*)alloc(257 * 4);

  hipMemsetAsync(rolecnt, 0, 16, stream);
  hipMemsetAsync(bucketcnt, 0, 257 * 4, stream);
  hipMemsetAsync(sposinv, 0xFF, (size_t)rows_pad * 4, stream);   // -1 = pad row

  int egrid4k = (Etot + 4095) / 4096;
  int ngrid = (N + 255) / 256;
  rolecnt_kernel<<<ngrid, 256, 0, stream>>>(role, rolecnt, N);
  roleinfo_kernel<<<1, 64, 0, stream>>>(rolecnt, rolefill, roleinfo);
  permscatter_kernel<<<ngrid, 256, 0, stream>>>(role, rolefill, spos, sposinv, N);
  coarsehist_kernel<<<egrid4k, 256, 0, stream>>>(ei, bucketcnt, E, N, shiftB);
  bucketscan_kernel<<<1, 256, 0, stream>>>(bucketcnt, bucketbase, bucketfill, NB);
  partition_kernel<<<egrid4k, 256, 0, stream>>>(ei, spos, roleinfo, bucketfill,
                                                recs, E, N, shiftB);
  binscatter_kernel<<<NB, 1024, 0, stream>>>(recs, bucketbase, off3, ssrc, W, N, NB);
  zeropad_kernel<<<384, 256, 0, stream>>>(roleinfo, Ax, Ah);

  prep_xh_kernel<<<(rows_pad * 32 + 255) / 256, 256, 0, stream>>>(x, h, sposinv, xq8, Ax, Ah, rows_pad);

  PrepW pw;
  for (int c = 0; c < 6; ++c) {
    pw.W[c] = (const float*)d_in[Wi[c]];
    pw.Wg[c] = (const float*)d_in[Wgi[c]];
    pw.bg[c] = (const float*)d_in[bgi[c]];
  }
  prep_wf_kernel<<<1152, 256, 0, stream>>>(pw, Wf);
  PrepP pp;
  for (int c = 0; c < 6; ++c) { pp.W[c] = (const float*)d_in[Wi[c]]; pp.S[c] = (const float*)d_in[Si[c]]; }
  prep_pf_kernel<<<2304, 128, 0, stream>>>(pp, Pf);

  gather_xh_kernel<<<rows_pad / 8, 512, 0, stream>>>(xq8, off3, ssrc, sposinv, Ax, Ah, cntf);

  // pass 1: one dispatch, cv 0..4 = {xz,xr,xh on Ax (bias)} + {hz,hr on Ah}; conv fastest
  GArgs g0;
  { int cvs[5] = {0, 2, 4, 1, 3};
    static const int bi2[5] = {8, 17, 26, -1, -1};
    const bf16* Apts[5] = {Ax, Ax, Ax, Ah, Ah};
    for (int k = 0; k < 5; ++k) {
      int c = cvs[k];
      g0.Ap[k] = Apts[k];
      g0.wf[k] = Wf + (size_t)c * 49152;
      g0.pf[k] = Pf + (size_t)c * 3 * 16384;
      g0.out[k] = outs[c];
      g0.bias[k] = (bi2[k] >= 0) ? (const float*)d_in[bi2[k]] : nullptr;
    } }
  gemm_kernel<<<dim3(5, gx), 256, 0, stream>>>(g0, cntf, roleinfo);

  combine1_kernel<<<(N * 16 + 255) / 256, 256, 0, stream>>>(outs[0], outs[1], outs[2], outs[3],
                                                            h, spos, zbuf, q8, Aq, N);

  gather_q_kernel<<<rows_pad / 8, 512, 0, stream>>>(q8, off3, ssrc, sposinv, Aq);

  // pass 2: conv hh(5) on Aq
  GArgs g2 = {};
  g2.Ap[0] = Aq;
  g2.wf[0] = Wf + (size_t)5 * 49152;
  g2.pf[0] = Pf + (size_t)5 * 3 * 16384;
  g2.out[0] = outs[5];
  g2.bias[0] = nullptr;
  gemm_kernel<<<dim3(1, gx), 256, 0, stream>>>(g2, cntf, roleinfo);

  combine2_kernel<<<(N * 16 + 255) / 256, 256, 0, stream>>>(zbuf, outs[4], outs[5], h, spos,
                                                            (float*)d_out, N);
}

// Round 12
// 601.602 us; speedup vs baseline: 1.9311x; 1.0150x over previous
//
#include <hip/hip_runtime.h>

// GraphGRU on MI355X — round 18.
//   Combine chain restructured (base r17 = 610.6 µs; gather/CSR/gemm/prep untouched):
//   - zbuf ELIMINATED: combine2 recomputes z = sigmoid(o0+o1) from the bf16 outs directly
//     (byte-identical arithmetic; zbuf stored the same f32 result). Removes 24.5 MB f32 write
//     + 49 MB f32 read; combine1 no longer reads o0/o1 at all.
//   - combines flipped t-major: outs reads contiguous, q8/Aq self-part writes line-mergeable
//     (was random-t 16-B scatter = partial-line amplification).
//   - outs[5] un-aliased from outs[0] (combine2 needs o0 alive for z).

typedef __bf16 bf16;
typedef __bf16 bf16x8 __attribute__((ext_vector_type(8)));
typedef float  f32x4  __attribute__((ext_vector_type(4)));
typedef float  f32x2  __attribute__((ext_vector_type(2)));
typedef unsigned char u8;

#define DH 128

__device__ __forceinline__ float sigmoidf_(float x) { return 1.0f / (1.0f + expf(-x)); }

// ---------------- CSR build (bucket-local) ----------------
__global__ __launch_bounds__(256) void rolecnt_kernel(const int* __restrict__ role,
                                                      int* __restrict__ rolecnt, int N)
{
  int i = blockIdx.x * 256 + threadIdx.x;
  int lane = threadIdx.x & 63;
  int r = (i < N) ? role[i] : -1;
  #pragma unroll
  for (int rr = 0; rr < 3; ++rr) {
    unsigned long long mask = __ballot(r == rr);
    if (lane == 0 && mask) atomicAdd(&rolecnt[rr], __popcll(mask));
  }
}

__global__ void roleinfo_kernel(const int* __restrict__ rolecnt,
                                int* __restrict__ rolefill, int* __restrict__ roleinfo)
{
  if (threadIdx.x == 0) {
    int c0 = rolecnt[0], c1 = rolecnt[1], c2 = rolecnt[2];
    int s1 = (c0 + 255) & ~255;
    int s2 = s1 + ((c1 + 255) & ~255);
    int mp = s2 + ((c2 + 255) & ~255);
    rolefill[0] = 0; rolefill[1] = s1; rolefill[2] = s2;
    roleinfo[0] = s1; roleinfo[1] = s2;
    roleinfo[2] = c0;      roleinfo[3] = s1 - c0;
    roleinfo[4] = s1 + c1; roleinfo[5] = s2 - s1 - c1;
    roleinfo[6] = s2 + c2; roleinfo[7] = mp - s2 - c2;
  }
}

__global__ __launch_bounds__(256) void permscatter_kernel(const int* __restrict__ role, int* __restrict__ rolefill,
                                                          int* __restrict__ spos, int* __restrict__ sposinv, int N)
{
  int i = blockIdx.x * 256 + threadIdx.x;
  int lane = threadIdx.x & 63;
  int r = (i < N) ? role[i] : -1;
  #pragma unroll
  for (int rr = 0; rr < 3; ++rr) {
    unsigned long long mask = __ballot(r == rr);
    if (!mask) continue;
    int base = 0;
    if (lane == 0) base = atomicAdd(&rolefill[rr], __popcll(mask));
    base = __shfl(base, 0);
    if (r == rr) {
      int rank = (int)__popcll(mask & ((1ull << lane) - 1ull));
      int pos = base + rank;
      spos[i] = pos;
      sposinv[pos] = i;
    }
  }
}

// coarse per-bucket edge counts (bucket = dst >> shiftB, <=256 buckets)
__global__ __launch_bounds__(256) void coarsehist_kernel(const int* __restrict__ ei,
                                                         int* __restrict__ bucketcnt,
                                                         int E, int N, int shiftB)
{
  __shared__ int lc[256];
  lc[threadIdx.x] = 0;
  __syncthreads();
  const int base = blockIdx.x * 4096;
  #pragma unroll
  for (int k = 0; k < 16; ++k) {
    int i = base + k * 256 + threadIdx.x;
    if (i < E + N) {
      int dst = (i < E) ? ei[E + i] : i - E;
      atomicAdd(&lc[dst >> shiftB], 1);
    }
  }
  __syncthreads();
  int c = lc[threadIdx.x];
  if (c > 0) atomicAdd(&bucketcnt[threadIdx.x], c);
}

// single-block scan of bucket counts -> bucketbase (excl, +total at [NB]) and bucketfill
__global__ __launch_bounds__(256) void bucketscan_kernel(const int* __restrict__ bucketcnt,
                                                         int* __restrict__ bucketbase,
                                                         int* __restrict__ bucketfill, int NB)
{
  __shared__ int lh[256];
  int tid = threadIdx.x;
  lh[tid] = (tid < NB) ? bucketcnt[tid] : 0;
  __syncthreads();
  for (int d = 1; d < 256; d <<= 1) {
    int v = (tid >= d) ? lh[tid - d] : 0;
    __syncthreads();
    lh[tid] += v;
    __syncthreads();
  }
  int excl = (tid > 0) ? lh[tid - 1] : 0;
  if (tid < NB) { bucketbase[tid] = excl; bucketfill[tid] = excl; }
  if (tid == 0) bucketbase[NB] = lh[255];
}

// stage 1: partition edges into dst-range buckets; records = (bin, t)
__global__ __launch_bounds__(256) void partition_kernel(
    const int* __restrict__ ei, const int* __restrict__ spos,
    const int* __restrict__ roleinfo, int* __restrict__ bucketfill,
    int2* __restrict__ recs, int E, int N, int shiftB)
{
  __shared__ int lcnt[256], lbase[256];
  const int base = blockIdx.x * 4096;
  const int s1 = roleinfo[0], s2 = roleinfo[1];
  lcnt[threadIdx.x] = 0;
  __syncthreads();
  int myb[16], mybin[16], myt[16];
  #pragma unroll
  for (int k = 0; k < 16; ++k) {
    int i = base + k * 256 + threadIdx.x;
    myb[k] = -1;
    if (i < E + N) {
      int src, dst;
      if (i < E) { src = ei[i]; dst = ei[E + i]; } else { src = i - E; dst = i - E; }
      int t = spos[src];
      int r = (t >= s2) ? 2 : (t >= s1) ? 1 : 0;
      myb[k] = dst >> shiftB;
      mybin[k] = dst * 3 + r;
      myt[k] = t;
      atomicAdd(&lcnt[myb[k]], 1);
    }
  }
  __syncthreads();
  int c = lcnt[threadIdx.x];
  lbase[threadIdx.x] = (c > 0) ? atomicAdd(&bucketfill[threadIdx.x], c) : 0;
  __syncthreads();
  lcnt[threadIdx.x] = 0;          // reuse as per-bucket cursor
  __syncthreads();
  #pragma unroll
  for (int k = 0; k < 16; ++k) {
    if (myb[k] >= 0) {
      int slot = atomicAdd(&lcnt[myb[k]], 1);
      recs[lbase[myb[k]] + slot] = make_int2(mybin[k], myt[k]);
    }
  }
}

// stage 2 (v2): per bucket, LDS histogram over local bins (<=768), LDS scan,
// write the bucket's off3 slice, then scatter ssrc via LDS cursors.
__global__ __launch_bounds__(1024) void binscatter_kernel(
    const int2* __restrict__ recs, const int* __restrict__ bucketbase,
    int* __restrict__ off3, int* __restrict__ ssrc, int W, int N, int NB)
{
  __shared__ int lh[1024];
  int b = blockIdx.x;
  int tid = threadIdx.x;
  int d0 = min(b * W, N), d1 = min((b + 1) * W, N);
  int nloc = (d1 - d0) * 3;                 // <= 768
  int s = bucketbase[b], e = bucketbase[b + 1];
  int lb0 = d0 * 3;

  lh[tid] = 0;
  __syncthreads();
  for (int i = s + tid; i < e; i += 1024)
    atomicAdd(&lh[recs[i].x - lb0], 1);
  __syncthreads();
  // inclusive scan over 1024 (bins >= nloc are zero)
  for (int d = 1; d < 1024; d <<= 1) {
    int v = (tid >= d) ? lh[tid - d] : 0;
    __syncthreads();
    lh[tid] += v;
    __syncthreads();
  }
  // write off3 slice: off3[lb0 + j] = s + excl(j)
  if (tid < nloc) off3[lb0 + tid] = s + ((tid > 0) ? lh[tid - 1] : 0);
  if (b == NB - 1 && tid == 0) off3[N * 3] = e;
  // convert to exclusive cursors
  int excl = (tid > 0) ? lh[tid - 1] : 0;
  __syncthreads();
  lh[tid] = excl;
  __syncthreads();
  for (int i = s + tid; i < e; i += 1024) {
    int2 rec = recs[i];
    int slot = atomicAdd(&lh[rec.x - lb0], 1);
    ssrc[s + slot] = rec.y;
  }
}

__global__ __launch_bounds__(256) void zeropad_kernel(const int* __restrict__ roleinfo,
                                                      bf16* __restrict__ Ax, bf16* __restrict__ Ah)
{
  int id = blockIdx.x * 256 + threadIdx.x;   // 98304
  int a = id / 49152, rem = id % 49152;
  int gp = rem / 16384, r2 = rem % 16384;
  int rr = r2 >> 6, c = r2 & 63;
  int gs = roleinfo[2 + gp * 2], gl = roleinfo[3 + gp * 2];
  if (rr < gl) {
    int row = gs + rr;
    size_t unit = (size_t)(row >> 4) * 1024 + c * 16 + (row & 15);
    bf16x8 z = {};
    ((bf16x8*)(a == 0 ? Ax : Ah))[unit] = z;
  }
}

// ---------------- prep (t-major: contiguous writes, full-line random reads) ----------------
__global__ __launch_bounds__(256) void prep_xh_kernel(const float* __restrict__ x, const float* __restrict__ h,
                                                      const int* __restrict__ sposinv, u8* __restrict__ xq8,
                                                      bf16* __restrict__ Ax, bf16* __restrict__ Ah, int rows_pad)
{
  int g = blockIdx.x * 256 + threadIdx.x;
  if (g >= rows_pad * 32) return;
  int t = g >> 5, j = g & 31;
  int n = sposinv[t];
  if (n < 0) return;                       // pad rows: A filled by zeropad; xq8 never read
  const float* src = (j < 16) ? (x + (size_t)n * 128 + (j << 3))
                              : (h + (size_t)n * 128 + ((j - 16) << 3));
  float4 v0 = ((const float4*)src)[0];
  float4 v1 = ((const float4*)src)[1];
  int lo = __builtin_amdgcn_cvt_pk_fp8_f32(v0.x, v0.y, 0, false);
  lo = __builtin_amdgcn_cvt_pk_fp8_f32(v0.z, v0.w, lo, true);
  int hi = __builtin_amdgcn_cvt_pk_fp8_f32(v1.x, v1.y, 0, false);
  hi = __builtin_amdgcn_cvt_pk_fp8_f32(v1.z, v1.w, hi, true);
  *(int2*)(xq8 + (size_t)t * 256 + j * 8) = make_int2(lo, hi);
  bf16x8 o;
  o[0] = (bf16)v0.x; o[1] = (bf16)v0.y; o[2] = (bf16)v0.z; o[3] = (bf16)v0.w;
  o[4] = (bf16)v1.x; o[5] = (bf16)v1.y; o[6] = (bf16)v1.z; o[7] = (bf16)v1.w;
  size_t unit = (size_t)(t >> 4) * 1024 + (48 + (j & 15)) * 16 + (t & 15);
  ((bf16x8*)(j < 16 ? Ax : Ah))[unit] = o;
}

struct PrepW { const float* W[6]; const float* Wg[6]; const float* bg[6]; };
__global__ __launch_bounds__(256) void prep_wf_kernel(PrepW pw, bf16* __restrict__ Wf)
{
  int idx = blockIdx.x * 256 + threadIdx.x;
  if (idx >= 294912) return;
  int cv = idx / 49152, pos = idx % 49152;
  int ks4q = pos >> 10;
  int col = (pos >> 3) & 127, j = pos & 7;
  int k = (ks4q >> 2) * 32 + (ks4q & 3) * 8 + j;
  int r = k >> 7, kk = k & 127;
  float g = sigmoidf_(pw.Wg[cv][r * 128 + col] + pw.bg[cv][r * 128 + col]);
  Wf[idx] = (bf16)(pw.W[cv][kk * 128 + col] * g);
}

struct PrepP { const float* W[6]; const float* S[6]; };
__global__ __launch_bounds__(128) void prep_pf_kernel(PrepP pp, bf16* __restrict__ Pf)
{
  int b = blockIdx.x;                          // 6*3*128
  int cv = b / 384, rem = b % 384;
  int r = rem >> 7, kp = rem & 127;
  int col = threadIdx.x;
  const float* W = pp.W[cv] + (size_t)kp * 128;
  const float* S = pp.S[cv] + (size_t)r * 16384;
  float sum = 0.f;
  #pragma unroll 4
  for (int j2 = 0; j2 < 128; ++j2) sum += W[j2] * S[j2 * 128 + col];
  size_t o = (size_t)(cv * 3 + r) * 16384 + ((size_t)(kp >> 3) * 128 + col) * 8 + (kp & 7);
  Pf[o] = (bf16)sum;
}

// ---------------- gathers (t-ordered 8-node blocks, cooperative full-line NT writes) ----------------
#define ACCUM16(U, d) do { f32x2 f_;                                                   \
  f_ = __builtin_amdgcn_cvt_pk_f32_fp8((d).x, false); U[0]  += f_[0]; U[1]  += f_[1];  \
  f_ = __builtin_amdgcn_cvt_pk_f32_fp8((d).x, true);  U[2]  += f_[0]; U[3]  += f_[1];  \
  f_ = __builtin_amdgcn_cvt_pk_f32_fp8((d).y, false); U[4]  += f_[0]; U[5]  += f_[1];  \
  f_ = __builtin_amdgcn_cvt_pk_f32_fp8((d).y, true);  U[6]  += f_[0]; U[7]  += f_[1];  \
  f_ = __builtin_amdgcn_cvt_pk_f32_fp8((d).z, false); U[8]  += f_[0]; U[9]  += f_[1];  \
  f_ = __builtin_amdgcn_cvt_pk_f32_fp8((d).z, true);  U[10] += f_[0]; U[11] += f_[1];  \
  f_ = __builtin_amdgcn_cvt_pk_f32_fp8((d).w, false); U[12] += f_[0]; U[13] += f_[1];  \
  f_ = __builtin_amdgcn_cvt_pk_f32_fp8((d).w, true);  U[14] += f_[0]; U[15] += f_[1];  \
} while (0)

#define ACCSEL16(d, p) do {                      \
  if ((p) < o1)      { ACCUM16(u0, d); }         \
  else if ((p) < o2) { ACCUM16(u1, d); }         \
  else               { ACCUM16(u2, d); }         \
} while (0)

__global__ __launch_bounds__(512) void gather_xh_kernel(
    const u8* __restrict__ xq8, const int* __restrict__ off3, const int* __restrict__ ssrc,
    const int* __restrict__ sposinv, bf16* __restrict__ Ax, bf16* __restrict__ Ah,
    float4* __restrict__ cntf)
{
  __shared__ alignas(16) bf16 lds[8][768];
  int w = threadIdx.x >> 6, lane = threadIdx.x & 63;
  int t0 = blockIdx.x * 8;
  int t = t0 + w;
  int node = sposinv[t];                 // -1 for pad rows
  int qt = lane >> 4, ql = lane & 15;

  if (node >= 0) {
    int o0 = __builtin_amdgcn_readfirstlane(off3[node * 3]);
    int o1 = __builtin_amdgcn_readfirstlane(off3[node * 3 + 1]);
    int o2 = __builtin_amdgcn_readfirstlane(off3[node * 3 + 2]);
    int o3 = __builtin_amdgcn_readfirstlane(off3[node * 3 + 3]);
    float inv = 1.0f / (float)(o3 - o0);
    const u8* base = xq8 + ql * 16;

    float u0[16], u1[16], u2[16];
    #pragma unroll
    for (int k = 0; k < 16; ++k) { u0[k] = 0.f; u1[k] = 0.f; u2[k] = 0.f; }

    const int e = o3, emax = o3 - 1;
    for (int i = o0; i < e; i += 16) {
      int p0 = i + qt, p1 = p0 + 4, p2 = p0 + 8, p3 = p0 + 12;
      int t0i = ssrc[min(p0, emax)];
      int t1i = ssrc[min(p1, emax)];
      int t2i = ssrc[min(p2, emax)];
      int t3i = ssrc[min(p3, emax)];
      int4 d0 = make_int4(0, 0, 0, 0), d1 = d0, d2 = d0, d3 = d0;
      if (p0 < e) d0 = *(const int4*)(base + (size_t)t0i * 256);
      if (p1 < e) d1 = *(const int4*)(base + (size_t)t1i * 256);
      if (p2 < e) d2 = *(const int4*)(base + (size_t)t2i * 256);
      if (p3 < e) d3 = *(const int4*)(base + (size_t)t3i * 256);
      ACCSEL16(d0, p0);
      ACCSEL16(d1, p1);
      ACCSEL16(d2, p2);
      ACCSEL16(d3, p3);
    }

    #pragma unroll
    for (int k = 0; k < 16; ++k) {
      u0[k] += __shfl_xor(u0[k], 16); u0[k] += __shfl_xor(u0[k], 32);
      u1[k] += __shfl_xor(u1[k], 16); u1[k] += __shfl_xor(u1[k], 32);
      u2[k] += __shfl_xor(u2[k], 16); u2[k] += __shfl_xor(u2[k], 32);
    }
    if (qt == 0) {
      bf16x8 p0v, p1v;
      int sb0 = (ql < 8) ? (ql * 16) : (384 + (ql - 8) * 16);
      #pragma unroll
      for (int k = 0; k < 8; ++k) { p0v[k] = (bf16)(u0[k] * inv); p1v[k] = (bf16)(u0[8 + k] * inv); }
      *(bf16x8*)&lds[w][sb0] = p0v;
      *(bf16x8*)&lds[w][sb0 + 8] = p1v;
      #pragma unroll
      for (int k = 0; k < 8; ++k) { p0v[k] = (bf16)(u1[k] * inv); p1v[k] = (bf16)(u1[8 + k] * inv); }
      *(bf16x8*)&lds[w][sb0 + 128] = p0v;
      *(bf16x8*)&lds[w][sb0 + 136] = p1v;
      #pragma unroll
      for (int k = 0; k < 8; ++k) { p0v[k] = (bf16)(u2[k] * inv); p1v[k] = (bf16)(u2[8 + k] * inv); }
      *(bf16x8*)&lds[w][sb0 + 256] = p0v;
      *(bf16x8*)&lds[w][sb0 + 264] = p1v;
    }
    if (lane == 0)
      cntf[t] = make_float4((o1 - o0) * inv, (o2 - o1) * inv, (o3 - o2) * inv, (float)(o3 - o0));
  } else {
    // pad row: zero-fill this wave's LDS section so the cooperative write stores zeros
    if (lane < 48) {
      bf16x8 z = {};
      *(bf16x8*)&lds[w][lane * 16] = z;
      *(bf16x8*)&lds[w][lane * 16 + 8] = z;
    }
    if (lane == 0) cntf[t] = make_float4(0.f, 0.f, 0.f, 0.f);
  }

  __syncthreads();

  // cooperative write: 8 consecutive rows (t0..t0+7, same 16-group) -> full 128-B lines
  int tid = threadIdx.x;
  if (tid < 384) {
    int lc = tid >> 3, row = tid & 7;
    size_t unit = (size_t)(t0 >> 4) * 1024 + lc * 16 + (t0 & 15) + row;
    __builtin_nontemporal_store(*(const bf16x8*)&lds[row][lc * 8], (bf16x8*)Ax + unit);
    __builtin_nontemporal_store(*(const bf16x8*)&lds[row][384 + lc * 8], (bf16x8*)Ah + unit);
  }
}

#define ACCUM8(U, d) do { f32x2 f_;                                                  \
  f_ = __builtin_amdgcn_cvt_pk_f32_fp8((d).x, false); U[0] += f_[0]; U[1] += f_[1];  \
  f_ = __builtin_amdgcn_cvt_pk_f32_fp8((d).x, true);  U[2] += f_[0]; U[3] += f_[1];  \
  f_ = __builtin_amdgcn_cvt_pk_f32_fp8((d).y, false); U[4] += f_[0]; U[5] += f_[1];  \
  f_ = __builtin_amdgcn_cvt_pk_f32_fp8((d).y, true);  U[6] += f_[0]; U[7] += f_[1];  \
} while (0)

#define ACCSEL8(d, p) do {                      \
  if ((p) < o1)      { ACCUM8(v0, d); }         \
  else if ((p) < o2) { ACCUM8(v1, d); }         \
  else               { ACCUM8(v2, d); }         \
} while (0)

__global__ __launch_bounds__(512) void gather_q_kernel(
    const u8* __restrict__ q8, const int* __restrict__ off3, const int* __restrict__ ssrc,
    const int* __restrict__ sposinv, bf16* __restrict__ Aq)
{
  __shared__ alignas(16) bf16 lds[8][384];
  int w = threadIdx.x >> 6, lane = threadIdx.x & 63;
  int t0 = blockIdx.x * 8;
  int t = t0 + w;
  int node = sposinv[t];
  int qt = lane >> 4, ql = lane & 15;

  if (node >= 0) {
    int o0 = __builtin_amdgcn_readfirstlane(off3[node * 3]);
    int o1 = __builtin_amdgcn_readfirstlane(off3[node * 3 + 1]);
    int o2 = __builtin_amdgcn_readfirstlane(off3[node * 3 + 2]);
    int o3 = __builtin_amdgcn_readfirstlane(off3[node * 3 + 3]);
    float inv = 1.0f / (float)(o3 - o0);
    const u8* base = q8 + ql * 8;

    float v0[8], v1[8], v2[8];
    #pragma unroll
    for (int k = 0; k < 8; ++k) { v0[k] = 0.f; v1[k] = 0.f; v2[k] = 0.f; }

    const int e = o3, emax = o3 - 1;
    for (int i = o0; i < e; i += 16) {
      int p0 = i + qt, p1 = p0 + 4, p2 = p0 + 8, p3 = p0 + 12;
      int t0i = ssrc[min(p0, emax)];
      int t1i = ssrc[min(p1, emax)];
      int t2i = ssrc[min(p2, emax)];
      int t3i = ssrc[min(p3, emax)];
      int2 d0 = make_int2(0, 0), d1 = d0, d2 = d0, d3 = d0;
      if (p0 < e) d0 = *(const int2*)(base + (size_t)t0i * 128);
      if (p1 < e) d1 = *(const int2*)(base + (size_t)t1i * 128);
      if (p2 < e) d2 = *(const int2*)(base + (size_t)t2i * 128);
      if (p3 < e) d3 = *(const int2*)(base + (size_t)t3i * 128);
      ACCSEL8(d0, p0);
      ACCSEL8(d1, p1);
      ACCSEL8(d2, p2);
      ACCSEL8(d3, p3);
    }

    #pragma unroll
    for (int k = 0; k < 8; ++k) {
      v0[k] += __shfl_xor(v0[k], 16); v0[k] += __shfl_xor(v0[k], 32);
      v1[k] += __shfl_xor(v1[k], 16); v1[k] += __shfl_xor(v1[k], 32);
      v2[k] += __shfl_xor(v2[k], 16); v2[k] += __shfl_xor(v2[k], 32);
    }
    if (qt == 0) {
      bf16x8 pk;
      #pragma unroll
      for (int k = 0; k < 8; ++k) pk[k] = (bf16)(v0[k] * inv);
      *(bf16x8*)&lds[w][ql * 8] = pk;
      #pragma unroll
      for (int k = 0; k < 8; ++k) pk[k] = (bf16)(v1[k] * inv);
      *(bf16x8*)&lds[w][128 + ql * 8] = pk;
      #pragma unroll
      for (int k = 0; k < 8; ++k) pk[k] = (bf16)(v2[k] * inv);
      *(bf16x8*)&lds[w][256 + ql * 8] = pk;
    }
  } else {
    if (lane < 48) {
      bf16x8 z = {};
      *(bf16x8*)&lds[w][lane * 8] = z;
    }
  }

  __syncthreads();

  int tid = threadIdx.x;
  if (tid < 384) {
    int lc = tid >> 3, row = tid & 7;
    size_t unit = (size_t)(t0 >> 4) * 1024 + lc * 16 + (t0 & 15) + row;
    __builtin_nontemporal_store(*(const bf16x8*)&lds[row][lc * 8], (bf16x8*)Aq + unit);
  }
}

// ---------------- streaming MFMA GEMM (grid = (conv, tile); 2 row-blocks/wave, 3 waves/SIMD) --
struct GArgs {
  const bf16* Ap[5];
  const bf16* wf[5];
  const bf16* pf[5];
  bf16* out[5];
  const float* bias[5];
};

__global__ __launch_bounds__(256, 3) void gemm_kernel(GArgs ga, const float4* __restrict__ cntf,
                                                      const int* __restrict__ roleinfo)
{
  const int cv = blockIdx.x;           // conv varies fastest -> same A-tile L2-hot across convs
  const int tile = blockIdx.y;
  const bf16* __restrict__ Ap = ga.Ap[cv];
  const bf16* __restrict__ wf = ga.wf[cv];
  const bf16* __restrict__ pf = ga.pf[cv];
  bf16* __restrict__ out = ga.out[cv];
  const float* __restrict__ bias = ga.bias[cv];

  const int w = threadIdx.x >> 6, lane = threadIdx.x & 63;
  const int q = lane >> 4, l = lane & 15;
  const int rb0 = tile * 8 + w * 2;
  const int row0 = tile * 128;
  const int s1 = roleinfo[0], s2 = roleinfo[1];
  const int role = (row0 >= s2) ? 2 : (row0 >= s1) ? 1 : 0;
  const int laneoff = q * 128 + l;

  f32x4 acc[2][8];
  #pragma unroll
  for (int j = 0; j < 2; ++j)
    #pragma unroll
    for (int ct = 0; ct < 8; ++ct)
      #pragma unroll
      for (int k = 0; k < 4; ++k) acc[j][ct][k] = 0.f;

  const bf16x8* A0 = (const bf16x8*)Ap + (size_t)rb0 * 1024 + lane;
  const bf16x8* WF = (const bf16x8*)wf + laneoff;
  const bf16x8* PF = (const bf16x8*)pf + role * 2048 + laneoff;

  #pragma unroll 2
  for (int ks = 0; ks < 16; ++ks) {
    const bf16x8* bp = (ks < 12) ? (WF + ks * 512) : (PF + (ks - 12) * 512);
    bf16x8 a0 = A0[ks * 64];
    bf16x8 a1 = A0[1024 + ks * 64];
    #pragma unroll
    for (int ct = 0; ct < 8; ++ct) {
      bf16x8 b = bp[ct * 16];
      acc[0][ct] = __builtin_amdgcn_mfma_f32_16x16x32_bf16(a0, b, acc[0][ct], 0, 0, 0);
      acc[1][ct] = __builtin_amdgcn_mfma_f32_16x16x32_bf16(a1, b, acc[1][ct], 0, 0, 0);
    }
  }

  const bool hb = (bias != nullptr);
  #pragma unroll
  for (int j = 0; j < 2; ++j) {
    int rb = rb0 + j;
    float4 cfs[4];
    if (hb) {
      #pragma unroll
      for (int reg = 0; reg < 4; ++reg) cfs[reg] = cntf[rb * 16 + q * 4 + reg];
    }
    #pragma unroll
    for (int ct = 0; ct < 8; ++ct) {
      int col = ct * 16 + l;
      float b0 = 0, b1 = 0, b2 = 0;
      if (hb) { b0 = bias[col]; b1 = bias[128 + col]; b2 = bias[256 + col]; }
      #pragma unroll
      for (int reg = 0; reg < 4; ++reg) {
        int t = rb * 16 + q * 4 + reg;
        float v = acc[j][ct][reg];
        if (hb) v += cfs[reg].x * b0 + cfs[reg].y * b1 + cfs[reg].z * b2;
        out[(size_t)t * 128 + col] = (bf16)fmaxf(v, 0.f);
      }
    }
  }
}

// ---------------- combines (t-major; zbuf eliminated) ----------------
__global__ __launch_bounds__(256) void combine1_kernel(
    const bf16* __restrict__ o2, const bf16* __restrict__ o3,
    const float* __restrict__ h, const int* __restrict__ sposinv,
    u8* __restrict__ q8, bf16* __restrict__ Aq, int rows_pad)
{
  int g = blockIdx.x * 256 + threadIdx.x;
  if (g >= rows_pad * 16) return;
  int t = g >> 4, o = g & 15;
  int n = sposinv[t];
  if (n < 0) return;
  size_t tb = (size_t)t * 16 + o;
  bf16x8 a2 = ((const bf16x8*)o2)[tb];
  bf16x8 a3 = ((const bf16x8*)o3)[tb];
  size_t nb = (size_t)n * 16 + o;
  float4 h0 = ((const float4*)h)[nb * 2];
  float4 h1 = ((const float4*)h)[nb * 2 + 1];
  float hv[8] = {h0.x, h0.y, h0.z, h0.w, h1.x, h1.y, h1.z, h1.w};
  float qv[8];
  bf16x8 qb;
  #pragma unroll
  for (int j = 0; j < 8; ++j) {
    qv[j] = sigmoidf_((float)a2[j] + (float)a3[j]) * hv[j];
    qb[j] = (bf16)qv[j];
  }
  int lo = __builtin_amdgcn_cvt_pk_fp8_f32(qv[0], qv[1], 0, false);
  lo = __builtin_amdgcn_cvt_pk_fp8_f32(qv[2], qv[3], lo, true);
  int hi = __builtin_amdgcn_cvt_pk_fp8_f32(qv[4], qv[5], 0, false);
  hi = __builtin_amdgcn_cvt_pk_fp8_f32(qv[6], qv[7], hi, true);
  *(int2*)(q8 + (size_t)t * 128 + o * 8) = make_int2(lo, hi);
  size_t unit = (size_t)(t >> 4) * 1024 + (48 + o) * 16 + (t & 15);
  ((bf16x8*)Aq)[unit] = qb;
}

__global__ __launch_bounds__(256) void combine2_kernel(
    const bf16* __restrict__ o0, const bf16* __restrict__ o1,
    const bf16* __restrict__ o4, const bf16* __restrict__ o5,
    const float* __restrict__ h, const int* __restrict__ sposinv,
    float* __restrict__ out, int rows_pad)
{
  int g = blockIdx.x * 256 + threadIdx.x;
  if (g >= rows_pad * 16) return;
  int t = g >> 4, o = g & 15;
  int n = sposinv[t];
  if (n < 0) return;
  size_t tb = (size_t)t * 16 + o;
  bf16x8 a0 = ((const bf16x8*)o0)[tb];
  bf16x8 a1 = ((const bf16x8*)o1)[tb];
  bf16x8 a4 = ((const bf16x8*)o4)[tb];
  bf16x8 a5 = ((const bf16x8*)o5)[tb];
  size_t nb = (size_t)n * 16 + o;
  float4 h0 = ((const float4*)h)[nb * 2];
  float4 h1 = ((const float4*)h)[nb * 2 + 1];
  float hv[8] = {h0.x, h0.y, h0.z, h0.w, h1.x, h1.y, h1.z, h1.w};
  float ov[8];
  #pragma unroll
  for (int j = 0; j < 8; ++j) {
    float zv = sigmoidf_((float)a0[j] + (float)a1[j]);
    ov[j] = zv * hv[j] + (1.f - zv) * tanhf((float)a4[j] + (float)a5[j]);
  }
  ((float4*)out)[nb * 2]     = make_float4(ov[0], ov[1], ov[2], ov[3]);
  ((float4*)out)[nb * 2 + 1] = make_float4(ov[4], ov[5], ov[6], ov[7]);
}

// ---------------- host ----------------
extern "C" void kernel_launch(void* const* d_in, const int* in_sizes, int n_in,
                              void* d_out, int out_size, void* d_ws, size_t ws_size,
                              hipStream_t stream)
{
  (void)n_in; (void)out_size; (void)ws_size;
  const float* x    = (const float*)d_in[0];
  const float* h    = (const float*)d_in[1];
  const int*   ei   = (const int*)d_in[2];
  const int*   role = (const int*)d_in[3];
  const int N = in_sizes[0] / DH;
  const int E = in_sizes[2] / 2;
  const int Etot = E + N;
  const int rows_pad = ((N + 765) + 255) & ~255;
  const int gx = rows_pad / 128;
  const int n3 = N * 3;

  // bucket geometry: <=256 buckets of W=2^shiftB dst rows (N=50000 -> shiftB=8, W=256, NB=196)
  int shiftB = 8;
  while (((N - 1) >> shiftB) >= 256) ++shiftB;
  const int W = 1 << shiftB;
  const int NB = (N + W - 1) >> shiftB;

  // conv order: 0 xz, 1 hz, 2 xr, 3 hr, 4 xh, 5 hh
  static const int Wi[6]  = {4, 9, 13, 18, 22, 27};
  static const int Wgi[6] = {5, 10, 14, 19, 23, 28};
  static const int bgi[6] = {6, 11, 15, 20, 24, 29};
  static const int Si[6]  = {7, 12, 16, 21, 25, 30};

  char* p = (char*)d_ws;
  auto alloc = [&](size_t bytes) -> char* {
    char* r = p;
    p += (bytes + 255) & ~(size_t)255;
    return r;
  };

  bf16* Ax = (bf16*)alloc((size_t)rows_pad * 512 * 2);   // Aq aliases Ax
  bf16* Ah = (bf16*)alloc((size_t)rows_pad * 512 * 2);
  bf16* Aq = Ax;
  u8* xq8  = (u8*)alloc((size_t)rows_pad * 256);
  u8* q8   = (u8*)alloc((size_t)rows_pad * 128);
  bf16* outs[6];
  for (int c = 0; c < 6; ++c) outs[c] = (bf16*)alloc((size_t)rows_pad * 128 * 2);
  float4* cntf = (float4*)alloc((size_t)rows_pad * 16);
  bf16* Wf = (bf16*)alloc((size_t)6 * 49152 * 2);
  bf16* Pf = (bf16*)alloc((size_t)18 * 16384 * 2);
  int* off3  = (int*)alloc((size_t)(n3 + 1) * 4);
  int* ssrc  = (int*)alloc((size_t)Etot * 4);
  int2* recs = (int2*)alloc((size_t)Etot * 8);
  int* spos  = (int*)alloc((size_t)N * 4);
  int* sposinv = (int*)alloc((size_t)rows_pad * 4);
  int* rolecnt  = (int*)alloc(64);
  int* rolefill = (int*)alloc(64);
  int* roleinfo = (int*)alloc(64);
  int* bucketcnt  = (int*)alloc(257 * 4);
  int* bucketbase = (int*)alloc(258 * 4);
  int* bucketfill = (int*)alloc(257 * 4);

  hipMemsetAsync(rolecnt, 0, 16, stream);
  hipMemsetAsync(bucketcnt, 0, 257 * 4, stream);
  hipMemsetAsync(sposinv, 0xFF, (size_t)rows_pad * 4, stream);   // -1 = pad row

  int egrid4k = (Etot + 4095) / 4096;
  int ngrid = (N + 255) / 256;
  rolecnt_kernel<<<ngrid, 256, 0, stream>>>(role, rolecnt, N);
  roleinfo_kernel<<<1, 64, 0, stream>>>(rolecnt, rolefill, roleinfo);
  permscatter_kernel<<<ngrid, 256, 0, stream>>>(role, rolefill, spos, sposinv, N);
  coarsehist_kernel<<<egrid4k, 256, 0, stream>>>(ei, bucketcnt, E, N, shiftB);
  bucketscan_kernel<<<1, 256, 0, stream>>>(bucketcnt, bucketbase, bucketfill, NB);
  partition_kernel<<<egrid4k, 256, 0, stream>>>(ei, spos, roleinfo, bucketfill,
                                                recs, E, N, shiftB);
  binscatter_kernel<<<NB, 1024, 0, stream>>>(recs, bucketbase, off3, ssrc, W, N, NB);
  zeropad_kernel<<<384, 256, 0, stream>>>(roleinfo, Ax, Ah);

  prep_xh_kernel<<<(rows_pad * 32 + 255) / 256, 256, 0, stream>>>(x, h, sposinv, xq8, Ax, Ah, rows_pad);

  PrepW pw;
  for (int c = 0; c < 6; ++c) {
    pw.W[c] = (const float*)d_in[Wi[c]];
    pw.Wg[c] = (const float*)d_in[Wgi[c]];
    pw.bg[c] = (const float*)d_in[bgi[c]];
  }
  prep_wf_kernel<<<1152, 256, 0, stream>>>(pw, Wf);
  PrepP pp;
  for (int c = 0; c < 6; ++c) { pp.W[c] = (const float*)d_in[Wi[c]]; pp.S[c] = (const float*)d_in[Si[c]]; }
  prep_pf_kernel<<<2304, 128, 0, stream>>>(pp, Pf);

  gather_xh_kernel<<<rows_pad / 8, 512, 0, stream>>>(xq8, off3, ssrc, sposinv, Ax, Ah, cntf);

  // pass 1: one dispatch, cv 0..4 = {xz,xr,xh on Ax (bias)} + {hz,hr on Ah}; conv fastest
  GArgs g0;
  { int cvs[5] = {0, 2, 4, 1, 3};
    static const int bi2[5] = {8, 17, 26, -1, -1};
    const bf16* Apts[5] = {Ax, Ax, Ax, Ah, Ah};
    for (int k = 0; k < 5; ++k) {
      int c = cvs[k];
      g0.Ap[k] = Apts[k];
      g0.wf[k] = Wf + (size_t)c * 49152;
      g0.pf[k] = Pf + (size_t)c * 3 * 16384;
      g0.out[k] = outs[c];
      g0.bias[k] = (bi2[k] >= 0) ? (const float*)d_in[bi2[k]] : nullptr;
    } }
  gemm_kernel<<<dim3(5, gx), 256, 0, stream>>>(g0, cntf, roleinfo);

  combine1_kernel<<<(rows_pad * 16 + 255) / 256, 256, 0, stream>>>(outs[2], outs[3], h, sposinv,
                                                                   q8, Aq, rows_pad);

  gather_q_kernel<<<rows_pad / 8, 512, 0, stream>>>(q8, off3, ssrc, sposinv, Aq);

  // pass 2: conv hh(5) on Aq
  GArgs g2 = {};
  g2.Ap[0] = Aq;
  g2.wf[0] = Wf + (size_t)5 * 49152;
  g2.pf[0] = Pf + (size_t)5 * 3 * 16384;
  g2.out[0] = outs[5];
  g2.bias[0] = nullptr;
  gemm_kernel<<<dim3(1, gx), 256, 0, stream>>>(g2, cntf, roleinfo);

  combine2_kernel<<<(rows_pad * 16 + 255) / 256, 256, 0, stream>>>(outs[0], outs[1], outs[4], outs[5],
                                                                   h, sposinv, (float*)d_out, rows_pad);
}

// Round 13
// 598.736 us; speedup vs baseline: 1.9403x; 1.0048x over previous
//
#include <hip/hip_runtime.h>

// GraphGRU on MI355X — round 19.
//   Gather accumulators switched to packed f32x2 (v_pk_add_f32): cvt_pk_f32_fp8 already
//   yields f32x2, so accumulate is now 8 packed adds per 16-edge ACCUM (was 16 scalar) —
//   ~-25% gather VALU. Pure type change; loads/layout/shuffles/writes identical.
//   Discrimination experiment: gather_xh VALUBusy 42% -> ~33% and dur -8..-12 µs if
//   VALU-coupled; unchanged if at the ~2.3 TB/s memory ceiling (then model closed).
//   Everything else byte-identical to r18 (601.6 µs verified).

typedef __bf16 bf16;
typedef __bf16 bf16x8 __attribute__((ext_vector_type(8)));
typedef float  f32x4  __attribute__((ext_vector_type(4)));
typedef float  f32x2  __attribute__((ext_vector_type(2)));
typedef unsigned char u8;

#define DH 128

__device__ __forceinline__ float sigmoidf_(float x) { return 1.0f / (1.0f + expf(-x)); }

// ---------------- CSR build (bucket-local) ----------------
__global__ __launch_bounds__(256) void rolecnt_kernel(const int* __restrict__ role,
                                                      int* __restrict__ rolecnt, int N)
{
  int i = blockIdx.x * 256 + threadIdx.x;
  int lane = threadIdx.x & 63;
  int r = (i < N) ? role[i] : -1;
  #pragma unroll
  for (int rr = 0; rr < 3; ++rr) {
    unsigned long long mask = __ballot(r == rr);
    if (lane == 0 && mask) atomicAdd(&rolecnt[rr], __popcll(mask));
  }
}

__global__ void roleinfo_kernel(const int* __restrict__ rolecnt,
                                int* __restrict__ rolefill, int* __restrict__ roleinfo)
{
  if (threadIdx.x == 0) {
    int c0 = rolecnt[0], c1 = rolecnt[1], c2 = rolecnt[2];
    int s1 = (c0 + 255) & ~255;
    int s2 = s1 + ((c1 + 255) & ~255);
    int mp = s2 + ((c2 + 255) & ~255);
    rolefill[0] = 0; rolefill[1] = s1; rolefill[2] = s2;
    roleinfo[0] = s1; roleinfo[1] = s2;
    roleinfo[2] = c0;      roleinfo[3] = s1 - c0;
    roleinfo[4] = s1 + c1; roleinfo[5] = s2 - s1 - c1;
    roleinfo[6] = s2 + c2; roleinfo[7] = mp - s2 - c2;
  }
}

__global__ __launch_bounds__(256) void permscatter_kernel(const int* __restrict__ role, int* __restrict__ rolefill,
                                                          int* __restrict__ spos, int* __restrict__ sposinv, int N)
{
  int i = blockIdx.x * 256 + threadIdx.x;
  int lane = threadIdx.x & 63;
  int r = (i < N) ? role[i] : -1;
  #pragma unroll
  for (int rr = 0; rr < 3; ++rr) {
    unsigned long long mask = __ballot(r == rr);
    if (!mask) continue;
    int base = 0;
    if (lane == 0) base = atomicAdd(&rolefill[rr], __popcll(mask));
    base = __shfl(base, 0);
    if (r == rr) {
      int rank = (int)__popcll(mask & ((1ull << lane) - 1ull));
      int pos = base + rank;
      spos[i] = pos;
      sposinv[pos] = i;
    }
  }
}

// coarse per-bucket edge counts (bucket = dst >> shiftB, <=256 buckets)
__global__ __launch_bounds__(256) void coarsehist_kernel(const int* __restrict__ ei,
                                                         int* __restrict__ bucketcnt,
                                                         int E, int N, int shiftB)
{
  __shared__ int lc[256];
  lc[threadIdx.x] = 0;
  __syncthreads();
  const int base = blockIdx.x * 4096;
  #pragma unroll
  for (int k = 0; k < 16; ++k) {
    int i = base + k * 256 + threadIdx.x;
    if (i < E + N) {
      int dst = (i < E) ? ei[E + i] : i - E;
      atomicAdd(&lc[dst >> shiftB], 1);
    }
  }
  __syncthreads();
  int c = lc[threadIdx.x];
  if (c > 0) atomicAdd(&bucketcnt[threadIdx.x], c);
}

// single-block scan of bucket counts -> bucketbase (excl, +total at [NB]) and bucketfill
__global__ __launch_bounds__(256) void bucketscan_kernel(const int* __restrict__ bucketcnt,
                                                         int* __restrict__ bucketbase,
                                                         int* __restrict__ bucketfill, int NB)
{
  __shared__ int lh[256];
  int tid = threadIdx.x;
  lh[tid] = (tid < NB) ? bucketcnt[tid] : 0;
  __syncthreads();
  for (int d = 1; d < 256; d <<= 1) {
    int v = (tid >= d) ? lh[tid - d] : 0;
    __syncthreads();
    lh[tid] += v;
    __syncthreads();
  }
  int excl = (tid > 0) ? lh[tid - 1] : 0;
  if (tid < NB) { bucketbase[tid] = excl; bucketfill[tid] = excl; }
  if (tid == 0) bucketbase[NB] = lh[255];
}

// stage 1: partition edges into dst-range buckets; records = (bin, t)
__global__ __launch_bounds__(256) void partition_kernel(
    const int* __restrict__ ei, const int* __restrict__ spos,
    const int* __restrict__ roleinfo, int* __restrict__ bucketfill,
    int2* __restrict__ recs, int E, int N, int shiftB)
{
  __shared__ int lcnt[256], lbase[256];
  const int base = blockIdx.x * 4096;
  const int s1 = roleinfo[0], s2 = roleinfo[1];
  lcnt[threadIdx.x] = 0;
  __syncthreads();
  int myb[16], mybin[16], myt[16];
  #pragma unroll
  for (int k = 0; k < 16; ++k) {
    int i = base + k * 256 + threadIdx.x;
    myb[k] = -1;
    if (i < E + N) {
      int src, dst;
      if (i < E) { src = ei[i]; dst = ei[E + i]; } else { src = i - E; dst = i - E; }
      int t = spos[src];
      int r = (t >= s2) ? 2 : (t >= s1) ? 1 : 0;
      myb[k] = dst >> shiftB;
      mybin[k] = dst * 3 + r;
      myt[k] = t;
      atomicAdd(&lcnt[myb[k]], 1);
    }
  }
  __syncthreads();
  int c = lcnt[threadIdx.x];
  lbase[threadIdx.x] = (c > 0) ? atomicAdd(&bucketfill[threadIdx.x], c) : 0;
  __syncthreads();
  lcnt[threadIdx.x] = 0;          // reuse as per-bucket cursor
  __syncthreads();
  #pragma unroll
  for (int k = 0; k < 16; ++k) {
    if (myb[k] >= 0) {
      int slot = atomicAdd(&lcnt[myb[k]], 1);
      recs[lbase[myb[k]] + slot] = make_int2(mybin[k], myt[k]);
    }
  }
}

// stage 2 (v2): per bucket, LDS histogram over local bins (<=768), LDS scan,
// write the bucket's off3 slice, then scatter ssrc via LDS cursors.
__global__ __launch_bounds__(1024) void binscatter_kernel(
    const int2* __restrict__ recs, const int* __restrict__ bucketbase,
    int* __restrict__ off3, int* __restrict__ ssrc, int W, int N, int NB)
{
  __shared__ int lh[1024];
  int b = blockIdx.x;
  int tid = threadIdx.x;
  int d0 = min(b * W, N), d1 = min((b + 1) * W, N);
  int nloc = (d1 - d0) * 3;                 // <= 768
  int s = bucketbase[b], e = bucketbase[b + 1];
  int lb0 = d0 * 3;

  lh[tid] = 0;
  __syncthreads();
  for (int i = s + tid; i < e; i += 1024)
    atomicAdd(&lh[recs[i].x - lb0], 1);
  __syncthreads();
  // inclusive scan over 1024 (bins >= nloc are zero)
  for (int d = 1; d < 1024; d <<= 1) {
    int v = (tid >= d) ? lh[tid - d] : 0;
    __syncthreads();
    lh[tid] += v;
    __syncthreads();
  }
  // write off3 slice: off3[lb0 + j] = s + excl(j)
  if (tid < nloc) off3[lb0 + tid] = s + ((tid > 0) ? lh[tid - 1] : 0);
  if (b == NB - 1 && tid == 0) off3[N * 3] = e;
  // convert to exclusive cursors
  int excl = (tid > 0) ? lh[tid - 1] : 0;
  __syncthreads();
  lh[tid] = excl;
  __syncthreads();
  for (int i = s + tid; i < e; i += 1024) {
    int2 rec = recs[i];
    int slot = atomicAdd(&lh[rec.x - lb0], 1);
    ssrc[s + slot] = rec.y;
  }
}

__global__ __launch_bounds__(256) void zeropad_kernel(const int* __restrict__ roleinfo,
                                                      bf16* __restrict__ Ax, bf16* __restrict__ Ah)
{
  int id = blockIdx.x * 256 + threadIdx.x;   // 98304
  int a = id / 49152, rem = id % 49152;
  int gp = rem / 16384, r2 = rem % 16384;
  int rr = r2 >> 6, c = r2 & 63;
  int gs = roleinfo[2 + gp * 2], gl = roleinfo[3 + gp * 2];
  if (rr < gl) {
    int row = gs + rr;
    size_t unit = (size_t)(row >> 4) * 1024 + c * 16 + (row & 15);
    bf16x8 z = {};
    ((bf16x8*)(a == 0 ? Ax : Ah))[unit] = z;
  }
}

// ---------------- prep (t-major: contiguous writes, full-line random reads) ----------------
__global__ __launch_bounds__(256) void prep_xh_kernel(const float* __restrict__ x, const float* __restrict__ h,
                                                      const int* __restrict__ sposinv, u8* __restrict__ xq8,
                                                      bf16* __restrict__ Ax, bf16* __restrict__ Ah, int rows_pad)
{
  int g = blockIdx.x * 256 + threadIdx.x;
  if (g >= rows_pad * 32) return;
  int t = g >> 5, j = g & 31;
  int n = sposinv[t];
  if (n < 0) return;                       // pad rows: A filled by zeropad; xq8 never read
  const float* src = (j < 16) ? (x + (size_t)n * 128 + (j << 3))
                              : (h + (size_t)n * 128 + ((j - 16) << 3));
  float4 v0 = ((const float4*)src)[0];
  float4 v1 = ((const float4*)src)[1];
  int lo = __builtin_amdgcn_cvt_pk_fp8_f32(v0.x, v0.y, 0, false);
  lo = __builtin_amdgcn_cvt_pk_fp8_f32(v0.z, v0.w, lo, true);
  int hi = __builtin_amdgcn_cvt_pk_fp8_f32(v1.x, v1.y, 0, false);
  hi = __builtin_amdgcn_cvt_pk_fp8_f32(v1.z, v1.w, hi, true);
  *(int2*)(xq8 + (size_t)t * 256 + j * 8) = make_int2(lo, hi);
  bf16x8 o;
  o[0] = (bf16)v0.x; o[1] = (bf16)v0.y; o[2] = (bf16)v0.z; o[3] = (bf16)v0.w;
  o[4] = (bf16)v1.x; o[5] = (bf16)v1.y; o[6] = (bf16)v1.z; o[7] = (bf16)v1.w;
  size_t unit = (size_t)(t >> 4) * 1024 + (48 + (j & 15)) * 16 + (t & 15);
  ((bf16x8*)(j < 16 ? Ax : Ah))[unit] = o;
}

struct PrepW { const float* W[6]; const float* Wg[6]; const float* bg[6]; };
__global__ __launch_bounds__(256) void prep_wf_kernel(PrepW pw, bf16* __restrict__ Wf)
{
  int idx = blockIdx.x * 256 + threadIdx.x;
  if (idx >= 294912) return;
  int cv = idx / 49152, pos = idx % 49152;
  int ks4q = pos >> 10;
  int col = (pos >> 3) & 127, j = pos & 7;
  int k = (ks4q >> 2) * 32 + (ks4q & 3) * 8 + j;
  int r = k >> 7, kk = k & 127;
  float g = sigmoidf_(pw.Wg[cv][r * 128 + col] + pw.bg[cv][r * 128 + col]);
  Wf[idx] = (bf16)(pw.W[cv][kk * 128 + col] * g);
}

struct PrepP { const float* W[6]; const float* S[6]; };
__global__ __launch_bounds__(128) void prep_pf_kernel(PrepP pp, bf16* __restrict__ Pf)
{
  int b = blockIdx.x;                          // 6*3*128
  int cv = b / 384, rem = b % 384;
  int r = rem >> 7, kp = rem & 127;
  int col = threadIdx.x;
  const float* W = pp.W[cv] + (size_t)kp * 128;
  const float* S = pp.S[cv] + (size_t)r * 16384;
  float sum = 0.f;
  #pragma unroll 4
  for (int j2 = 0; j2 < 128; ++j2) sum += W[j2] * S[j2 * 128 + col];
  size_t o = (size_t)(cv * 3 + r) * 16384 + ((size_t)(kp >> 3) * 128 + col) * 8 + (kp & 7);
  Pf[o] = (bf16)sum;
}

// ---------------- gathers (t-ordered 8-node blocks, packed-f32 accumulators) ----------------
#define ACCUM16(U, d) do { f32x2 f_;                               \
  f_ = __builtin_amdgcn_cvt_pk_f32_fp8((d).x, false); U[0] += f_;  \
  f_ = __builtin_amdgcn_cvt_pk_f32_fp8((d).x, true);  U[1] += f_;  \
  f_ = __builtin_amdgcn_cvt_pk_f32_fp8((d).y, false); U[2] += f_;  \
  f_ = __builtin_amdgcn_cvt_pk_f32_fp8((d).y, true);  U[3] += f_;  \
  f_ = __builtin_amdgcn_cvt_pk_f32_fp8((d).z, false); U[4] += f_;  \
  f_ = __builtin_amdgcn_cvt_pk_f32_fp8((d).z, true);  U[5] += f_;  \
  f_ = __builtin_amdgcn_cvt_pk_f32_fp8((d).w, false); U[6] += f_;  \
  f_ = __builtin_amdgcn_cvt_pk_f32_fp8((d).w, true);  U[7] += f_;  \
} while (0)

#define ACCSEL16(d, p) do {                      \
  if ((p) < o1)      { ACCUM16(u0, d); }         \
  else if ((p) < o2) { ACCUM16(u1, d); }         \
  else               { ACCUM16(u2, d); }         \
} while (0)

__global__ __launch_bounds__(512) void gather_xh_kernel(
    const u8* __restrict__ xq8, const int* __restrict__ off3, const int* __restrict__ ssrc,
    const int* __restrict__ sposinv, bf16* __restrict__ Ax, bf16* __restrict__ Ah,
    float4* __restrict__ cntf)
{
  __shared__ alignas(16) bf16 lds[8][768];
  int w = threadIdx.x >> 6, lane = threadIdx.x & 63;
  int t0 = blockIdx.x * 8;
  int t = t0 + w;
  int node = sposinv[t];                 // -1 for pad rows
  int qt = lane >> 4, ql = lane & 15;

  if (node >= 0) {
    int o0 = __builtin_amdgcn_readfirstlane(off3[node * 3]);
    int o1 = __builtin_amdgcn_readfirstlane(off3[node * 3 + 1]);
    int o2 = __builtin_amdgcn_readfirstlane(off3[node * 3 + 2]);
    int o3 = __builtin_amdgcn_readfirstlane(off3[node * 3 + 3]);
    float inv = 1.0f / (float)(o3 - o0);
    const u8* base = xq8 + ql * 16;

    f32x2 u0[8], u1[8], u2[8];
    #pragma unroll
    for (int k = 0; k < 8; ++k) {
      u0[k][0] = 0.f; u0[k][1] = 0.f;
      u1[k][0] = 0.f; u1[k][1] = 0.f;
      u2[k][0] = 0.f; u2[k][1] = 0.f;
    }

    const int e = o3, emax = o3 - 1;
    for (int i = o0; i < e; i += 16) {
      int p0 = i + qt, p1 = p0 + 4, p2 = p0 + 8, p3 = p0 + 12;
      int t0i = ssrc[min(p0, emax)];
      int t1i = ssrc[min(p1, emax)];
      int t2i = ssrc[min(p2, emax)];
      int t3i = ssrc[min(p3, emax)];
      int4 d0 = make_int4(0, 0, 0, 0), d1 = d0, d2 = d0, d3 = d0;
      if (p0 < e) d0 = *(const int4*)(base + (size_t)t0i * 256);
      if (p1 < e) d1 = *(const int4*)(base + (size_t)t1i * 256);
      if (p2 < e) d2 = *(const int4*)(base + (size_t)t2i * 256);
      if (p3 < e) d3 = *(const int4*)(base + (size_t)t3i * 256);
      ACCSEL16(d0, p0);
      ACCSEL16(d1, p1);
      ACCSEL16(d2, p2);
      ACCSEL16(d3, p3);
    }

    #pragma unroll
    for (int k = 0; k < 8; ++k) {
      u0[k][0] += __shfl_xor(u0[k][0], 16); u0[k][0] += __shfl_xor(u0[k][0], 32);
      u0[k][1] += __shfl_xor(u0[k][1], 16); u0[k][1] += __shfl_xor(u0[k][1], 32);
      u1[k][0] += __shfl_xor(u1[k][0], 16); u1[k][0] += __shfl_xor(u1[k][0], 32);
      u1[k][1] += __shfl_xor(u1[k][1], 16); u1[k][1] += __shfl_xor(u1[k][1], 32);
      u2[k][0] += __shfl_xor(u2[k][0], 16); u2[k][0] += __shfl_xor(u2[k][0], 32);
      u2[k][1] += __shfl_xor(u2[k][1], 16); u2[k][1] += __shfl_xor(u2[k][1], 32);
    }
    if (qt == 0) {
      bf16x8 p0v, p1v;
      int sb0 = (ql < 8) ? (ql * 16) : (384 + (ql - 8) * 16);
      #pragma unroll
      for (int k = 0; k < 8; ++k) {
        p0v[k] = (bf16)(u0[k >> 1][k & 1] * inv);
        p1v[k] = (bf16)(u0[4 + (k >> 1)][k & 1] * inv);
      }
      *(bf16x8*)&lds[w][sb0] = p0v;
      *(bf16x8*)&lds[w][sb0 + 8] = p1v;
      #pragma unroll
      for (int k = 0; k < 8; ++k) {
        p0v[k] = (bf16)(u1[k >> 1][k & 1] * inv);
        p1v[k] = (bf16)(u1[4 + (k >> 1)][k & 1] * inv);
      }
      *(bf16x8*)&lds[w][sb0 + 128] = p0v;
      *(bf16x8*)&lds[w][sb0 + 136] = p1v;
      #pragma unroll
      for (int k = 0; k < 8; ++k) {
        p0v[k] = (bf16)(u2[k >> 1][k & 1] * inv);
        p1v[k] = (bf16)(u2[4 + (k >> 1)][k & 1] * inv);
      }
      *(bf16x8*)&lds[w][sb0 + 256] = p0v;
      *(bf16x8*)&lds[w][sb0 + 264] = p1v;
    }
    if (lane == 0)
      cntf[t] = make_float4((o1 - o0) * inv, (o2 - o1) * inv, (o3 - o2) * inv, (float)(o3 - o0));
  } else {
    // pad row: zero-fill this wave's LDS section so the cooperative write stores zeros
    if (lane < 48) {
      bf16x8 z = {};
      *(bf16x8*)&lds[w][lane * 16] = z;
      *(bf16x8*)&lds[w][lane * 16 + 8] = z;
    }
    if (lane == 0) cntf[t] = make_float4(0.f, 0.f, 0.f, 0.f);
  }

  __syncthreads();

  // cooperative write: 8 consecutive rows (t0..t0+7, same 16-group) -> full 128-B lines
  int tid = threadIdx.x;
  if (tid < 384) {
    int lc = tid >> 3, row = tid & 7;
    size_t unit = (size_t)(t0 >> 4) * 1024 + lc * 16 + (t0 & 15) + row;
    __builtin_nontemporal_store(*(const bf16x8*)&lds[row][lc * 8], (bf16x8*)Ax + unit);
    __builtin_nontemporal_store(*(const bf16x8*)&lds[row][384 + lc * 8], (bf16x8*)Ah + unit);
  }
}

#define ACCUM8(U, d) do { f32x2 f_;                                \
  f_ = __builtin_amdgcn_cvt_pk_f32_fp8((d).x, false); U[0] += f_;  \
  f_ = __builtin_amdgcn_cvt_pk_f32_fp8((d).x, true);  U[1] += f_;  \
  f_ = __builtin_amdgcn_cvt_pk_f32_fp8((d).y, false); U[2] += f_;  \
  f_ = __builtin_amdgcn_cvt_pk_f32_fp8((d).y, true);  U[3] += f_;  \
} while (0)

#define ACCSEL8(d, p) do {                      \
  if ((p) < o1)      { ACCUM8(v0, d); }         \
  else if ((p) < o2) { ACCUM8(v1, d); }         \
  else               { ACCUM8(v2, d); }         \
} while (0)

__global__ __launch_bounds__(512) void gather_q_kernel(
    const u8* __restrict__ q8, const int* __restrict__ off3, const int* __restrict__ ssrc,
    const int* __restrict__ sposinv, bf16* __restrict__ Aq)
{
  __shared__ alignas(16) bf16 lds[8][384];
  int w = threadIdx.x >> 6, lane = threadIdx.x & 63;
  int t0 = blockIdx.x * 8;
  int t = t0 + w;
  int node = sposinv[t];
  int qt = lane >> 4, ql = lane & 15;

  if (node >= 0) {
    int o0 = __builtin_amdgcn_readfirstlane(off3[node * 3]);
    int o1 = __builtin_amdgcn_readfirstlane(off3[node * 3 + 1]);
    int o2 = __builtin_amdgcn_readfirstlane(off3[node * 3 + 2]);
    int o3 = __builtin_amdgcn_readfirstlane(off3[node * 3 + 3]);
    float inv = 1.0f / (float)(o3 - o0);
    const u8* base = q8 + ql * 8;

    f32x2 v0[4], v1[4], v2[4];
    #pragma unroll
    for (int k = 0; k < 4; ++k) {
      v0[k][0] = 0.f; v0[k][1] = 0.f;
      v1[k][0] = 0.f; v1[k][1] = 0.f;
      v2[k][0] = 0.f; v2[k][1] = 0.f;
    }

    const int e = o3, emax = o3 - 1;
    for (int i = o0; i < e; i += 16) {
      int p0 = i + qt, p1 = p0 + 4, p2 = p0 + 8, p3 = p0 + 12;
      int t0i = ssrc[min(p0, emax)];
      int t1i = ssrc[min(p1, emax)];
      int t2i = ssrc[min(p2, emax)];
      int t3i = ssrc[min(p3, emax)];
      int2 d0 = make_int2(0, 0), d1 = d0, d2 = d0, d3 = d0;
      if (p0 < e) d0 = *(const int2*)(base + (size_t)t0i * 128);
      if (p1 < e) d1 = *(const int2*)(base + (size_t)t1i * 128);
      if (p2 < e) d2 = *(const int2*)(base + (size_t)t2i * 128);
      if (p3 < e) d3 = *(const int2*)(base + (size_t)t3i * 128);
      ACCSEL8(d0, p0);
      ACCSEL8(d1, p1);
      ACCSEL8(d2, p2);
      ACCSEL8(d3, p3);
    }

    #pragma unroll
    for (int k = 0; k < 4; ++k) {
      v0[k][0] += __shfl_xor(v0[k][0], 16); v0[k][0] += __shfl_xor(v0[k][0], 32);
      v0[k][1] += __shfl_xor(v0[k][1], 16); v0[k][1] += __shfl_xor(v0[k][1], 32);
      v1[k][0] += __shfl_xor(v1[k][0], 16); v1[k][0] += __shfl_xor(v1[k][0], 32);
      v1[k][1] += __shfl_xor(v1[k][1], 16); v1[k][1] += __shfl_xor(v1[k][1], 32);
      v2[k][0] += __shfl_xor(v2[k][0], 16); v2[k][0] += __shfl_xor(v2[k][0], 32);
      v2[k][1] += __shfl_xor(v2[k][1], 16); v2[k][1] += __shfl_xor(v2[k][1], 32);
    }
    if (qt == 0) {
      bf16x8 pk;
      #pragma unroll
      for (int k = 0; k < 8; ++k) pk[k] = (bf16)(v0[k >> 1][k & 1] * inv);
      *(bf16x8*)&lds[w][ql * 8] = pk;
      #pragma unroll
      for (int k = 0; k < 8; ++k) pk[k] = (bf16)(v1[k >> 1][k & 1] * inv);
      *(bf16x8*)&lds[w][128 + ql * 8] = pk;
      #pragma unroll
      for (int k = 0; k < 8; ++k) pk[k] = (bf16)(v2[k >> 1][k & 1] * inv);
      *(bf16x8*)&lds[w][256 + ql * 8] = pk;
    }
  } else {
    if (lane < 48) {
      bf16x8 z = {};
      *(bf16x8*)&lds[w][lane * 8] = z;
    }
  }

  __syncthreads();

  int tid = threadIdx.x;
  if (tid < 384) {
    int lc = tid >> 3, row = tid & 7;
    size_t unit = (size_t)(t0 >> 4) * 1024 + lc * 16 + (t0 & 15) + row;
    __builtin_nontemporal_store(*(const bf16x8*)&lds[row][lc * 8], (bf16x8*)Aq + unit);
  }
}

// ---------------- streaming MFMA GEMM (grid = (conv, tile); 2 row-blocks/wave, 3 waves/SIMD) --
struct GArgs {
  const bf16* Ap[5];
  const bf16* wf[5];
  const bf16* pf[5];
  bf16* out[5];
  const float* bias[5];
};

__global__ __launch_bounds__(256, 3) void gemm_kernel(GArgs ga, const float4* __restrict__ cntf,
                                                      const int* __restrict__ roleinfo)
{
  const int cv = blockIdx.x;           // conv varies fastest -> same A-tile L2-hot across convs
  const int tile = blockIdx.y;
  const bf16* __restrict__ Ap = ga.Ap[cv];
  const bf16* __restrict__ wf = ga.wf[cv];
  const bf16* __restrict__ pf = ga.pf[cv];
  bf16* __restrict__ out = ga.out[cv];
  const float* __restrict__ bias = ga.bias[cv];

  const int w = threadIdx.x >> 6, lane = threadIdx.x & 63;
  const int q = lane >> 4, l = lane & 15;
  const int rb0 = tile * 8 + w * 2;
  const int row0 = tile * 128;
  const int s1 = roleinfo[0], s2 = roleinfo[1];
  const int role = (row0 >= s2) ? 2 : (row0 >= s1) ? 1 : 0;
  const int laneoff = q * 128 + l;

  f32x4 acc[2][8];
  #pragma unroll
  for (int j = 0; j < 2; ++j)
    #pragma unroll
    for (int ct = 0; ct < 8; ++ct)
      #pragma unroll
      for (int k = 0; k < 4; ++k) acc[j][ct][k] = 0.f;

  const bf16x8* A0 = (const bf16x8*)Ap + (size_t)rb0 * 1024 + lane;
  const bf16x8* WF = (const bf16x8*)wf + laneoff;
  const bf16x8* PF = (const bf16x8*)pf + role * 2048 + laneoff;

  #pragma unroll 2
  for (int ks = 0; ks < 16; ++ks) {
    const bf16x8* bp = (ks < 12) ? (WF + ks * 512) : (PF + (ks - 12) * 512);
    bf16x8 a0 = A0[ks * 64];
    bf16x8 a1 = A0[1024 + ks * 64];
    #pragma unroll
    for (int ct = 0; ct < 8; ++ct) {
      bf16x8 b = bp[ct * 16];
      acc[0][ct] = __builtin_amdgcn_mfma_f32_16x16x32_bf16(a0, b, acc[0][ct], 0, 0, 0);
      acc[1][ct] = __builtin_amdgcn_mfma_f32_16x16x32_bf16(a1, b, acc[1][ct], 0, 0, 0);
    }
  }

  const bool hb = (bias != nullptr);
  #pragma unroll
  for (int j = 0; j < 2; ++j) {
    int rb = rb0 + j;
    float4 cfs[4];
    if (hb) {
      #pragma unroll
      for (int reg = 0; reg < 4; ++reg) cfs[reg] = cntf[rb * 16 + q * 4 + reg];
    }
    #pragma unroll
    for (int ct = 0; ct < 8; ++ct) {
      int col = ct * 16 + l;
      float b0 = 0, b1 = 0, b2 = 0;
      if (hb) { b0 = bias[col]; b1 = bias[128 + col]; b2 = bias[256 + col]; }
      #pragma unroll
      for (int reg = 0; reg < 4; ++reg) {
        int t = rb * 16 + q * 4 + reg;
        float v = acc[j][ct][reg];
        if (hb) v += cfs[reg].x * b0 + cfs[reg].y * b1 + cfs[reg].z * b2;
        out[(size_t)t * 128 + col] = (bf16)fmaxf(v, 0.f);
      }
    }
  }
}

// ---------------- combines (t-major; zbuf eliminated) ----------------
__global__ __launch_bounds__(256) void combine1_kernel(
    const bf16* __restrict__ o2, const bf16* __restrict__ o3,
    const float* __restrict__ h, const int* __restrict__ sposinv,
    u8* __restrict__ q8, bf16* __restrict__ Aq, int rows_pad)
{
  int g = blockIdx.x * 256 + threadIdx.x;
  if (g >= rows_pad * 16) return;
  int t = g >> 4, o = g & 15;
  int n = sposinv[t];
  if (n < 0) return;
  size_t tb = (size_t)t * 16 + o;
  bf16x8 a2 = ((const bf16x8*)o2)[tb];
  bf16x8 a3 = ((const bf16x8*)o3)[tb];
  size_t nb = (size_t)n * 16 + o;
  float4 h0 = ((const float4*)h)[nb * 2];
  float4 h1 = ((const float4*)h)[nb * 2 + 1];
  float hv[8] = {h0.x, h0.y, h0.z, h0.w, h1.x, h1.y, h1.z, h1.w};
  float qv[8];
  bf16x8 qb;
  #pragma unroll
  for (int j = 0; j < 8; ++j) {
    qv[j] = sigmoidf_((float)a2[j] + (float)a3[j]) * hv[j];
    qb[j] = (bf16)qv[j];
  }
  int lo = __builtin_amdgcn_cvt_pk_fp8_f32(qv[0], qv[1], 0, false);
  lo = __builtin_amdgcn_cvt_pk_fp8_f32(qv[2], qv[3], lo, true);
  int hi = __builtin_amdgcn_cvt_pk_fp8_f32(qv[4], qv[5], 0, false);
  hi = __builtin_amdgcn_cvt_pk_fp8_f32(qv[6], qv[7], hi, true);
  *(int2*)(q8 + (size_t)t * 128 + o * 8) = make_int2(lo, hi);
  size_t unit = (size_t)(t >> 4) * 1024 + (48 + o) * 16 + (t & 15);
  ((bf16x8*)Aq)[unit] = qb;
}

__global__ __launch_bounds__(256) void combine2_kernel(
    const bf16* __restrict__ o0, const bf16* __restrict__ o1,
    const bf16* __restrict__ o4, const bf16* __restrict__ o5,
    const float* __restrict__ h, const int* __restrict__ sposinv,
    float* __restrict__ out, int rows_pad)
{
  int g = blockIdx.x * 256 + threadIdx.x;
  if (g >= rows_pad * 16) return;
  int t = g >> 4, o = g & 15;
  int n = sposinv[t];
  if (n < 0) return;
  size_t tb = (size_t)t * 16 + o;
  bf16x8 a0 = ((const bf16x8*)o0)[tb];
  bf16x8 a1 = ((const bf16x8*)o1)[tb];
  bf16x8 a4 = ((const bf16x8*)o4)[tb];
  bf16x8 a5 = ((const bf16x8*)o5)[tb];
  size_t nb = (size_t)n * 16 + o;
  float4 h0 = ((const float4*)h)[nb * 2];
  float4 h1 = ((const float4*)h)[nb * 2 + 1];
  float hv[8] = {h0.x, h0.y, h0.z, h0.w, h1.x, h1.y, h1.z, h1.w};
  float ov[8];
  #pragma unroll
  for (int j = 0; j < 8; ++j) {
    float zv = sigmoidf_((float)a0[j] + (float)a1[j]);
    ov[j] = zv * hv[j] + (1.f - zv) * tanhf((float)a4[j] + (float)a5[j]);
  }
  ((float4*)out)[nb * 2]     = make_float4(ov[0], ov[1], ov[2], ov[3]);
  ((float4*)out)[nb * 2 + 1] = make_float4(ov[4], ov[5], ov[6], ov[7]);
}

// ---------------- host ----------------
extern "C" void kernel_launch(void* const* d_in, const int* in_sizes, int n_in,
                              void* d_out, int out_size, void* d_ws, size_t ws_size,
                              hipStream_t stream)
{
  (void)n_in; (void)out_size; (void)ws_size;
  const float* x    = (const float*)d_in[0];
  const float* h    = (const float*)d_in[1];
  const int*   ei   = (const int*)d_in[2];
  const int*   role = (const int*)d_in[3];
  const int N = in_sizes[0] / DH;
  const int E = in_sizes[2] / 2;
  const int Etot = E + N;
  const int rows_pad = ((N + 765) + 255) & ~255;
  const int gx = rows_pad / 128;
  const int n3 = N * 3;

  // bucket geometry: <=256 buckets of W=2^shiftB dst rows (N=50000 -> shiftB=8, W=256, NB=196)
  int shiftB = 8;
  while (((N - 1) >> shiftB) >= 256) ++shiftB;
  const int W = 1 << shiftB;
  const int NB = (N + W - 1) >> shiftB;

  // conv order: 0 xz, 1 hz, 2 xr, 3 hr, 4 xh, 5 hh
  static const int Wi[6]  = {4, 9, 13, 18, 22, 27};
  static const int Wgi[6] = {5, 10, 14, 19, 23, 28};
  static const int bgi[6] = {6, 11, 15, 20, 24, 29};
  static const int Si[6]  = {7, 12, 16, 21, 25, 30};

  char* p = (char*)d_ws;
  auto alloc = [&](size_t bytes) -> char* {
    char* r = p;
    p += (bytes + 255) & ~(size_t)255;
    return r;
  };

  bf16* Ax = (bf16*)alloc((size_t)rows_pad * 512 * 2);   // Aq aliases Ax
  bf16* Ah = (bf16*)alloc((size_t)rows_pad * 512 * 2);
  bf16* Aq = Ax;
  u8* xq8  = (u8*)alloc((size_t)rows_pad * 256);
  u8* q8   = (u8*)alloc((size_t)rows_pad * 128);
  bf16* outs[6];
  for (int c = 0; c < 6; ++c) outs[c] = (bf16*)alloc((size_t)rows_pad * 128 * 2);
  float4* cntf = (float4*)alloc((size_t)rows_pad * 16);
  bf16* Wf = (bf16*)alloc((size_t)6 * 49152 * 2);
  bf16* Pf = (bf16*)alloc((size_t)18 * 16384 * 2);
  int* off3  = (int*)alloc((size_t)(n3 + 1) * 4);
  int* ssrc  = (int*)alloc((size_t)Etot * 4);
  int2* recs = (int2*)alloc((size_t)Etot * 8);
  int* spos  = (int*)alloc((size_t)N * 4);
  int* sposinv = (int*)alloc((size_t)rows_pad * 4);
  int* rolecnt  = (int*)alloc(64);
  int* rolefill = (int*)alloc(64);
  int* roleinfo = (int*)alloc(64);
  int* bucketcnt  = (int*)alloc(257 * 4);
  int* bucketbase = (int*)alloc(258 * 4);
  int* bucketfill = (int*)alloc(257 * 4);

  hipMemsetAsync(rolecnt, 0, 16, stream);
  hipMemsetAsync(bucketcnt, 0, 257 * 4, stream);
  hipMemsetAsync(sposinv, 0xFF, (size_t)rows_pad * 4, stream);   // -1 = pad row

  int egrid4k = (Etot + 4095) / 4096;
  int ngrid = (N + 255) / 256;
  rolecnt_kernel<<<ngrid, 256, 0, stream>>>(role, rolecnt, N);
  roleinfo_kernel<<<1, 64, 0, stream>>>(rolecnt, rolefill, roleinfo);
  permscatter_kernel<<<ngrid, 256, 0, stream>>>(role, rolefill, spos, sposinv, N);
  coarsehist_kernel<<<egrid4k, 256, 0, stream>>>(ei, bucketcnt, E, N, shiftB);
  bucketscan_kernel<<<1, 256, 0, stream>>>(bucketcnt, bucketbase, bucketfill, NB);
  partition_kernel<<<egrid4k, 256, 0, stream>>>(ei, spos, roleinfo, bucketfill,
                                                recs, E, N, shiftB);
  binscatter_kernel<<<NB, 1024, 0, stream>>>(recs, bucketbase, off3, ssrc, W, N, NB);
  zeropad_kernel<<<384, 256, 0, stream>>>(roleinfo, Ax, Ah);

  prep_xh_kernel<<<(rows_pad * 32 + 255) / 256, 256, 0, stream>>>(x, h, sposinv, xq8, Ax, Ah, rows_pad);

  PrepW pw;
  for (int c = 0; c < 6; ++c) {
    pw.W[c] = (const float*)d_in[Wi[c]];
    pw.Wg[c] = (const float*)d_in[Wgi[c]];
    pw.bg[c] = (const float*)d_in[bgi[c]];
  }
  prep_wf_kernel<<<1152, 256, 0, stream>>>(pw, Wf);
  PrepP pp;
  for (int c = 0; c < 6; ++c) { pp.W[c] = (const float*)d_in[Wi[c]]; pp.S[c] = (const float*)d_in[Si[c]]; }
  prep_pf_kernel<<<2304, 128, 0, stream>>>(pp, Pf);

  gather_xh_kernel<<<rows_pad / 8, 512, 0, stream>>>(xq8, off3, ssrc, sposinv, Ax, Ah, cntf);

  // pass 1: one dispatch, cv 0..4 = {xz,xr,xh on Ax (bias)} + {hz,hr on Ah}; conv fastest
  GArgs g0;
  { int cvs[5] = {0, 2, 4, 1, 3};
    static const int bi2[5] = {8, 17, 26, -1, -1};
    const bf16* Apts[5] = {Ax, Ax, Ax, Ah, Ah};
    for (int k = 0; k < 5; ++k) {
      int c = cvs[k];
      g0.Ap[k] = Apts[k];
      g0.wf[k] = Wf + (size_t)c * 49152;
      g0.pf[k] = Pf + (size_t)c * 3 * 16384;
      g0.out[k] = outs[c];
      g0.bias[k] = (bi2[k] >= 0) ? (const float*)d_in[bi2[k]] : nullptr;
    } }
  gemm_kernel<<<dim3(5, gx), 256, 0, stream>>>(g0, cntf, roleinfo);

  combine1_kernel<<<(rows_pad * 16 + 255) / 256, 256, 0, stream>>>(outs[2], outs[3], h, sposinv,
                                                                   q8, Aq, rows_pad);

  gather_q_kernel<<<rows_pad / 8, 512, 0, stream>>>(q8, off3, ssrc, sposinv, Aq);

  // pass 2: conv hh(5) on Aq
  GArgs g2 = {};
  g2.Ap[0] = Aq;
  g2.wf[0] = Wf + (size_t)5 * 49152;
  g2.pf[0] = Pf + (size_t)5 * 3 * 16384;
  g2.out[0] = outs[5];
  g2.bias[0] = nullptr;
  gemm_kernel<<<dim3(1, gx), 256, 0, stream>>>(g2, cntf, roleinfo);

  combine2_kernel<<<(rows_pad * 16 + 255) / 256, 256, 0, stream>>>(outs[0], outs[1], outs[4], outs[5],
                                                                   h, sposinv, (float*)d_out, rows_pad);
}